// Round 8
// baseline (643.484 us; speedup 1.0000x reference)
//
#include <hip/hip_runtime.h>

typedef unsigned short ushort_t;
typedef unsigned int uint_t;
typedef __attribute__((ext_vector_type(8))) short short8;
typedef __attribute__((ext_vector_type(4))) float f32x4;

#define SCALE 0.17677669529663687f

__device__ __forceinline__ float blo(uint_t u) { return __uint_as_float(u << 16); }
__device__ __forceinline__ float bhi(uint_t u) { return __uint_as_float(u & 0xffff0000u); }
__device__ __forceinline__ float u2f(ushort_t u) { return __uint_as_float(((uint_t)u) << 16); }
// fp32 -> bf16 (RNE), finite inputs
__device__ __forceinline__ ushort_t f2u(float f) {
    const uint_t x = __float_as_uint(f);
    return (ushort_t)((x + 0x7fffu + ((x >> 16) & 1u)) >> 16);
}
__device__ __forceinline__ uint_t pack2(float a, float b) {
    return (uint_t)f2u(a) | ((uint_t)f2u(b) << 16);
}

__device__ __forceinline__ float dot8(const float* qa, uint4 u) {
    return qa[0] * blo(u.x) + qa[1] * bhi(u.x) + qa[2] * blo(u.y) + qa[3] * bhi(u.y)
         + qa[4] * blo(u.z) + qa[5] * bhi(u.z) + qa[6] * blo(u.w) + qa[7] * bhi(u.w);
}
__device__ __forceinline__ void pv8(float* a, float e, uint4 u) {
    a[0] += e * blo(u.x); a[1] += e * bhi(u.x); a[2] += e * blo(u.y); a[3] += e * bhi(u.y);
    a[4] += e * blo(u.z); a[5] += e * bhi(u.z); a[6] += e * blo(u.w); a[7] += e * bhi(u.w);
}

// ==================================================================
// MAIN PATH: qkv materialized in ws as bf16 [p][j], p=131072, j=384.
// Requires ws_size >= 96 MB.
// ==================================================================

// ------------------------------------------------------------------
// k_qqkv (MFMA): qkv[p, j] = bf16( sum_c x[b,c,p]*qkv_w[c,j] + qkv_b[j] )
// Block = 128 pixels x all 384 j (3 j-tiles of 128), K=128.
// ------------------------------------------------------------------
__global__ __launch_bounds__(256) void k_qqkv(
    const float* __restrict__ x, const float* __restrict__ w,
    const float* __restrict__ wb, ushort_t* __restrict__ qkv)
{
    __shared__ ushort_t XT[128 * 128];  // [p][c] swizzled
    __shared__ ushort_t WT[128 * 128];  // [j][c] swizzled; reused as D [p][j]
    const int t = threadIdx.x;
    const int p0 = blockIdx.x * 128;
    const int b = p0 >> 14;             // HW = 16384
    const int rem = p0 & 16383;
    const float* xb = x + ((size_t)b << 21) + rem;

    // ---- stage XT: x[c][p] -> bf16 XT[p][c] (coalesced reads along p)
#pragma unroll
    for (int it = 0; it < 8; ++it) {
        const int slot = it * 256 + t;
        const int p = slot & 127, cb = slot >> 7;   // cb = 16B block along c
        uint4 u;
        {
            const float a0 = xb[(size_t)(cb * 8 + 0) * 16384 + p];
            const float a1 = xb[(size_t)(cb * 8 + 1) * 16384 + p];
            const float a2 = xb[(size_t)(cb * 8 + 2) * 16384 + p];
            const float a3 = xb[(size_t)(cb * 8 + 3) * 16384 + p];
            const float a4 = xb[(size_t)(cb * 8 + 4) * 16384 + p];
            const float a5 = xb[(size_t)(cb * 8 + 5) * 16384 + p];
            const float a6 = xb[(size_t)(cb * 8 + 6) * 16384 + p];
            const float a7 = xb[(size_t)(cb * 8 + 7) * 16384 + p];
            u.x = pack2(a0, a1); u.y = pack2(a2, a3);
            u.z = pack2(a4, a5); u.w = pack2(a6, a7);
        }
        *(uint4*)&XT[p * 128 + ((cb ^ (p & 7)) << 3)] = u;
    }

    const int l = t & 63, wv = t >> 6;
    const int wj = (wv >> 1) * 64, wp = (wv & 1) * 64;
    const int lr = l & 15, lg = l >> 4;

    for (int jt = 0; jt < 3; ++jt) {
        const int j0 = jt * 128;
        __syncthreads();   // XT ready (jt=0) / prior D drained (jt>0)

        // ---- stage WT: w[c][j0+j] -> bf16 WT[j][c] (coalesced along j; L2-hot)
#pragma unroll
        for (int it = 0; it < 8; ++it) {
            const int slot = it * 256 + t;
            const int j = slot & 127, cb = slot >> 7;
            uint4 u;
            {
                const float a0 = w[(size_t)(cb * 8 + 0) * 384 + j0 + j];
                const float a1 = w[(size_t)(cb * 8 + 1) * 384 + j0 + j];
                const float a2 = w[(size_t)(cb * 8 + 2) * 384 + j0 + j];
                const float a3 = w[(size_t)(cb * 8 + 3) * 384 + j0 + j];
                const float a4 = w[(size_t)(cb * 8 + 4) * 384 + j0 + j];
                const float a5 = w[(size_t)(cb * 8 + 5) * 384 + j0 + j];
                const float a6 = w[(size_t)(cb * 8 + 6) * 384 + j0 + j];
                const float a7 = w[(size_t)(cb * 8 + 7) * 384 + j0 + j];
                u.x = pack2(a0, a1); u.y = pack2(a2, a3);
                u.z = pack2(a4, a5); u.w = pack2(a6, a7);
            }
            *(uint4*)&WT[j * 128 + ((cb ^ (j & 7)) << 3)] = u;
        }
        __syncthreads();

        f32x4 acc[4][4];
#pragma unroll
        for (int i = 0; i < 4; ++i)
#pragma unroll
            for (int j = 0; j < 4; ++j) acc[i][j] = (f32x4){0.f, 0.f, 0.f, 0.f};

#pragma unroll
        for (int ks = 0; ks < 4; ++ks) {
            const int kb = ks * 4 + lg;
            short8 af[4], bf[4];
#pragma unroll
            for (int i = 0; i < 4; ++i) {
                const int jr = wj + i * 16 + lr;
                af[i] = *(const short8*)&WT[jr * 128 + ((kb ^ (jr & 7)) << 3)];
                const int pr = wp + i * 16 + lr;
                bf[i] = *(const short8*)&XT[pr * 128 + ((kb ^ (pr & 7)) << 3)];
            }
#pragma unroll
            for (int ji = 0; ji < 4; ++ji)
#pragma unroll
                for (int pi = 0; pi < 4; ++pi)
                    acc[ji][pi] = __builtin_amdgcn_mfma_f32_16x16x32_bf16(
                        af[ji], bf[pi], acc[ji][pi], 0, 0, 0);
        }
        __syncthreads();   // all WT reads done before D overwrite

        // ---- D write: lane holds 4 consecutive j at fixed p per acc tile
#pragma unroll
        for (int ji = 0; ji < 4; ++ji) {
            const int jq = wj + ji * 16 + 4 * lg;            // local j quad base
            const float4 bias = *(const float4*)&wb[j0 + jq];
#pragma unroll
            for (int pi = 0; pi < 4; ++pi) {
                const int p = wp + pi * 16 + lr;
                uint2 o;
                o.x = pack2(acc[ji][pi][0] + bias.x, acc[ji][pi][1] + bias.y);
                o.y = pack2(acc[ji][pi][2] + bias.z, acc[ji][pi][3] + bias.w);
                *(uint2*)&WT[p * 128 + (((jq >> 3) ^ (p & 7)) << 3) + (jq & 7)] = o;
            }
        }
        __syncthreads();

        // ---- copy D -> qkv, coalesced 16B writes (lanes sweep j)
#pragma unroll
        for (int it = 0; it < 8; ++it) {
            const int slot = it * 256 + t;
            const int seg = slot & 15, p = slot >> 4;
            const uint4 v = *(const uint4*)&WT[p * 128 + ((seg ^ (p & 7)) << 3)];
            *(uint4*)&qkv[(size_t)(p0 + p) * 384 + j0 + seg * 8] = v;
        }
    }
}

// ------------------------------------------------------------------
// k_attn3: per 8x8 window. ATTENTION ONLY (QK + online softmax + PV).
// Writes raw xa (fp32, channel-major [b][c][p]) into out; proj is a
// separate MFMA kernel (k_proj) that reads/writes out in place.
// Thread (h = t>>6, n = t&63).
// ------------------------------------------------------------------
__global__ __launch_bounds__(256, 4) void k_attn3(
    const ushort_t* __restrict__ qkv, const float* __restrict__ rpb,
    float* __restrict__ out)
{
    // [0, 8704) uints: k rows (64 x 68) then v rows (64 x 68), bf16 pairs.
    // [8704, 9604) floats: rpb table (225 x 4).
    __shared__ float arena[9604];
    uint_t* kv32 = (uint_t*)arena;
    float* rpbl = arena + 8704;
    const int t = threadIdx.x;
    const int b = blockIdx.x >> 8, wy = (blockIdx.x >> 4) & 15, wx = blockIdx.x & 15;
    const int prow0 = (b << 14) + (wy * 8) * 128 + wx * 8;
    const uint_t* qkvu = (const uint_t*)qkv;

    // stage k (j 128..255) and v (j 256..383): per m, 64 uints each
    for (int i = t; i < 4096; i += 256) {
        const int m = i >> 6, u = i & 63;
        const size_t pr = (size_t)(prow0 + (m >> 3) * 128 + (m & 7)) * 192;
        kv32[m * 68 + u]        = qkvu[pr + 64 + u];
        kv32[4352 + m * 68 + u] = qkvu[pr + 128 + u];
    }
    for (int i = t; i < 900; i += 256) rpbl[i] = rpb[i];

    const int h = t >> 6, n = t & 63;
    const size_t pq = (size_t)(prow0 + (n >> 3) * 128 + (n & 7)) * 192;
    float qa[32];
    const uint_t* qrow = qkvu + pq + h * 16;
#pragma unroll
    for (int j = 0; j < 16; ++j) {
        const uint_t u = qrow[j];
        qa[2 * j]     = blo(u) * SCALE;
        qa[2 * j + 1] = bhi(u) * SCALE;
    }
    __syncthreads();

    const int ry = n >> 3, rx = n & 7;
    const float* rpbl_t = rpbl + h;
    const int rbase = (ry + 7) * 15 + (rx + 7);

    const uint_t* kbase = kv32 + h * 16;
    const uint_t* vbase = kv32 + 4352 + h * 16;

    float mx = -1e30f, l = 0.f;
    float acc[32];
#pragma unroll
    for (int cc = 0; cc < 32; ++cc) acc[cc] = 0.f;

#pragma unroll 4
    for (int m = 0; m < 64; ++m) {
        const uint4* kr = (const uint4*)(kbase + m * 68);
        const uint4 k0 = kr[0], k1 = kr[1], k2 = kr[2], k3 = kr[3];
        float s = (dot8(qa, k0) + dot8(qa + 8, k1))
                + (dot8(qa + 16, k2) + dot8(qa + 24, k3));
        s += rpbl_t[4 * (rbase - (m >> 3) * 15 - (m & 7))];
        if (s > mx) {
            const float sc = __expf(mx - s);
            mx = s;
            l *= sc;
#pragma unroll
            for (int cc = 0; cc < 32; ++cc) acc[cc] *= sc;
        }
        const float e = __expf(s - mx);
        l += e;
        const uint4* vr = (const uint4*)(vbase + m * 68);
        const uint4 v0 = vr[0], v1 = vr[1], v2 = vr[2], v3 = vr[3];
        pv8(acc, e, v0); pv8(acc + 8, e, v1);
        pv8(acc + 16, e, v2); pv8(acc + 24, e, v3);
    }
    const float inv = 1.f / l;

    // write raw xa, channel-major: out[b][h*32+cc][oy*128+ox]
    const int oy = wy * 8 + ry, ox = wx * 8 + rx;
    float* ob = out + ((size_t)b << 21) + (size_t)(oy * 128 + ox);
#pragma unroll
    for (int cc = 0; cc < 32; ++cc)
        ob[(size_t)(h * 32 + cc) << 14] = acc[cc] * inv;
}

// ------------------------------------------------------------------
// k_proj (MFMA, in-place on out): out[b][j][p] =
//    rate1 * ( sum_c xa[b][c][p] * pw[c][j] + pb[j] ), xa = current out.
// ------------------------------------------------------------------
__global__ __launch_bounds__(256) void k_proj(
    const float* __restrict__ pw, const float* __restrict__ pb,
    const float* __restrict__ r1, float* __restrict__ out)
{
    __shared__ ushort_t XT[128 * 128];  // xa^T [p][c] swizzled
    __shared__ ushort_t WT[128 * 128];  // pw^T [j][c] swizzled
    const int t = threadIdx.x;
    const int p0 = blockIdx.x * 128;
    const int b = p0 >> 14;
    const int rem = p0 & 16383;
    const float* xb = out + ((size_t)b << 21) + rem;

    // ---- stage XT from out (xa), coalesced along p
#pragma unroll
    for (int it = 0; it < 8; ++it) {
        const int slot = it * 256 + t;
        const int p = slot & 127, cb = slot >> 7;
        uint4 u;
        {
            const float a0 = xb[(size_t)(cb * 8 + 0) * 16384 + p];
            const float a1 = xb[(size_t)(cb * 8 + 1) * 16384 + p];
            const float a2 = xb[(size_t)(cb * 8 + 2) * 16384 + p];
            const float a3 = xb[(size_t)(cb * 8 + 3) * 16384 + p];
            const float a4 = xb[(size_t)(cb * 8 + 4) * 16384 + p];
            const float a5 = xb[(size_t)(cb * 8 + 5) * 16384 + p];
            const float a6 = xb[(size_t)(cb * 8 + 6) * 16384 + p];
            const float a7 = xb[(size_t)(cb * 8 + 7) * 16384 + p];
            u.x = pack2(a0, a1); u.y = pack2(a2, a3);
            u.z = pack2(a4, a5); u.w = pack2(a6, a7);
        }
        *(uint4*)&XT[p * 128 + ((cb ^ (p & 7)) << 3)] = u;
    }
    // ---- stage WT from pw (128x128), coalesced along j
#pragma unroll
    for (int it = 0; it < 8; ++it) {
        const int slot = it * 256 + t;
        const int j = slot & 127, cb = slot >> 7;
        uint4 u;
        {
            const float a0 = pw[(size_t)(cb * 8 + 0) * 128 + j];
            const float a1 = pw[(size_t)(cb * 8 + 1) * 128 + j];
            const float a2 = pw[(size_t)(cb * 8 + 2) * 128 + j];
            const float a3 = pw[(size_t)(cb * 8 + 3) * 128 + j];
            const float a4 = pw[(size_t)(cb * 8 + 4) * 128 + j];
            const float a5 = pw[(size_t)(cb * 8 + 5) * 128 + j];
            const float a6 = pw[(size_t)(cb * 8 + 6) * 128 + j];
            const float a7 = pw[(size_t)(cb * 8 + 7) * 128 + j];
            u.x = pack2(a0, a1); u.y = pack2(a2, a3);
            u.z = pack2(a4, a5); u.w = pack2(a6, a7);
        }
        *(uint4*)&WT[j * 128 + ((cb ^ (j & 7)) << 3)] = u;
    }
    __syncthreads();   // all global reads of this block's pixels complete here

    const int l = t & 63, wv = t >> 6;
    const int wj = (wv >> 1) * 64, wp = (wv & 1) * 64;
    const int lr = l & 15, lg = l >> 4;

    f32x4 acc[4][4];
#pragma unroll
    for (int i = 0; i < 4; ++i)
#pragma unroll
        for (int j = 0; j < 4; ++j) acc[i][j] = (f32x4){0.f, 0.f, 0.f, 0.f};

#pragma unroll
    for (int ks = 0; ks < 4; ++ks) {
        const int kb = ks * 4 + lg;
        short8 af[4], bf[4];
#pragma unroll
        for (int i = 0; i < 4; ++i) {
            const int jr = wj + i * 16 + lr;
            af[i] = *(const short8*)&WT[jr * 128 + ((kb ^ (jr & 7)) << 3)];
            const int pr = wp + i * 16 + lr;
            bf[i] = *(const short8*)&XT[pr * 128 + ((kb ^ (pr & 7)) << 3)];
        }
#pragma unroll
        for (int ji = 0; ji < 4; ++ji)
#pragma unroll
            for (int pi = 0; pi < 4; ++pi)
                acc[ji][pi] = __builtin_amdgcn_mfma_f32_16x16x32_bf16(
                    af[ji], bf[pi], acc[ji][pi], 0, 0, 0);
    }

    const float rate1 = r1[0];
    float* obase = out + ((size_t)b << 21) + rem;
    // lane holds j = jq..jq+3 at pixel p; stores are 16-lane p-contiguous
#pragma unroll
    for (int ji = 0; ji < 4; ++ji) {
        const int jq = wj + ji * 16 + 4 * lg;
        const float4 bias = *(const float4*)&pb[jq];
#pragma unroll
        for (int pi = 0; pi < 4; ++pi) {
            const int p = wp + pi * 16 + lr;
            float* op = obase + (size_t)jq * 16384 + p;
            op[0]     = rate1 * (acc[ji][pi][0] + bias.x);
            op[16384] = rate1 * (acc[ji][pi][1] + bias.y);
            op[32768] = rate1 * (acc[ji][pi][2] + bias.z);
            op[49152] = rate1 * (acc[ji][pi][3] + bias.w);
        }
    }
}

// ------------------------------------------------------------------
// k_conv4: per 8x4 output tile (8 wide x 4 tall; halo 6x10 = 60
// pixels), 256 threads, ~61 KB LDS -> 2 blocks/CU. Stage all 60 full
// qkv rows into LDS once (full cache-line use), then run the 8
// d-chunks from LDS: fcl[36][60] then 81-tap conv per (out-pixel,
// oc-pair); RMW out += rate2*(conv+depb).
// ------------------------------------------------------------------
__global__ __launch_bounds__(256) void k_conv4(
    const ushort_t* __restrict__ qkv, const float* __restrict__ fcw,
    const float* __restrict__ fcb, const float* __restrict__ depw,
    const float* __restrict__ depb, const float* __restrict__ r2,
    float* __restrict__ out)
{
    __shared__ ushort_t qbuf[23280];            // 60 x 388 ushorts (776 B rows)
    __shared__ float fcl[2160];                 // [(i*4+dd)*60 + pix]
    __shared__ __align__(16) float dwl[1296];   // [kk81][16 oc-in-chunk]
    __shared__ float fcwl[108];
    __shared__ float fcbl[9];

    const int t = threadIdx.x;
    const int b = blockIdx.x >> 9, tile = blockIdx.x & 511;
    const int ty0 = (tile >> 4) << 2;           // 32 ty tiles of 4
    const int tx0 = (tile & 15) << 3;           // 16 tx tiles of 8
    if (t < 108) fcwl[t] = fcw[t];
    else if (t < 117) fcbl[t - 108] = fcb[t - 108];
    const float rate2 = r2[0];

    // ---- stage qbuf: 60 halo rows x 48 uint4 each, zeros outside image
    const uint4* qkv4 = (const uint4*)qkv;
    for (int i = t; i < 2880; i += 256) {
        const int row = i / 48, seg = i - row * 48;
        const int hr = row / 10, hc = row - hr * 10;
        const int gy = ty0 + hr - 1, gx = tx0 + hc - 1;
        uint4 v = make_uint4(0u, 0u, 0u, 0u);
        if ((unsigned)gy < 128u && (unsigned)gx < 128u) {
            const int g = (b << 14) + gy * 128 + gx;
            v = qkv4[(size_t)g * 48 + seg];
        }
        char* dst = (char*)qbuf + row * 776 + seg * 16;
        *(uint2*)dst       = make_uint2(v.x, v.y);
        *(uint2*)(dst + 8) = make_uint2(v.z, v.w);
    }

    const int op = t & 31, og = t >> 5;         // out pixel, oc-pair group
    const int py = op >> 3, px = op & 7;
    const int dd_c = og >> 1;                   // fcl dd for this og (pairwise)
    const int gy_o = ty0 + py, gx_o = tx0 + px;
    float* ob = out + ((size_t)b << 21) + (size_t)(gy_o * 128 + gx_o);

    for (int chunk = 0; chunk < 8; ++chunk) {
        __syncthreads();   // qbuf/fcwl ready (chunk 0) / prior conv reads done

        // ---- dep weights for this chunk
        for (int i = t; i < 1296; i += 256)
            dwl[i] = depw[(chunk * 16 + (i & 15)) * 81 + (i >> 4)];

        // ---- fcl: 9 i x 60 pixels, 4 dd each, from qbuf (LDS)
        for (int v = t; v < 540; v += 256) {
            const int i9 = v / 60, pix = v - i9 * 60;
            const int hr = pix / 10, hc = pix - hr * 10;
            const int gy = ty0 + hr - 1, gx = tx0 + hc - 1;
            const bool inb = ((unsigned)gy < 128u) && ((unsigned)gx < 128u);
            const float bv = inb ? fcbl[i9] : 0.f;
            float fo0 = bv, fo1 = bv, fo2 = bv, fo3 = bv;
            const char* qrow = (const char*)qbuf + pix * 776 + chunk * 8;
#pragma unroll
            for (int e = 0; e < 12; ++e) {
                const uint2 q = *(const uint2*)(qrow + e * 64);
                const float wv = fcwl[i9 * 12 + e];
                fo0 += wv * blo(q.x); fo1 += wv * bhi(q.x);
                fo2 += wv * blo(q.y); fo3 += wv * bhi(q.y);
            }
            float* fp = fcl + i9 * 240 + pix;   // (i9*4+dd)*60 + pix
            fp[0] = fo0; fp[60] = fo1; fp[120] = fo2; fp[180] = fo3;
        }
        __syncthreads();

        // ---- conv: thread (op, og) does oc = chunk*16 + og*2 + {0,1}
        float a0 = 0.f, a1 = 0.f;
#pragma unroll
        for (int ii = 0; ii < 9; ++ii) {
#pragma unroll
            for (int kk = 0; kk < 9; ++kk) {
                const int ky = kk / 3, kx = kk - (kk / 3) * 3;
                const float f = fcl[(ii * 4 + dd_c) * 60 + (py + ky) * 10 + px + kx];
                const float2 w2 = *(const float2*)&dwl[(ii * 9 + kk) * 16 + og * 2];
                a0 += f * w2.x; a1 += f * w2.y;
            }
        }
        const int oc0 = chunk * 16 + og * 2;
        ob[(size_t)oc0 << 14]       += rate2 * (a0 + depb[oc0]);
        ob[(size_t)(oc0 + 1) << 14] += rate2 * (a1 + depb[oc0 + 1]);
    }
}

// ==================================================================
// FALLBACK PATH (ws too small): round-5 kernels, verbatim.
// ==================================================================
#define WS_W2  0
#define WS_B2  36864
#define WS_TOT 37152

__global__ __launch_bounds__(256) void k_prep_f(
    const float* __restrict__ qkv_w, const float* __restrict__ qkv_b,
    const float* __restrict__ fcw, const float* __restrict__ fcb,
    float* __restrict__ ws)
{
    const int idx = blockIdx.x * 256 + threadIdx.x;
    if (idx < WS_B2) {
        const int c = idx / 288, r = idx - c * 288, i = r >> 5, d = r & 31;
        float s = 0.f;
#pragma unroll
        for (int e = 0; e < 12; ++e)
            s += fcw[i * 12 + e] * qkv_w[c * 384 + e * 32 + d];
        ws[idx] = s;
    } else if (idx < WS_TOT) {
        const int r = idx - WS_B2, i = r >> 5, d = r & 31;
        float s = fcb[i];
#pragma unroll
        for (int e = 0; e < 12; ++e)
            s += fcw[i * 12 + e] * qkv_b[e * 32 + d];
        ws[idx] = s;
    }
}

__global__ __launch_bounds__(256) void k_attn_f(
    const float* __restrict__ x, const float* __restrict__ qw,
    const float* __restrict__ qb, const float* __restrict__ pw,
    const float* __restrict__ pb, const float* __restrict__ rpb,
    const float* __restrict__ r1, float* __restrict__ out)
{
    __shared__ ushort_t xw[8192];
    __shared__ float arena[8450];
    ushort_t* kvb = (ushort_t*)arena;
    const int t = threadIdx.x;
    const int b = blockIdx.x >> 8, wy = (blockIdx.x >> 4) & 15, wx = blockIdx.x & 15;
    const size_t xbase = ((size_t)b << 21) + (size_t)((wy * 8) * 128 + wx * 8);
    for (int i = t; i < 8192; i += 256) {
        const int c = i >> 6, p = i & 63;
        xw[i] = f2u(x[xbase + (size_t)c * 16384 + (p >> 3) * 128 + (p & 7)]);
    }
    __syncthreads();
    const int h = t >> 6, n = t & 63;
    float qa[32], ka[32], va[32];
#pragma unroll
    for (int cc = 0; cc < 32; ++cc) {
        qa[cc] = qb[h * 32 + cc];
        ka[cc] = qb[128 + h * 32 + cc];
        va[cc] = qb[256 + h * 32 + cc];
    }
    const float* wbase = qw + h * 32;
    for (int c = 0; c < 128; ++c) {
        const float xv = u2f(xw[c * 64 + n]);
        const float* wr = wbase + c * 384;
#pragma unroll
        for (int j = 0; j < 8; ++j) {
            const float4 aq = ((const float4*)wr)[j];
            const float4 ak = ((const float4*)(wr + 128))[j];
            const float4 av = ((const float4*)(wr + 256))[j];
            qa[4 * j + 0] += xv * aq.x; qa[4 * j + 1] += xv * aq.y;
            qa[4 * j + 2] += xv * aq.z; qa[4 * j + 3] += xv * aq.w;
            ka[4 * j + 0] += xv * ak.x; ka[4 * j + 1] += xv * ak.y;
            ka[4 * j + 2] += xv * ak.z; ka[4 * j + 3] += xv * ak.w;
            va[4 * j + 0] += xv * av.x; va[4 * j + 1] += xv * av.y;
            va[4 * j + 2] += xv * av.z; va[4 * j + 3] += xv * av.w;
        }
    }
#pragma unroll
    for (int cc = 0; cc < 32; ++cc) qa[cc] *= SCALE;
    uint_t* kv32 = (uint_t*)kvb;
#pragma unroll
    for (int j = 0; j < 16; ++j) {
        kv32[n * 66 + h * 16 + j] = pack2(ka[2 * j], ka[2 * j + 1]);
        kv32[4224 + n * 66 + h * 16 + j] = pack2(va[2 * j], va[2 * j + 1]);
    }
    __syncthreads();
    const int ry = n >> 3, rx = n & 7;
    float sar[64];
    float mx = -1e30f;
#pragma unroll
    for (int m = 0; m < 64; ++m) {
        const uint2* kr = (const uint2*)(kvb + m * 132 + h * 32);
        float s = 0.f;
#pragma unroll
        for (int j = 0; j < 8; ++j) {
            const uint2 u = kr[j];
            s += qa[4 * j + 0] * blo(u.x) + qa[4 * j + 1] * bhi(u.x)
               + qa[4 * j + 2] * blo(u.y) + qa[4 * j + 3] * bhi(u.y);
        }
        s += rpb[((ry - (m >> 3) + 7) * 15 + (rx - (m & 7) + 7)) * 4 + h];
        sar[m] = s;
        mx = fmaxf(mx, s);
    }
    float l = 0.f;
#pragma unroll
    for (int m = 0; m < 64; ++m) { const float e = __expf(sar[m] - mx); sar[m] = e; l += e; }
    const float inv = 1.f / l;
    float acc[32];
#pragma unroll
    for (int cc = 0; cc < 32; ++cc) acc[cc] = 0.f;
#pragma unroll
    for (int m = 0; m < 64; ++m) {
        const float pm = sar[m];
        const uint2* vr = (const uint2*)(kvb + 8448 + m * 132 + h * 32);
#pragma unroll
        for (int j = 0; j < 8; ++j) {
            const uint2 u = vr[j];
            acc[4 * j + 0] += pm * blo(u.x); acc[4 * j + 1] += pm * bhi(u.x);
            acc[4 * j + 2] += pm * blo(u.y); acc[4 * j + 3] += pm * bhi(u.y);
        }
    }
    __syncthreads();
#pragma unroll
    for (int cc = 0; cc < 32; ++cc) arena[n * 130 + h * 32 + cc] = acc[cc] * inv;
    __syncthreads();
    const int p = t & 63, jb = t >> 6;
    float aj[32];
#pragma unroll
    for (int jj = 0; jj < 32; ++jj) aj[jj] = pb[jb * 32 + jj];
    const float* xr = arena + p * 130;
    const float* pwb = pw + jb * 32;
    for (int c = 0; c < 128; ++c) {
        const float xv = xr[c];
        const float4* pr = (const float4*)(pwb + c * 128);
#pragma unroll
        for (int j = 0; j < 8; ++j) {
            const float4 w4 = pr[j];
            aj[4 * j + 0] += xv * w4.x; aj[4 * j + 1] += xv * w4.y;
            aj[4 * j + 2] += xv * w4.z; aj[4 * j + 3] += xv * w4.w;
        }
    }
    const float rate1 = r1[0];
    const int oy = wy * 8 + (p >> 3), ox = wx * 8 + (p & 7);
    float* ob = out + ((size_t)b << 21) + (size_t)(oy * 128 + ox);
#pragma unroll
    for (int jj = 0; jj < 32; ++jj)
        ob[(size_t)(jb * 32 + jj) << 14] = rate1 * aj[jj];
}

__global__ __launch_bounds__(256) void k_conv_f(
    const float* __restrict__ x, const float* __restrict__ ws,
    const float* __restrict__ depw, const float* __restrict__ depb,
    const float* __restrict__ r2, float* __restrict__ out)
{
    __shared__ float arena[12960];
    __shared__ float b2s[36];
    float* w2l = arena;
    ushort_t* xl = (ushort_t*)(arena + 4608);
    float* fcl = arena;
    float* dwl = arena + 11664;
    const int t = threadIdx.x;
    const int b = blockIdx.x >> 6, tile = blockIdx.x & 63;
    const int ty0 = (tile >> 3) << 4, tx0 = (tile & 7) << 4;
    const size_t xbase = ((size_t)b << 21);
    const float rate2 = r2[0];
    const int py = t >> 4, px = t & 15;
    float* ob = out + ((size_t)b << 21) + (size_t)((ty0 + py) * 128 + (tx0 + px));
    const int r0 = t / 18, c0 = t - r0 * 18;
    const bool ok0 = ((unsigned)(ty0 + r0 - 1) < 128u) && ((unsigned)(tx0 + c0 - 1) < 128u);
    const int t1 = 256 + t, r1i = t1 / 18, c1 = t1 - r1i * 18;
    const bool ok1 = (t < 68) && ((unsigned)(ty0 + r1i - 1) < 128u) && ((unsigned)(tx0 + c1 - 1) < 128u);
    for (int chunk = 0; chunk < 8; ++chunk) {
        __syncthreads();
        for (int i = t; i < 4608; i += 256) {
            const int c = i / 36, r = i - c * 36;
            w2l[i] = ws[WS_W2 + c * 288 + (r >> 2) * 32 + chunk * 4 + (r & 3)];
        }
        if (t < 36) b2s[t] = ws[WS_B2 + (t >> 2) * 32 + chunk * 4 + (t & 3)];
        __syncthreads();
        float fca[2][36];
#pragma unroll
        for (int r = 0; r < 36; ++r) { fca[0][r] = b2s[r]; fca[1][r] = b2s[r]; }
        for (int cs = 0; cs < 8; ++cs) {
            if (cs) __syncthreads();
            for (int i = t; i < 5184; i += 256) {
                const int cc = i / 324, pp = i - cc * 324;
                const int row = pp / 18, col = pp - row * 18;
                const int hy = ty0 + row - 1, hx = tx0 + col - 1;
                ushort_t v = 0;
                if ((unsigned)hy < 128u && (unsigned)hx < 128u)
                    v = f2u(x[xbase + (size_t)(cs * 16 + cc) * 16384 + hy * 128 + hx]);
                xl[i] = v;
            }
            __syncthreads();
#pragma unroll 4
            for (int cc = 0; cc < 16; ++cc) {
                const float xv0 = u2f(xl[cc * 324 + t]);
                const float xv1 = (t < 68) ? u2f(xl[cc * 324 + 256 + t]) : 0.f;
                const float* wr = w2l + (cs * 16 + cc) * 36;
#pragma unroll
                for (int r = 0; r < 36; r += 4) {
                    const float4 w4 = *(const float4*)(wr + r);
                    fca[0][r + 0] += xv0 * w4.x; fca[0][r + 1] += xv0 * w4.y;
                    fca[0][r + 2] += xv0 * w4.z; fca[0][r + 3] += xv0 * w4.w;
                    fca[1][r + 0] += xv1 * w4.x; fca[1][r + 1] += xv1 * w4.y;
                    fca[1][r + 2] += xv1 * w4.z; fca[1][r + 3] += xv1 * w4.w;
                }
            }
        }
        __syncthreads();
#pragma unroll
        for (int r = 0; r < 36; ++r) {
            fcl[r * 324 + t] = ok0 ? fca[0][r] : 0.f;
            if (t < 68) fcl[r * 324 + 256 + t] = ok1 ? fca[1][r] : 0.f;
        }
        for (int i = t; i < 1296; i += 256) {
            const int kk = i >> 4, ocl = i & 15;
            dwl[i] = depw[(chunk * 16 + ocl) * 81 + kk];
        }
        __syncthreads();
        float4 accv[4];
#pragma unroll
        for (int dd = 0; dd < 4; ++dd) accv[dd] = make_float4(0.f, 0.f, 0.f, 0.f);
#pragma unroll
        for (int ii = 0; ii < 9; ++ii) {
#pragma unroll
            for (int kk = 0; kk < 9; ++kk) {
                const int ky = kk / 3, kx = kk - (kk / 3) * 3;
                const int hpix = (py + ky) * 18 + px + kx;
                const float4* dwp = (const float4*)&dwl[(ii * 9 + kk) * 16];
#pragma unroll
                for (int dd = 0; dd < 4; ++dd) {
                    const float f = fcl[(ii * 4 + dd) * 324 + hpix];
                    const float4 d4 = dwp[dd];
                    accv[dd].x += f * d4.x; accv[dd].y += f * d4.y;
                    accv[dd].z += f * d4.z; accv[dd].w += f * d4.w;
                }
            }
        }
#pragma unroll
        for (int dd = 0; dd < 4; ++dd) {
            const float av[4] = {accv[dd].x, accv[dd].y, accv[dd].z, accv[dd].w};
#pragma unroll
            for (int j = 0; j < 4; ++j) {
                const int oc = chunk * 16 + dd * 4 + j;
                ob[(size_t)oc << 14] += rate2 * (av[j] + depb[oc]);
            }
        }
    }
}

// ------------------------------------------------------------------
extern "C" void kernel_launch(void* const* d_in, const int* in_sizes, int n_in,
                              void* d_out, int out_size, void* d_ws, size_t ws_size,
                              hipStream_t stream) {
    (void)in_sizes; (void)n_in; (void)out_size;
    const float* x      = (const float*)d_in[0];
    const float* qkv_w  = (const float*)d_in[1];
    const float* qkv_b  = (const float*)d_in[2];
    const float* proj_w = (const float*)d_in[3];
    const float* proj_b = (const float*)d_in[4];
    const float* rpb    = (const float*)d_in[5];
    const float* fc_w   = (const float*)d_in[6];
    const float* fc_b   = (const float*)d_in[7];
    const float* dep_w  = (const float*)d_in[8];
    const float* dep_b  = (const float*)d_in[9];
    const float* rate1  = (const float*)d_in[10];
    const float* rate2  = (const float*)d_in[11];
    float* out = (float*)d_out;

    if (ws_size >= (size_t)131072 * 384 * 2) {
        ushort_t* qkv = (ushort_t*)d_ws;   // 96 MB bf16
        k_qqkv<<<dim3(1024), dim3(256), 0, stream>>>(x, qkv_w, qkv_b, qkv);
        k_attn3<<<dim3(2048), dim3(256), 0, stream>>>(qkv, rpb, out);
        k_proj<<<dim3(1024), dim3(256), 0, stream>>>(proj_w, proj_b, rate1, out);
        k_conv4<<<dim3(4096), dim3(256), 0, stream>>>(qkv, fc_w, fc_b, dep_w,
                                                      dep_b, rate2, out);
    } else {
        float* wsf = (float*)d_ws;         // 148.6 KB
        k_prep_f<<<dim3(146), dim3(256), 0, stream>>>(qkv_w, qkv_b, fc_w, fc_b, wsf);
        k_attn_f<<<dim3(2048), dim3(256), 0, stream>>>(x, qkv_w, qkv_b, proj_w,
                                                       proj_b, rpb, rate1, out);
        k_conv_f<<<dim3(512), dim3(256), 0, stream>>>(x, wsf, dep_w, dep_b,
                                                      rate2, out);
    }
}

// Round 9
// 535.726 us; speedup vs baseline: 1.2011x; 1.2011x over previous
//
#include <hip/hip_runtime.h>

typedef unsigned short ushort_t;
typedef unsigned int uint_t;
typedef __attribute__((ext_vector_type(8))) short short8;
typedef __attribute__((ext_vector_type(4))) float f32x4;

#define SCALE 0.17677669529663687f

__device__ __forceinline__ float blo(uint_t u) { return __uint_as_float(u << 16); }
__device__ __forceinline__ float bhi(uint_t u) { return __uint_as_float(u & 0xffff0000u); }
__device__ __forceinline__ float u2f(ushort_t u) { return __uint_as_float(((uint_t)u) << 16); }
// fp32 -> bf16 (RNE), finite inputs
__device__ __forceinline__ ushort_t f2u(float f) {
    const uint_t x = __float_as_uint(f);
    return (ushort_t)((x + 0x7fffu + ((x >> 16) & 1u)) >> 16);
}
__device__ __forceinline__ uint_t pack2(float a, float b) {
    return (uint_t)f2u(a) | ((uint_t)f2u(b) << 16);
}

__device__ __forceinline__ float dot8(const float* qa, uint4 u) {
    return qa[0] * blo(u.x) + qa[1] * bhi(u.x) + qa[2] * blo(u.y) + qa[3] * bhi(u.y)
         + qa[4] * blo(u.z) + qa[5] * bhi(u.z) + qa[6] * blo(u.w) + qa[7] * bhi(u.w);
}
__device__ __forceinline__ void pv8(float* a, float e, uint4 u) {
    a[0] += e * blo(u.x); a[1] += e * bhi(u.x); a[2] += e * blo(u.y); a[3] += e * bhi(u.y);
    a[4] += e * blo(u.z); a[5] += e * bhi(u.z); a[6] += e * blo(u.w); a[7] += e * bhi(u.w);
}

// ==================================================================
// MAIN PATH: qkv materialized in ws as bf16 [p][j], p=131072, j=384.
// Requires ws_size >= 96 MB.
// ==================================================================

// ------------------------------------------------------------------
// k_qqkv (MFMA): qkv[p, j] = bf16( sum_c x[b,c,p]*qkv_w[c,j] + qkv_b[j] )
// Block = 128 pixels x all 384 j (3 j-tiles of 128), K=128.
// ------------------------------------------------------------------
__global__ __launch_bounds__(256) void k_qqkv(
    const float* __restrict__ x, const float* __restrict__ w,
    const float* __restrict__ wb, ushort_t* __restrict__ qkv)
{
    __shared__ ushort_t XT[128 * 128];  // [p][c] swizzled
    __shared__ ushort_t WT[128 * 128];  // [j][c] swizzled; reused as D [p][j]
    const int t = threadIdx.x;
    const int p0 = blockIdx.x * 128;
    const int b = p0 >> 14;             // HW = 16384
    const int rem = p0 & 16383;
    const float* xb = x + ((size_t)b << 21) + rem;

    // ---- stage XT: x[c][p] -> bf16 XT[p][c] (coalesced reads along p)
#pragma unroll
    for (int it = 0; it < 8; ++it) {
        const int slot = it * 256 + t;
        const int p = slot & 127, cb = slot >> 7;   // cb = 16B block along c
        uint4 u;
        {
            const float a0 = xb[(size_t)(cb * 8 + 0) * 16384 + p];
            const float a1 = xb[(size_t)(cb * 8 + 1) * 16384 + p];
            const float a2 = xb[(size_t)(cb * 8 + 2) * 16384 + p];
            const float a3 = xb[(size_t)(cb * 8 + 3) * 16384 + p];
            const float a4 = xb[(size_t)(cb * 8 + 4) * 16384 + p];
            const float a5 = xb[(size_t)(cb * 8 + 5) * 16384 + p];
            const float a6 = xb[(size_t)(cb * 8 + 6) * 16384 + p];
            const float a7 = xb[(size_t)(cb * 8 + 7) * 16384 + p];
            u.x = pack2(a0, a1); u.y = pack2(a2, a3);
            u.z = pack2(a4, a5); u.w = pack2(a6, a7);
        }
        *(uint4*)&XT[p * 128 + ((cb ^ (p & 7)) << 3)] = u;
    }

    const int l = t & 63, wv = t >> 6;
    const int wj = (wv >> 1) * 64, wp = (wv & 1) * 64;
    const int lr = l & 15, lg = l >> 4;

    for (int jt = 0; jt < 3; ++jt) {
        const int j0 = jt * 128;
        __syncthreads();   // XT ready (jt=0) / prior D drained (jt>0)

        // ---- stage WT: w[c][j0+j] -> bf16 WT[j][c] (coalesced along j; L2-hot)
#pragma unroll
        for (int it = 0; it < 8; ++it) {
            const int slot = it * 256 + t;
            const int j = slot & 127, cb = slot >> 7;
            uint4 u;
            {
                const float a0 = w[(size_t)(cb * 8 + 0) * 384 + j0 + j];
                const float a1 = w[(size_t)(cb * 8 + 1) * 384 + j0 + j];
                const float a2 = w[(size_t)(cb * 8 + 2) * 384 + j0 + j];
                const float a3 = w[(size_t)(cb * 8 + 3) * 384 + j0 + j];
                const float a4 = w[(size_t)(cb * 8 + 4) * 384 + j0 + j];
                const float a5 = w[(size_t)(cb * 8 + 5) * 384 + j0 + j];
                const float a6 = w[(size_t)(cb * 8 + 6) * 384 + j0 + j];
                const float a7 = w[(size_t)(cb * 8 + 7) * 384 + j0 + j];
                u.x = pack2(a0, a1); u.y = pack2(a2, a3);
                u.z = pack2(a4, a5); u.w = pack2(a6, a7);
            }
            *(uint4*)&WT[j * 128 + ((cb ^ (j & 7)) << 3)] = u;
        }
        __syncthreads();

        f32x4 acc[4][4];
#pragma unroll
        for (int i = 0; i < 4; ++i)
#pragma unroll
            for (int j = 0; j < 4; ++j) acc[i][j] = (f32x4){0.f, 0.f, 0.f, 0.f};

#pragma unroll
        for (int ks = 0; ks < 4; ++ks) {
            const int kb = ks * 4 + lg;
            short8 af[4], bf[4];
#pragma unroll
            for (int i = 0; i < 4; ++i) {
                const int jr = wj + i * 16 + lr;
                af[i] = *(const short8*)&WT[jr * 128 + ((kb ^ (jr & 7)) << 3)];
                const int pr = wp + i * 16 + lr;
                bf[i] = *(const short8*)&XT[pr * 128 + ((kb ^ (pr & 7)) << 3)];
            }
#pragma unroll
            for (int ji = 0; ji < 4; ++ji)
#pragma unroll
                for (int pi = 0; pi < 4; ++pi)
                    acc[ji][pi] = __builtin_amdgcn_mfma_f32_16x16x32_bf16(
                        af[ji], bf[pi], acc[ji][pi], 0, 0, 0);
        }
        __syncthreads();   // all WT reads done before D overwrite

        // ---- D write: lane holds 4 consecutive j at fixed p per acc tile
#pragma unroll
        for (int ji = 0; ji < 4; ++ji) {
            const int jq = wj + ji * 16 + 4 * lg;            // local j quad base
            const float4 bias = *(const float4*)&wb[j0 + jq];
#pragma unroll
            for (int pi = 0; pi < 4; ++pi) {
                const int p = wp + pi * 16 + lr;
                uint2 o;
                o.x = pack2(acc[ji][pi][0] + bias.x, acc[ji][pi][1] + bias.y);
                o.y = pack2(acc[ji][pi][2] + bias.z, acc[ji][pi][3] + bias.w);
                *(uint2*)&WT[p * 128 + (((jq >> 3) ^ (p & 7)) << 3) + (jq & 7)] = o;
            }
        }
        __syncthreads();

        // ---- copy D -> qkv, coalesced 16B writes (lanes sweep j)
#pragma unroll
        for (int it = 0; it < 8; ++it) {
            const int slot = it * 256 + t;
            const int seg = slot & 15, p = slot >> 4;
            const uint4 v = *(const uint4*)&WT[p * 128 + ((seg ^ (p & 7)) << 3)];
            *(uint4*)&qkv[(size_t)(p0 + p) * 384 + j0 + seg * 8] = v;
        }
    }
}

// ------------------------------------------------------------------
// k_attn3: per 8x8 window. ATTENTION ONLY (QK + online softmax + PV).
// Writes raw xa (fp32, channel-major [b][c][p]) into out; proj is a
// separate MFMA kernel (k_proj) that reads/writes out in place.
// Thread (h = t>>6, n = t&63).
// ------------------------------------------------------------------
__global__ __launch_bounds__(256, 4) void k_attn3(
    const ushort_t* __restrict__ qkv, const float* __restrict__ rpb,
    float* __restrict__ out)
{
    // [0, 8704) uints: k rows (64 x 68) then v rows (64 x 68), bf16 pairs.
    // [8704, 9604) floats: rpb table (225 x 4).
    __shared__ float arena[9604];
    uint_t* kv32 = (uint_t*)arena;
    float* rpbl = arena + 8704;
    const int t = threadIdx.x;
    const int b = blockIdx.x >> 8, wy = (blockIdx.x >> 4) & 15, wx = blockIdx.x & 15;
    const int prow0 = (b << 14) + (wy * 8) * 128 + wx * 8;
    const uint_t* qkvu = (const uint_t*)qkv;

    // stage k (j 128..255) and v (j 256..383): per m, 64 uints each
    for (int i = t; i < 4096; i += 256) {
        const int m = i >> 6, u = i & 63;
        const size_t pr = (size_t)(prow0 + (m >> 3) * 128 + (m & 7)) * 192;
        kv32[m * 68 + u]        = qkvu[pr + 64 + u];
        kv32[4352 + m * 68 + u] = qkvu[pr + 128 + u];
    }
    for (int i = t; i < 900; i += 256) rpbl[i] = rpb[i];

    const int h = t >> 6, n = t & 63;
    const size_t pq = (size_t)(prow0 + (n >> 3) * 128 + (n & 7)) * 192;
    float qa[32];
    const uint_t* qrow = qkvu + pq + h * 16;
#pragma unroll
    for (int j = 0; j < 16; ++j) {
        const uint_t u = qrow[j];
        qa[2 * j]     = blo(u) * SCALE;
        qa[2 * j + 1] = bhi(u) * SCALE;
    }
    __syncthreads();

    const int ry = n >> 3, rx = n & 7;
    const float* rpbl_t = rpbl + h;
    const int rbase = (ry + 7) * 15 + (rx + 7);

    const uint_t* kbase = kv32 + h * 16;
    const uint_t* vbase = kv32 + 4352 + h * 16;

    float mx = -1e30f, l = 0.f;
    float acc[32];
#pragma unroll
    for (int cc = 0; cc < 32; ++cc) acc[cc] = 0.f;

#pragma unroll 4
    for (int m = 0; m < 64; ++m) {
        const uint4* kr = (const uint4*)(kbase + m * 68);
        const uint4 k0 = kr[0], k1 = kr[1], k2 = kr[2], k3 = kr[3];
        float s = (dot8(qa, k0) + dot8(qa + 8, k1))
                + (dot8(qa + 16, k2) + dot8(qa + 24, k3));
        s += rpbl_t[4 * (rbase - (m >> 3) * 15 - (m & 7))];
        if (s > mx) {
            const float sc = __expf(mx - s);
            mx = s;
            l *= sc;
#pragma unroll
            for (int cc = 0; cc < 32; ++cc) acc[cc] *= sc;
        }
        const float e = __expf(s - mx);
        l += e;
        const uint4* vr = (const uint4*)(vbase + m * 68);
        const uint4 v0 = vr[0], v1 = vr[1], v2 = vr[2], v3 = vr[3];
        pv8(acc, e, v0); pv8(acc + 8, e, v1);
        pv8(acc + 16, e, v2); pv8(acc + 24, e, v3);
    }
    const float inv = 1.f / l;

    // write raw xa, channel-major: out[b][h*32+cc][oy*128+ox]
    const int oy = wy * 8 + ry, ox = wx * 8 + rx;
    float* ob = out + ((size_t)b << 21) + (size_t)(oy * 128 + ox);
#pragma unroll
    for (int cc = 0; cc < 32; ++cc)
        ob[(size_t)(h * 32 + cc) << 14] = acc[cc] * inv;
}

// ------------------------------------------------------------------
// k_proj (MFMA, in-place on out): out[b][j][p] =
//    rate1 * ( sum_c xa[b][c][p] * pw[c][j] + pb[j] ), xa = current out.
// ------------------------------------------------------------------
__global__ __launch_bounds__(256) void k_proj(
    const float* __restrict__ pw, const float* __restrict__ pb,
    const float* __restrict__ r1, float* __restrict__ out)
{
    __shared__ ushort_t XT[128 * 128];  // xa^T [p][c] swizzled
    __shared__ ushort_t WT[128 * 128];  // pw^T [j][c] swizzled
    const int t = threadIdx.x;
    const int p0 = blockIdx.x * 128;
    const int b = p0 >> 14;
    const int rem = p0 & 16383;
    const float* xb = out + ((size_t)b << 21) + rem;

    // ---- stage XT from out (xa), coalesced along p
#pragma unroll
    for (int it = 0; it < 8; ++it) {
        const int slot = it * 256 + t;
        const int p = slot & 127, cb = slot >> 7;
        uint4 u;
        {
            const float a0 = xb[(size_t)(cb * 8 + 0) * 16384 + p];
            const float a1 = xb[(size_t)(cb * 8 + 1) * 16384 + p];
            const float a2 = xb[(size_t)(cb * 8 + 2) * 16384 + p];
            const float a3 = xb[(size_t)(cb * 8 + 3) * 16384 + p];
            const float a4 = xb[(size_t)(cb * 8 + 4) * 16384 + p];
            const float a5 = xb[(size_t)(cb * 8 + 5) * 16384 + p];
            const float a6 = xb[(size_t)(cb * 8 + 6) * 16384 + p];
            const float a7 = xb[(size_t)(cb * 8 + 7) * 16384 + p];
            u.x = pack2(a0, a1); u.y = pack2(a2, a3);
            u.z = pack2(a4, a5); u.w = pack2(a6, a7);
        }
        *(uint4*)&XT[p * 128 + ((cb ^ (p & 7)) << 3)] = u;
    }
    // ---- stage WT from pw (128x128), coalesced along j
#pragma unroll
    for (int it = 0; it < 8; ++it) {
        const int slot = it * 256 + t;
        const int j = slot & 127, cb = slot >> 7;
        uint4 u;
        {
            const float a0 = pw[(size_t)(cb * 8 + 0) * 128 + j];
            const float a1 = pw[(size_t)(cb * 8 + 1) * 128 + j];
            const float a2 = pw[(size_t)(cb * 8 + 2) * 128 + j];
            const float a3 = pw[(size_t)(cb * 8 + 3) * 128 + j];
            const float a4 = pw[(size_t)(cb * 8 + 4) * 128 + j];
            const float a5 = pw[(size_t)(cb * 8 + 5) * 128 + j];
            const float a6 = pw[(size_t)(cb * 8 + 6) * 128 + j];
            const float a7 = pw[(size_t)(cb * 8 + 7) * 128 + j];
            u.x = pack2(a0, a1); u.y = pack2(a2, a3);
            u.z = pack2(a4, a5); u.w = pack2(a6, a7);
        }
        *(uint4*)&WT[j * 128 + ((cb ^ (j & 7)) << 3)] = u;
    }
    __syncthreads();   // all global reads of this block's pixels complete here

    const int l = t & 63, wv = t >> 6;
    const int wj = (wv >> 1) * 64, wp = (wv & 1) * 64;
    const int lr = l & 15, lg = l >> 4;

    f32x4 acc[4][4];
#pragma unroll
    for (int i = 0; i < 4; ++i)
#pragma unroll
        for (int j = 0; j < 4; ++j) acc[i][j] = (f32x4){0.f, 0.f, 0.f, 0.f};

#pragma unroll
    for (int ks = 0; ks < 4; ++ks) {
        const int kb = ks * 4 + lg;
        short8 af[4], bf[4];
#pragma unroll
        for (int i = 0; i < 4; ++i) {
            const int jr = wj + i * 16 + lr;
            af[i] = *(const short8*)&WT[jr * 128 + ((kb ^ (jr & 7)) << 3)];
            const int pr = wp + i * 16 + lr;
            bf[i] = *(const short8*)&XT[pr * 128 + ((kb ^ (pr & 7)) << 3)];
        }
#pragma unroll
        for (int ji = 0; ji < 4; ++ji)
#pragma unroll
            for (int pi = 0; pi < 4; ++pi)
                acc[ji][pi] = __builtin_amdgcn_mfma_f32_16x16x32_bf16(
                    af[ji], bf[pi], acc[ji][pi], 0, 0, 0);
    }

    const float rate1 = r1[0];
    float* obase = out + ((size_t)b << 21) + rem;
    // lane holds j = jq..jq+3 at pixel p; stores are 16-lane p-contiguous
#pragma unroll
    for (int ji = 0; ji < 4; ++ji) {
        const int jq = wj + ji * 16 + 4 * lg;
        const float4 bias = *(const float4*)&pb[jq];
#pragma unroll
        for (int pi = 0; pi < 4; ++pi) {
            const int p = wp + pi * 16 + lr;
            float* op = obase + (size_t)jq * 16384 + p;
            op[0]     = rate1 * (acc[ji][pi][0] + bias.x);
            op[16384] = rate1 * (acc[ji][pi][1] + bias.y);
            op[32768] = rate1 * (acc[ji][pi][2] + bias.z);
            op[49152] = rate1 * (acc[ji][pi][3] + bias.w);
        }
    }
}

// ------------------------------------------------------------------
// k_conv5: conv2 structure (direct global qkv reads, no LDS staging
// of raw rows) with HALVED phase count: 4 chunk-pairs of 8 d each,
// uint4 (16B) reads per line-touch instead of uint2 (8B).
// Tile 16 wide x 8 tall (halo 18x10 = 180), 1024 blocks x 256 thr,
// ~63 KB LDS -> 2 blocks/CU.
// ------------------------------------------------------------------
__global__ __launch_bounds__(256) void k_conv5(
    const ushort_t* __restrict__ qkv, const float* __restrict__ fcw,
    const float* __restrict__ fcb, const float* __restrict__ depw,
    const float* __restrict__ depb, const float* __restrict__ r2,
    float* __restrict__ out)
{
    __shared__ float fcl[12960];               // [(ii*8+dd)*180 + pix]
    __shared__ __align__(16) float dwl[2592];  // [kk81][32 oc-in-chunkpair]
    __shared__ float fcwl[108];
    __shared__ float fcbl[9];

    const int t = threadIdx.x;
    const int b = blockIdx.x >> 7, tile = blockIdx.x & 127;
    const int ty0 = (tile >> 3) << 3;          // 16 ty tiles of 8 rows
    const int tx0 = (tile & 7) << 4;           // 8  tx tiles of 16 cols
    if (t < 108) fcwl[t] = fcw[t];
    else if (t < 117) fcbl[t - 108] = fcb[t - 108];
    const float rate2 = r2[0];

    // halo pixel for the fc phase (t < 180 active)
    const int hr = t / 18, hc = t - hr * 18;
    const int gy = ty0 + hr - 1, gx = tx0 + hc - 1;
    const bool inb = (t < 180) && ((unsigned)gy < 128u) && ((unsigned)gx < 128u);
    const int g = inb ? ((b << 14) + gy * 128 + gx) : 0;

    const int op = t & 127, og = t >> 7;       // out pixel, oc-group (16 oc)
    const int py = op >> 4, px = op & 15;
    float* ob = out + ((size_t)b << 21) + (size_t)((ty0 + py) * 128 + tx0 + px);

    const uint4* qkv4 = (const uint4*)qkv;

    for (int cp = 0; cp < 4; ++cp) {           // chunk-pair: d = cp*8 .. cp*8+7
        __syncthreads();   // fcwl/fcbl visible (cp 0) / prior conv reads done

        for (int i = t; i < 2592; i += 256)
            dwl[i] = depw[(cp * 32 + (i & 31)) * 81 + (i >> 5)];

        if (t < 180) {
            float fo[9][8];
#pragma unroll
            for (int ii = 0; ii < 9; ++ii) {
                const float bv = inb ? fcbl[ii] : 0.f;
#pragma unroll
                for (int dd = 0; dd < 8; ++dd) fo[ii][dd] = bv;
            }
            if (inb) {
                const uint4* qp = qkv4 + (size_t)g * 48 + cp;
#pragma unroll
                for (int e = 0; e < 12; ++e) {
                    const uint4 q = qp[e * 4];
                    const float f0 = blo(q.x), f1 = bhi(q.x);
                    const float f2 = blo(q.y), f3 = bhi(q.y);
                    const float f4 = blo(q.z), f5 = bhi(q.z);
                    const float f6 = blo(q.w), f7 = bhi(q.w);
#pragma unroll
                    for (int ii = 0; ii < 9; ++ii) {
                        const float wv = fcwl[ii * 12 + e];
                        fo[ii][0] += wv * f0; fo[ii][1] += wv * f1;
                        fo[ii][2] += wv * f2; fo[ii][3] += wv * f3;
                        fo[ii][4] += wv * f4; fo[ii][5] += wv * f5;
                        fo[ii][6] += wv * f6; fo[ii][7] += wv * f7;
                    }
                }
            }
#pragma unroll
            for (int ii = 0; ii < 9; ++ii)
#pragma unroll
                for (int dd = 0; dd < 8; ++dd)
                    fcl[(ii * 8 + dd) * 180 + t] = fo[ii][dd];
        }
        __syncthreads();

        // conv: thread (op, og) computes oc = cp*32 + og*16 + j, j=0..15
        float a[16];
#pragma unroll
        for (int j = 0; j < 16; ++j) a[j] = 0.f;
#pragma unroll
        for (int ii = 0; ii < 9; ++ii) {
#pragma unroll
            for (int kk = 0; kk < 9; ++kk) {
                const int ky = kk / 3, kx = kk - (kk / 3) * 3;
                const int hp = (py + ky) * 18 + px + kx;
                const float* fp = &fcl[(ii * 8 + og * 4) * 180 + hp];
                const float f0 = fp[0], f1 = fp[180], f2 = fp[360], f3 = fp[540];
                const float4* dw = (const float4*)&dwl[(ii * 9 + kk) * 32 + og * 16];
                const float4 w0 = dw[0], w1 = dw[1], w2 = dw[2], w3 = dw[3];
                a[0]  += f0 * w0.x; a[1]  += f0 * w0.y; a[2]  += f0 * w0.z; a[3]  += f0 * w0.w;
                a[4]  += f1 * w1.x; a[5]  += f1 * w1.y; a[6]  += f1 * w1.z; a[7]  += f1 * w1.w;
                a[8]  += f2 * w2.x; a[9]  += f2 * w2.y; a[10] += f2 * w2.z; a[11] += f2 * w2.w;
                a[12] += f3 * w3.x; a[13] += f3 * w3.y; a[14] += f3 * w3.z; a[15] += f3 * w3.w;
            }
        }
#pragma unroll
        for (int j = 0; j < 16; ++j) {
            const int oc = cp * 32 + og * 16 + j;
            ob[(size_t)oc << 14] += rate2 * (a[j] + depb[oc]);
        }
    }
}

// ==================================================================
// FALLBACK PATH (ws too small): round-5 kernels, verbatim.
// ==================================================================
#define WS_W2  0
#define WS_B2  36864
#define WS_TOT 37152

__global__ __launch_bounds__(256) void k_prep_f(
    const float* __restrict__ qkv_w, const float* __restrict__ qkv_b,
    const float* __restrict__ fcw, const float* __restrict__ fcb,
    float* __restrict__ ws)
{
    const int idx = blockIdx.x * 256 + threadIdx.x;
    if (idx < WS_B2) {
        const int c = idx / 288, r = idx - c * 288, i = r >> 5, d = r & 31;
        float s = 0.f;
#pragma unroll
        for (int e = 0; e < 12; ++e)
            s += fcw[i * 12 + e] * qkv_w[c * 384 + e * 32 + d];
        ws[idx] = s;
    } else if (idx < WS_TOT) {
        const int r = idx - WS_B2, i = r >> 5, d = r & 31;
        float s = fcb[i];
#pragma unroll
        for (int e = 0; e < 12; ++e)
            s += fcw[i * 12 + e] * qkv_b[e * 32 + d];
        ws[idx] = s;
    }
}

__global__ __launch_bounds__(256) void k_attn_f(
    const float* __restrict__ x, const float* __restrict__ qw,
    const float* __restrict__ qb, const float* __restrict__ pw,
    const float* __restrict__ pb, const float* __restrict__ rpb,
    const float* __restrict__ r1, float* __restrict__ out)
{
    __shared__ ushort_t xw[8192];
    __shared__ float arena[8450];
    ushort_t* kvb = (ushort_t*)arena;
    const int t = threadIdx.x;
    const int b = blockIdx.x >> 8, wy = (blockIdx.x >> 4) & 15, wx = blockIdx.x & 15;
    const size_t xbase = ((size_t)b << 21) + (size_t)((wy * 8) * 128 + wx * 8);
    for (int i = t; i < 8192; i += 256) {
        const int c = i >> 6, p = i & 63;
        xw[i] = f2u(x[xbase + (size_t)c * 16384 + (p >> 3) * 128 + (p & 7)]);
    }
    __syncthreads();
    const int h = t >> 6, n = t & 63;
    float qa[32], ka[32], va[32];
#pragma unroll
    for (int cc = 0; cc < 32; ++cc) {
        qa[cc] = qb[h * 32 + cc];
        ka[cc] = qb[128 + h * 32 + cc];
        va[cc] = qb[256 + h * 32 + cc];
    }
    const float* wbase = qw + h * 32;
    for (int c = 0; c < 128; ++c) {
        const float xv = u2f(xw[c * 64 + n]);
        const float* wr = wbase + c * 384;
#pragma unroll
        for (int j = 0; j < 8; ++j) {
            const float4 aq = ((const float4*)wr)[j];
            const float4 ak = ((const float4*)(wr + 128))[j];
            const float4 av = ((const float4*)(wr + 256))[j];
            qa[4 * j + 0] += xv * aq.x; qa[4 * j + 1] += xv * aq.y;
            qa[4 * j + 2] += xv * aq.z; qa[4 * j + 3] += xv * aq.w;
            ka[4 * j + 0] += xv * ak.x; ka[4 * j + 1] += xv * ak.y;
            ka[4 * j + 2] += xv * ak.z; ka[4 * j + 3] += xv * ak.w;
            va[4 * j + 0] += xv * av.x; va[4 * j + 1] += xv * av.y;
            va[4 * j + 2] += xv * av.z; va[4 * j + 3] += xv * av.w;
        }
    }
#pragma unroll
    for (int cc = 0; cc < 32; ++cc) qa[cc] *= SCALE;
    uint_t* kv32 = (uint_t*)kvb;
#pragma unroll
    for (int j = 0; j < 16; ++j) {
        kv32[n * 66 + h * 16 + j] = pack2(ka[2 * j], ka[2 * j + 1]);
        kv32[4224 + n * 66 + h * 16 + j] = pack2(va[2 * j], va[2 * j + 1]);
    }
    __syncthreads();
    const int ry = n >> 3, rx = n & 7;
    float sar[64];
    float mx = -1e30f;
#pragma unroll
    for (int m = 0; m < 64; ++m) {
        const uint2* kr = (const uint2*)(kvb + m * 132 + h * 32);
        float s = 0.f;
#pragma unroll
        for (int j = 0; j < 8; ++j) {
            const uint2 u = kr[j];
            s += qa[4 * j + 0] * blo(u.x) + qa[4 * j + 1] * bhi(u.x)
               + qa[4 * j + 2] * blo(u.y) + qa[4 * j + 3] * bhi(u.y);
        }
        s += rpb[((ry - (m >> 3) + 7) * 15 + (rx - (m & 7) + 7)) * 4 + h];
        sar[m] = s;
        mx = fmaxf(mx, s);
    }
    float l = 0.f;
#pragma unroll
    for (int m = 0; m < 64; ++m) { const float e = __expf(sar[m] - mx); sar[m] = e; l += e; }
    const float inv = 1.f / l;
    float acc[32];
#pragma unroll
    for (int cc = 0; cc < 32; ++cc) acc[cc] = 0.f;
#pragma unroll
    for (int m = 0; m < 64; ++m) {
        const float pm = sar[m];
        const uint2* vr = (const uint2*)(kvb + 8448 + m * 132 + h * 32);
#pragma unroll
        for (int j = 0; j < 8; ++j) {
            const uint2 u = vr[j];
            acc[4 * j + 0] += pm * blo(u.x); acc[4 * j + 1] += pm * bhi(u.x);
            acc[4 * j + 2] += pm * blo(u.y); acc[4 * j + 3] += pm * bhi(u.y);
        }
    }
    __syncthreads();
#pragma unroll
    for (int cc = 0; cc < 32; ++cc) arena[n * 130 + h * 32 + cc] = acc[cc] * inv;
    __syncthreads();
    const int p = t & 63, jb = t >> 6;
    float aj[32];
#pragma unroll
    for (int jj = 0; jj < 32; ++jj) aj[jj] = pb[jb * 32 + jj];
    const float* xr = arena + p * 130;
    const float* pwb = pw + jb * 32;
    for (int c = 0; c < 128; ++c) {
        const float xv = xr[c];
        const float4* pr = (const float4*)(pwb + c * 128);
#pragma unroll
        for (int j = 0; j < 8; ++j) {
            const float4 w4 = pr[j];
            aj[4 * j + 0] += xv * w4.x; aj[4 * j + 1] += xv * w4.y;
            aj[4 * j + 2] += xv * w4.z; aj[4 * j + 3] += xv * w4.w;
        }
    }
    const float rate1 = r1[0];
    const int oy = wy * 8 + (p >> 3), ox = wx * 8 + (p & 7);
    float* ob = out + ((size_t)b << 21) + (size_t)(oy * 128 + ox);
#pragma unroll
    for (int jj = 0; jj < 32; ++jj)
        ob[(size_t)(jb * 32 + jj) << 14] = rate1 * aj[jj];
}

__global__ __launch_bounds__(256) void k_conv_f(
    const float* __restrict__ x, const float* __restrict__ ws,
    const float* __restrict__ depw, const float* __restrict__ depb,
    const float* __restrict__ r2, float* __restrict__ out)
{
    __shared__ float arena[12960];
    __shared__ float b2s[36];
    float* w2l = arena;
    ushort_t* xl = (ushort_t*)(arena + 4608);
    float* fcl = arena;
    float* dwl = arena + 11664;
    const int t = threadIdx.x;
    const int b = blockIdx.x >> 6, tile = blockIdx.x & 63;
    const int ty0 = (tile >> 3) << 4, tx0 = (tile & 7) << 4;
    const size_t xbase = ((size_t)b << 21);
    const float rate2 = r2[0];
    const int py = t >> 4, px = t & 15;
    float* ob = out + ((size_t)b << 21) + (size_t)((ty0 + py) * 128 + (tx0 + px));
    const int r0 = t / 18, c0 = t - r0 * 18;
    const bool ok0 = ((unsigned)(ty0 + r0 - 1) < 128u) && ((unsigned)(tx0 + c0 - 1) < 128u);
    const int t1 = 256 + t, r1i = t1 / 18, c1 = t1 - r1i * 18;
    const bool ok1 = (t < 68) && ((unsigned)(ty0 + r1i - 1) < 128u) && ((unsigned)(tx0 + c1 - 1) < 128u);
    for (int chunk = 0; chunk < 8; ++chunk) {
        __syncthreads();
        for (int i = t; i < 4608; i += 256) {
            const int c = i / 36, r = i - c * 36;
            w2l[i] = ws[WS_W2 + c * 288 + (r >> 2) * 32 + chunk * 4 + (r & 3)];
        }
        if (t < 36) b2s[t] = ws[WS_B2 + (t >> 2) * 32 + chunk * 4 + (t & 3)];
        __syncthreads();
        float fca[2][36];
#pragma unroll
        for (int r = 0; r < 36; ++r) { fca[0][r] = b2s[r]; fca[1][r] = b2s[r]; }
        for (int cs = 0; cs < 8; ++cs) {
            if (cs) __syncthreads();
            for (int i = t; i < 5184; i += 256) {
                const int cc = i / 324, pp = i - cc * 324;
                const int row = pp / 18, col = pp - row * 18;
                const int hy = ty0 + row - 1, hx = tx0 + col - 1;
                ushort_t v = 0;
                if ((unsigned)hy < 128u && (unsigned)hx < 128u)
                    v = f2u(x[xbase + (size_t)(cs * 16 + cc) * 16384 + hy * 128 + hx]);
                xl[i] = v;
            }
            __syncthreads();
#pragma unroll 4
            for (int cc = 0; cc < 16; ++cc) {
                const float xv0 = u2f(xl[cc * 324 + t]);
                const float xv1 = (t < 68) ? u2f(xl[cc * 324 + 256 + t]) : 0.f;
                const float* wr = w2l + (cs * 16 + cc) * 36;
#pragma unroll
                for (int r = 0; r < 36; r += 4) {
                    const float4 w4 = *(const float4*)(wr + r);
                    fca[0][r + 0] += xv0 * w4.x; fca[0][r + 1] += xv0 * w4.y;
                    fca[0][r + 2] += xv0 * w4.z; fca[0][r + 3] += xv0 * w4.w;
                    fca[1][r + 0] += xv1 * w4.x; fca[1][r + 1] += xv1 * w4.y;
                    fca[1][r + 2] += xv1 * w4.z; fca[1][r + 3] += xv1 * w4.w;
                }
            }
        }
        __syncthreads();
#pragma unroll
        for (int r = 0; r < 36; ++r) {
            fcl[r * 324 + t] = ok0 ? fca[0][r] : 0.f;
            if (t < 68) fcl[r * 324 + 256 + t] = ok1 ? fca[1][r] : 0.f;
        }
        for (int i = t; i < 1296; i += 256) {
            const int kk = i >> 4, ocl = i & 15;
            dwl[i] = depw[(chunk * 16 + ocl) * 81 + kk];
        }
        __syncthreads();
        float4 accv[4];
#pragma unroll
        for (int dd = 0; dd < 4; ++dd) accv[dd] = make_float4(0.f, 0.f, 0.f, 0.f);
#pragma unroll
        for (int ii = 0; ii < 9; ++ii) {
#pragma unroll
            for (int kk = 0; kk < 9; ++kk) {
                const int ky = kk / 3, kx = kk - (kk / 3) * 3;
                const int hpix = (py + ky) * 18 + px + kx;
                const float4* dwp = (const float4*)&dwl[(ii * 9 + kk) * 16];
#pragma unroll
                for (int dd = 0; dd < 4; ++dd) {
                    const float f = fcl[(ii * 4 + dd) * 324 + hpix];
                    const float4 d4 = dwp[dd];
                    accv[dd].x += f * d4.x; accv[dd].y += f * d4.y;
                    accv[dd].z += f * d4.z; accv[dd].w += f * d4.w;
                }
            }
        }
#pragma unroll
        for (int dd = 0; dd < 4; ++dd) {
            const float av[4] = {accv[dd].x, accv[dd].y, accv[dd].z, accv[dd].w};
#pragma unroll
            for (int j = 0; j < 4; ++j) {
                const int oc = chunk * 16 + dd * 4 + j;
                ob[(size_t)oc << 14] += rate2 * (av[j] + depb[oc]);
            }
        }
    }
}

// ------------------------------------------------------------------
extern "C" void kernel_launch(void* const* d_in, const int* in_sizes, int n_in,
                              void* d_out, int out_size, void* d_ws, size_t ws_size,
                              hipStream_t stream) {
    (void)in_sizes; (void)n_in; (void)out_size;
    const float* x      = (const float*)d_in[0];
    const float* qkv_w  = (const float*)d_in[1];
    const float* qkv_b  = (const float*)d_in[2];
    const float* proj_w = (const float*)d_in[3];
    const float* proj_b = (const float*)d_in[4];
    const float* rpb    = (const float*)d_in[5];
    const float* fc_w   = (const float*)d_in[6];
    const float* fc_b   = (const float*)d_in[7];
    const float* dep_w  = (const float*)d_in[8];
    const float* dep_b  = (const float*)d_in[9];
    const float* rate1  = (const float*)d_in[10];
    const float* rate2  = (const float*)d_in[11];
    float* out = (float*)d_out;

    if (ws_size >= (size_t)131072 * 384 * 2) {
        ushort_t* qkv = (ushort_t*)d_ws;   // 96 MB bf16
        k_qqkv<<<dim3(1024), dim3(256), 0, stream>>>(x, qkv_w, qkv_b, qkv);
        k_attn3<<<dim3(2048), dim3(256), 0, stream>>>(qkv, rpb, out);
        k_proj<<<dim3(1024), dim3(256), 0, stream>>>(proj_w, proj_b, rate1, out);
        k_conv5<<<dim3(1024), dim3(256), 0, stream>>>(qkv, fc_w, fc_b, dep_w,
                                                      dep_b, rate2, out);
    } else {
        float* wsf = (float*)d_ws;         // 148.6 KB
        k_prep_f<<<dim3(146), dim3(256), 0, stream>>>(qkv_w, qkv_b, fc_w, fc_b, wsf);
        k_attn_f<<<dim3(2048), dim3(256), 0, stream>>>(x, qkv_w, qkv_b, proj_w,
                                                       proj_b, rpb, rate1, out);
        k_conv_f<<<dim3(512), dim3(256), 0, stream>>>(x, wsf, dep_w, dep_b,
                                                      rate2, out);
    }
}

// Round 10
// 433.201 us; speedup vs baseline: 1.4854x; 1.2367x over previous
//
#include <hip/hip_runtime.h>

typedef unsigned short ushort_t;
typedef unsigned int uint_t;
typedef __attribute__((ext_vector_type(8))) short short8;
typedef __attribute__((ext_vector_type(4))) float f32x4;

#define SCALE 0.17677669529663687f

__device__ __forceinline__ float blo(uint_t u) { return __uint_as_float(u << 16); }
__device__ __forceinline__ float bhi(uint_t u) { return __uint_as_float(u & 0xffff0000u); }
__device__ __forceinline__ float u2f(ushort_t u) { return __uint_as_float(((uint_t)u) << 16); }
// fp32 -> bf16 (RNE), finite inputs
__device__ __forceinline__ ushort_t f2u(float f) {
    const uint_t x = __float_as_uint(f);
    return (ushort_t)((x + 0x7fffu + ((x >> 16) & 1u)) >> 16);
}
__device__ __forceinline__ uint_t pack2(float a, float b) {
    return (uint_t)f2u(a) | ((uint_t)f2u(b) << 16);
}

__device__ __forceinline__ float dot8(const float* qa, uint4 u) {
    return qa[0] * blo(u.x) + qa[1] * bhi(u.x) + qa[2] * blo(u.y) + qa[3] * bhi(u.y)
         + qa[4] * blo(u.z) + qa[5] * bhi(u.z) + qa[6] * blo(u.w) + qa[7] * bhi(u.w);
}
__device__ __forceinline__ void pv8(float* a, float e, uint4 u) {
    a[0] += e * blo(u.x); a[1] += e * bhi(u.x); a[2] += e * blo(u.y); a[3] += e * bhi(u.y);
    a[4] += e * blo(u.z); a[5] += e * bhi(u.z); a[6] += e * blo(u.w); a[7] += e * bhi(u.w);
}

// ==================================================================
// MAIN PATH: qkv materialized in ws as bf16 [p][j], p=131072, j=384.
// Requires ws_size >= 96 MB.
// ==================================================================

// ------------------------------------------------------------------
// k_qqkv (MFMA): qkv[p, j] = bf16( sum_c x[b,c,p]*qkv_w[c,j] + qkv_b[j] )
// Block = 128 pixels x all 384 j (3 j-tiles of 128), K=128.
// ------------------------------------------------------------------
__global__ __launch_bounds__(256) void k_qqkv(
    const float* __restrict__ x, const float* __restrict__ w,
    const float* __restrict__ wb, ushort_t* __restrict__ qkv)
{
    __shared__ ushort_t XT[128 * 128];  // [p][c] swizzled
    __shared__ ushort_t WT[128 * 128];  // [j][c] swizzled; reused as D [p][j]
    const int t = threadIdx.x;
    const int p0 = blockIdx.x * 128;
    const int b = p0 >> 14;             // HW = 16384
    const int rem = p0 & 16383;
    const float* xb = x + ((size_t)b << 21) + rem;

    // ---- stage XT: x[c][p] -> bf16 XT[p][c] (coalesced reads along p)
#pragma unroll
    for (int it = 0; it < 8; ++it) {
        const int slot = it * 256 + t;
        const int p = slot & 127, cb = slot >> 7;   // cb = 16B block along c
        uint4 u;
        {
            const float a0 = xb[(size_t)(cb * 8 + 0) * 16384 + p];
            const float a1 = xb[(size_t)(cb * 8 + 1) * 16384 + p];
            const float a2 = xb[(size_t)(cb * 8 + 2) * 16384 + p];
            const float a3 = xb[(size_t)(cb * 8 + 3) * 16384 + p];
            const float a4 = xb[(size_t)(cb * 8 + 4) * 16384 + p];
            const float a5 = xb[(size_t)(cb * 8 + 5) * 16384 + p];
            const float a6 = xb[(size_t)(cb * 8 + 6) * 16384 + p];
            const float a7 = xb[(size_t)(cb * 8 + 7) * 16384 + p];
            u.x = pack2(a0, a1); u.y = pack2(a2, a3);
            u.z = pack2(a4, a5); u.w = pack2(a6, a7);
        }
        *(uint4*)&XT[p * 128 + ((cb ^ (p & 7)) << 3)] = u;
    }

    const int l = t & 63, wv = t >> 6;
    const int wj = (wv >> 1) * 64, wp = (wv & 1) * 64;
    const int lr = l & 15, lg = l >> 4;

    for (int jt = 0; jt < 3; ++jt) {
        const int j0 = jt * 128;
        __syncthreads();   // XT ready (jt=0) / prior D drained (jt>0)

        // ---- stage WT: w[c][j0+j] -> bf16 WT[j][c] (coalesced along j; L2-hot)
#pragma unroll
        for (int it = 0; it < 8; ++it) {
            const int slot = it * 256 + t;
            const int j = slot & 127, cb = slot >> 7;
            uint4 u;
            {
                const float a0 = w[(size_t)(cb * 8 + 0) * 384 + j0 + j];
                const float a1 = w[(size_t)(cb * 8 + 1) * 384 + j0 + j];
                const float a2 = w[(size_t)(cb * 8 + 2) * 384 + j0 + j];
                const float a3 = w[(size_t)(cb * 8 + 3) * 384 + j0 + j];
                const float a4 = w[(size_t)(cb * 8 + 4) * 384 + j0 + j];
                const float a5 = w[(size_t)(cb * 8 + 5) * 384 + j0 + j];
                const float a6 = w[(size_t)(cb * 8 + 6) * 384 + j0 + j];
                const float a7 = w[(size_t)(cb * 8 + 7) * 384 + j0 + j];
                u.x = pack2(a0, a1); u.y = pack2(a2, a3);
                u.z = pack2(a4, a5); u.w = pack2(a6, a7);
            }
            *(uint4*)&WT[j * 128 + ((cb ^ (j & 7)) << 3)] = u;
        }
        __syncthreads();

        f32x4 acc[4][4];
#pragma unroll
        for (int i = 0; i < 4; ++i)
#pragma unroll
            for (int j = 0; j < 4; ++j) acc[i][j] = (f32x4){0.f, 0.f, 0.f, 0.f};

#pragma unroll
        for (int ks = 0; ks < 4; ++ks) {
            const int kb = ks * 4 + lg;
            short8 af[4], bf[4];
#pragma unroll
            for (int i = 0; i < 4; ++i) {
                const int jr = wj + i * 16 + lr;
                af[i] = *(const short8*)&WT[jr * 128 + ((kb ^ (jr & 7)) << 3)];
                const int pr = wp + i * 16 + lr;
                bf[i] = *(const short8*)&XT[pr * 128 + ((kb ^ (pr & 7)) << 3)];
            }
#pragma unroll
            for (int ji = 0; ji < 4; ++ji)
#pragma unroll
                for (int pi = 0; pi < 4; ++pi)
                    acc[ji][pi] = __builtin_amdgcn_mfma_f32_16x16x32_bf16(
                        af[ji], bf[pi], acc[ji][pi], 0, 0, 0);
        }
        __syncthreads();   // all WT reads done before D overwrite

        // ---- D write: lane holds 4 consecutive j at fixed p per acc tile
#pragma unroll
        for (int ji = 0; ji < 4; ++ji) {
            const int jq = wj + ji * 16 + 4 * lg;            // local j quad base
            const float4 bias = *(const float4*)&wb[j0 + jq];
#pragma unroll
            for (int pi = 0; pi < 4; ++pi) {
                const int p = wp + pi * 16 + lr;
                uint2 o;
                o.x = pack2(acc[ji][pi][0] + bias.x, acc[ji][pi][1] + bias.y);
                o.y = pack2(acc[ji][pi][2] + bias.z, acc[ji][pi][3] + bias.w);
                *(uint2*)&WT[p * 128 + (((jq >> 3) ^ (p & 7)) << 3) + (jq & 7)] = o;
            }
        }
        __syncthreads();

        // ---- copy D -> qkv, coalesced 16B writes (lanes sweep j)
#pragma unroll
        for (int it = 0; it < 8; ++it) {
            const int slot = it * 256 + t;
            const int seg = slot & 15, p = slot >> 4;
            const uint4 v = *(const uint4*)&WT[p * 128 + ((seg ^ (p & 7)) << 3)];
            *(uint4*)&qkv[(size_t)(p0 + p) * 384 + j0 + seg * 8] = v;
        }
    }
}

// ------------------------------------------------------------------
// k_attn4 (MFMA attention): per 8x8 window, wave = head.
// S = mfma(A=K rows m, B=Q rows n) -> S[col=n=lane&15][row=m=4*lg+r].
// Row softmax via 16 local vals + shfl_xor(16/32). P -> bf16 in LDS
// (aliases dead Q/K region). O = mfma(A=V^T rows d, B=P rows n).
// Writes raw xa (fp32, channel-major) into out; k_proj follows.
// ------------------------------------------------------------------
__global__ __launch_bounds__(256) void k_attn4(
    const ushort_t* __restrict__ qkv, const float* __restrict__ rpb,
    float* __restrict__ out)
{
    // uints: Q[0,4352) K[4352,8704) VT[8704,13056) rpb[13056,13956)
    // P aliases [0,8704): head h at h*2176, row stride 34 uints (68 sh).
    __shared__ uint_t lds[13956];
    ushort_t* lds_sh = (ushort_t*)lds;
    float* rpbl = (float*)(lds + 13056);
    const int t = threadIdx.x;
    const int b = blockIdx.x >> 8, wy = (blockIdx.x >> 4) & 15, wx = blockIdx.x & 15;
    const int prow0 = (b << 14) + (wy * 8) * 128 + wx * 8;
    const uint_t* qkvu = (const uint_t*)qkv;

    // ---- stage Q,K rows (68-uint stride) + V transposed (VT[d][m])
    for (int i = t; i < 4096; i += 256) {
        const int m = i >> 6, u = i & 63;
        const size_t pr = (size_t)(prow0 + (m >> 3) * 128 + (m & 7)) * 192;
        lds[m * 68 + u]        = qkvu[pr + u];
        lds[4352 + m * 68 + u] = qkvu[pr + 64 + u];
        const uint_t v = qkvu[pr + 128 + u];
        lds_sh[17408 + (2 * u) * 68 + m]     = (ushort_t)(v & 0xffffu);
        lds_sh[17408 + (2 * u + 1) * 68 + m] = (ushort_t)(v >> 16);
    }
    for (int i = t; i < 900; i += 256) rpbl[i] = rpb[i];
    __syncthreads();

    const int h = t >> 6, l = t & 63;
    const int lr = l & 15, lg = l >> 4;

    // ---- QK^T: 16 MFMAs
    short8 af_k[4], bf_q[4];
#pragma unroll
    for (int i = 0; i < 4; ++i) {
        af_k[i] = *(const short8*)&lds_sh[8704 + (i * 16 + lr) * 136 + h * 32 + lg * 8];
        bf_q[i] = *(const short8*)&lds_sh[(i * 16 + lr) * 136 + h * 32 + lg * 8];
    }
    f32x4 sA[4][4];   // [nt][mt]
#pragma unroll
    for (int nt = 0; nt < 4; ++nt)
#pragma unroll
        for (int mt = 0; mt < 4; ++mt)
            sA[nt][mt] = __builtin_amdgcn_mfma_f32_16x16x32_bf16(
                af_k[mt], bf_q[nt], (f32x4){0.f, 0.f, 0.f, 0.f}, 0, 0, 0);

    // ---- softmax per row n (lane owns n = nt*16+lr; m split over lg)
    float inv[4];
#pragma unroll
    for (int nt = 0; nt < 4; ++nt) {
        const int n = nt * 16 + lr;
        const int ry = n >> 3, rx = n & 7;
        float mxv = -1e30f;
#pragma unroll
        for (int mt = 0; mt < 4; ++mt)
#pragma unroll
            for (int r = 0; r < 4; ++r) {
                const int m = mt * 16 + lg * 4 + r;
                const float bias =
                    rpbl[((ry - (m >> 3) + 7) * 15 + (rx - (m & 7) + 7)) * 4 + h];
                const float s = sA[nt][mt][r] * SCALE + bias;
                sA[nt][mt][r] = s;
                mxv = fmaxf(mxv, s);
            }
        mxv = fmaxf(mxv, __shfl_xor(mxv, 16));
        mxv = fmaxf(mxv, __shfl_xor(mxv, 32));
        float ls = 0.f;
#pragma unroll
        for (int mt = 0; mt < 4; ++mt)
#pragma unroll
            for (int r = 0; r < 4; ++r) {
                const float e = __expf(sA[nt][mt][r] - mxv);
                sA[nt][mt][r] = e;
                ls += e;
            }
        ls += __shfl_xor(ls, 16);
        ls += __shfl_xor(ls, 32);
        inv[nt] = 1.f / ls;
    }

    __syncthreads();   // all waves done reading Q/K before P overwrites

    // ---- P (bf16) into LDS, row n stride 34 uints
    uint_t* Pb = lds + h * 2176;
#pragma unroll
    for (int nt = 0; nt < 4; ++nt) {
        const int n = nt * 16 + lr;
#pragma unroll
        for (int mt = 0; mt < 4; ++mt) {
            uint2 o;
            o.x = pack2(sA[nt][mt][0], sA[nt][mt][1]);
            o.y = pack2(sA[nt][mt][2], sA[nt][mt][3]);
            *(uint2*)&Pb[n * 34 + mt * 8 + lg * 2] = o;
        }
    }
    asm volatile("s_waitcnt lgkmcnt(0)" ::: "memory");

    // ---- PV: O = mfma(A=VT rows d, B=P rows n), K=64 (2 steps)
    union U8 { short8 s8; uint2 u2[2]; };
    f32x4 oA[2][4];
#pragma unroll
    for (int dt = 0; dt < 2; ++dt)
#pragma unroll
        for (int nt = 0; nt < 4; ++nt) oA[dt][nt] = (f32x4){0.f, 0.f, 0.f, 0.f};
#pragma unroll
    for (int ks = 0; ks < 2; ++ks) {
        const int kb = ks * 4 + lg;
        short8 av[2], bp[4];
#pragma unroll
        for (int dt = 0; dt < 2; ++dt) {
            U8 u;
            const int d = h * 32 + dt * 16 + lr;
            u.u2[0] = *(const uint2*)&lds[8704 + d * 34 + kb * 4];
            u.u2[1] = *(const uint2*)&lds[8704 + d * 34 + kb * 4 + 2];
            av[dt] = u.s8;
        }
#pragma unroll
        for (int nt = 0; nt < 4; ++nt) {
            U8 u;
            const int n = nt * 16 + lr;
            u.u2[0] = *(const uint2*)&Pb[n * 34 + kb * 4];
            u.u2[1] = *(const uint2*)&Pb[n * 34 + kb * 4 + 2];
            bp[nt] = u.s8;
        }
#pragma unroll
        for (int dt = 0; dt < 2; ++dt)
#pragma unroll
            for (int nt = 0; nt < 4; ++nt)
                oA[dt][nt] = __builtin_amdgcn_mfma_f32_16x16x32_bf16(
                    av[dt], bp[nt], oA[dt][nt], 0, 0, 0);
    }

    // ---- write raw xa channel-major: out[b][h*32+d][pix(n)]
    float* ob = out + ((size_t)b << 21);
    const int pixbase = (wy * 8) * 128 + wx * 8;
#pragma unroll
    for (int dt = 0; dt < 2; ++dt)
#pragma unroll
        for (int nt = 0; nt < 4; ++nt) {
            const int n = nt * 16 + lr;
            const size_t po = (size_t)(pixbase + (n >> 3) * 128 + (n & 7));
            const float iv = inv[nt];
#pragma unroll
            for (int r = 0; r < 4; ++r) {
                const int d = h * 32 + dt * 16 + lg * 4 + r;
                ob[((size_t)d << 14) + po] = oA[dt][nt][r] * iv;
            }
        }
}

// ------------------------------------------------------------------
// k_proj (MFMA, in-place on out): out[b][j][p] =
//    rate1 * ( sum_c xa[b][c][p] * pw[c][j] + pb[j] ), xa = current out.
// ------------------------------------------------------------------
__global__ __launch_bounds__(256) void k_proj(
    const float* __restrict__ pw, const float* __restrict__ pb,
    const float* __restrict__ r1, float* __restrict__ out)
{
    __shared__ ushort_t XT[128 * 128];  // xa^T [p][c] swizzled
    __shared__ ushort_t WT[128 * 128];  // pw^T [j][c] swizzled
    const int t = threadIdx.x;
    const int p0 = blockIdx.x * 128;
    const int b = p0 >> 14;
    const int rem = p0 & 16383;
    const float* xb = out + ((size_t)b << 21) + rem;

    // ---- stage XT from out (xa), coalesced along p
#pragma unroll
    for (int it = 0; it < 8; ++it) {
        const int slot = it * 256 + t;
        const int p = slot & 127, cb = slot >> 7;
        uint4 u;
        {
            const float a0 = xb[(size_t)(cb * 8 + 0) * 16384 + p];
            const float a1 = xb[(size_t)(cb * 8 + 1) * 16384 + p];
            const float a2 = xb[(size_t)(cb * 8 + 2) * 16384 + p];
            const float a3 = xb[(size_t)(cb * 8 + 3) * 16384 + p];
            const float a4 = xb[(size_t)(cb * 8 + 4) * 16384 + p];
            const float a5 = xb[(size_t)(cb * 8 + 5) * 16384 + p];
            const float a6 = xb[(size_t)(cb * 8 + 6) * 16384 + p];
            const float a7 = xb[(size_t)(cb * 8 + 7) * 16384 + p];
            u.x = pack2(a0, a1); u.y = pack2(a2, a3);
            u.z = pack2(a4, a5); u.w = pack2(a6, a7);
        }
        *(uint4*)&XT[p * 128 + ((cb ^ (p & 7)) << 3)] = u;
    }
    // ---- stage WT from pw (128x128), coalesced along j
#pragma unroll
    for (int it = 0; it < 8; ++it) {
        const int slot = it * 256 + t;
        const int j = slot & 127, cb = slot >> 7;
        uint4 u;
        {
            const float a0 = pw[(size_t)(cb * 8 + 0) * 128 + j];
            const float a1 = pw[(size_t)(cb * 8 + 1) * 128 + j];
            const float a2 = pw[(size_t)(cb * 8 + 2) * 128 + j];
            const float a3 = pw[(size_t)(cb * 8 + 3) * 128 + j];
            const float a4 = pw[(size_t)(cb * 8 + 4) * 128 + j];
            const float a5 = pw[(size_t)(cb * 8 + 5) * 128 + j];
            const float a6 = pw[(size_t)(cb * 8 + 6) * 128 + j];
            const float a7 = pw[(size_t)(cb * 8 + 7) * 128 + j];
            u.x = pack2(a0, a1); u.y = pack2(a2, a3);
            u.z = pack2(a4, a5); u.w = pack2(a6, a7);
        }
        *(uint4*)&WT[j * 128 + ((cb ^ (j & 7)) << 3)] = u;
    }
    __syncthreads();   // all global reads of this block's pixels complete here

    const int l = t & 63, wv = t >> 6;
    const int wj = (wv >> 1) * 64, wp = (wv & 1) * 64;
    const int lr = l & 15, lg = l >> 4;

    f32x4 acc[4][4];
#pragma unroll
    for (int i = 0; i < 4; ++i)
#pragma unroll
        for (int j = 0; j < 4; ++j) acc[i][j] = (f32x4){0.f, 0.f, 0.f, 0.f};

#pragma unroll
    for (int ks = 0; ks < 4; ++ks) {
        const int kb = ks * 4 + lg;
        short8 af[4], bf[4];
#pragma unroll
        for (int i = 0; i < 4; ++i) {
            const int jr = wj + i * 16 + lr;
            af[i] = *(const short8*)&WT[jr * 128 + ((kb ^ (jr & 7)) << 3)];
            const int pr = wp + i * 16 + lr;
            bf[i] = *(const short8*)&XT[pr * 128 + ((kb ^ (pr & 7)) << 3)];
        }
#pragma unroll
        for (int ji = 0; ji < 4; ++ji)
#pragma unroll
            for (int pi = 0; pi < 4; ++pi)
                acc[ji][pi] = __builtin_amdgcn_mfma_f32_16x16x32_bf16(
                    af[ji], bf[pi], acc[ji][pi], 0, 0, 0);
    }

    const float rate1 = r1[0];
    float* obase = out + ((size_t)b << 21) + rem;
    // lane holds j = jq..jq+3 at pixel p; stores are 16-lane p-contiguous
#pragma unroll
    for (int ji = 0; ji < 4; ++ji) {
        const int jq = wj + ji * 16 + 4 * lg;
        const float4 bias = *(const float4*)&pb[jq];
#pragma unroll
        for (int pi = 0; pi < 4; ++pi) {
            const int p = wp + pi * 16 + lr;
            float* op = obase + (size_t)jq * 16384 + p;
            op[0]     = rate1 * (acc[ji][pi][0] + bias.x);
            op[16384] = rate1 * (acc[ji][pi][1] + bias.y);
            op[32768] = rate1 * (acc[ji][pi][2] + bias.z);
            op[49152] = rate1 * (acc[ji][pi][3] + bias.w);
        }
    }
}

// ------------------------------------------------------------------
// k_conv2 (RESTORED round-6 version, measured 189 us): per 16x16
// tile, 8 chunks of 4 d; direct global qkv reads; RMW out.
// ------------------------------------------------------------------
__global__ __launch_bounds__(256) void k_conv2(
    const ushort_t* __restrict__ qkv, const float* __restrict__ fcw,
    const float* __restrict__ fcb, const float* __restrict__ depw,
    const float* __restrict__ depb, const float* __restrict__ r2,
    float* __restrict__ out)
{
    __shared__ float fcl[11664];    // [(ii*4+dd)*324 + pix]
    __shared__ __align__(16) float dwl[1296];   // [kk81][16 oc-in-chunk]
    __shared__ float fcwl[108];
    __shared__ float fcbl[9];

    const int t = threadIdx.x;
    const int b = blockIdx.x >> 6, tile = blockIdx.x & 63;
    const int ty0 = (tile >> 3) << 4, tx0 = (tile & 7) << 4;
    if (t < 108) fcwl[t] = fcw[t];
    if (t < 9)   fcbl[t] = fcb[t];
    const float rate2 = r2[0];
    const int py = t >> 4, px = t & 15;
    float* ob = out + ((size_t)b << 21) + (size_t)((ty0 + py) * 128 + (tx0 + px));

    // this thread's halo pixels: pix0 = t, pix1 = 256+t (t<68)
    const int row0 = t / 18, col0 = t - row0 * 18;
    const int hy0 = ty0 + row0 - 1, hx0 = tx0 + col0 - 1;
    const int g0 = ((unsigned)hy0 < 128u && (unsigned)hx0 < 128u)
                       ? ((b << 14) + hy0 * 128 + hx0) : -1;
    const int t1 = t + 256, row1 = t1 / 18, col1 = t1 - row1 * 18;
    const int hy1 = ty0 + row1 - 1, hx1 = tx0 + col1 - 1;
    const int g1 = (t < 68 && (unsigned)hy1 < 128u && (unsigned)hx1 < 128u)
                       ? ((b << 14) + hy1 * 128 + hx1) : -1;

    for (int chunk = 0; chunk < 8; ++chunk) {
        __syncthreads();   // fcwl visible (chunk 0) / prior conv reads done
        for (int i = t; i < 1296; i += 256)
            dwl[i] = depw[(chunk * 16 + (i & 15)) * 81 + (i >> 4)];

#pragma unroll
        for (int half = 0; half < 2; ++half) {
            const int g = half ? g1 : g0;
            const int pix = half ? (256 + t) : t;
            if (half && t >= 68) break;
            float fo[9][4];
#pragma unroll
            for (int ii = 0; ii < 9; ++ii) {
                const float bv = (g >= 0) ? fcbl[ii] : 0.f;
                fo[ii][0] = bv; fo[ii][1] = bv; fo[ii][2] = bv; fo[ii][3] = bv;
            }
            if (g >= 0) {
                const uint2* qp = (const uint2*)(qkv + (size_t)g * 384 + chunk * 4);
#pragma unroll
                for (int e = 0; e < 12; ++e) {
                    const uint2 q = qp[e * 8];
                    const float f0 = blo(q.x), f1 = bhi(q.x);
                    const float f2 = blo(q.y), f3 = bhi(q.y);
#pragma unroll
                    for (int ii = 0; ii < 9; ++ii) {
                        const float wv = fcwl[ii * 12 + e];
                        fo[ii][0] += wv * f0; fo[ii][1] += wv * f1;
                        fo[ii][2] += wv * f2; fo[ii][3] += wv * f3;
                    }
                }
            }
#pragma unroll
            for (int ii = 0; ii < 9; ++ii)
#pragma unroll
                for (int dd = 0; dd < 4; ++dd)
                    fcl[(ii * 4 + dd) * 324 + pix] = fo[ii][dd];
        }
        __syncthreads();

        float4 accv[4];
#pragma unroll
        for (int dd = 0; dd < 4; ++dd) accv[dd] = make_float4(0.f, 0.f, 0.f, 0.f);
#pragma unroll
        for (int ii = 0; ii < 9; ++ii) {
#pragma unroll
            for (int kk = 0; kk < 9; ++kk) {
                const int ky = kk / 3, kx = kk - (kk / 3) * 3;
                const int hpix = (py + ky) * 18 + px + kx;
                const float4* dwp = (const float4*)&dwl[(ii * 9 + kk) * 16];
#pragma unroll
                for (int dd = 0; dd < 4; ++dd) {
                    const float f = fcl[(ii * 4 + dd) * 324 + hpix];
                    const float4 d4 = dwp[dd];
                    accv[dd].x += f * d4.x; accv[dd].y += f * d4.y;
                    accv[dd].z += f * d4.z; accv[dd].w += f * d4.w;
                }
            }
        }
#pragma unroll
        for (int dd = 0; dd < 4; ++dd) {
            const float av[4] = {accv[dd].x, accv[dd].y, accv[dd].z, accv[dd].w};
#pragma unroll
            for (int j = 0; j < 4; ++j) {
                const int oc = chunk * 16 + dd * 4 + j;
                ob[(size_t)oc << 14] += rate2 * (av[j] + depb[oc]);
            }
        }
    }
}

// ==================================================================
// FALLBACK PATH (ws too small): round-5 kernels, verbatim.
// ==================================================================
#define WS_W2  0
#define WS_B2  36864
#define WS_TOT 37152

__global__ __launch_bounds__(256) void k_prep_f(
    const float* __restrict__ qkv_w, const float* __restrict__ qkv_b,
    const float* __restrict__ fcw, const float* __restrict__ fcb,
    float* __restrict__ ws)
{
    const int idx = blockIdx.x * 256 + threadIdx.x;
    if (idx < WS_B2) {
        const int c = idx / 288, r = idx - c * 288, i = r >> 5, d = r & 31;
        float s = 0.f;
#pragma unroll
        for (int e = 0; e < 12; ++e)
            s += fcw[i * 12 + e] * qkv_w[c * 384 + e * 32 + d];
        ws[idx] = s;
    } else if (idx < WS_TOT) {
        const int r = idx - WS_B2, i = r >> 5, d = r & 31;
        float s = fcb[i];
#pragma unroll
        for (int e = 0; e < 12; ++e)
            s += fcw[i * 12 + e] * qkv_b[e * 32 + d];
        ws[idx] = s;
    }
}

__global__ __launch_bounds__(256) void k_attn_f(
    const float* __restrict__ x, const float* __restrict__ qw,
    const float* __restrict__ qb, const float* __restrict__ pw,
    const float* __restrict__ pb, const float* __restrict__ rpb,
    const float* __restrict__ r1, float* __restrict__ out)
{
    __shared__ ushort_t xw[8192];
    __shared__ float arena[8450];
    ushort_t* kvb = (ushort_t*)arena;
    const int t = threadIdx.x;
    const int b = blockIdx.x >> 8, wy = (blockIdx.x >> 4) & 15, wx = blockIdx.x & 15;
    const size_t xbase = ((size_t)b << 21) + (size_t)((wy * 8) * 128 + wx * 8);
    for (int i = t; i < 8192; i += 256) {
        const int c = i >> 6, p = i & 63;
        xw[i] = f2u(x[xbase + (size_t)c * 16384 + (p >> 3) * 128 + (p & 7)]);
    }
    __syncthreads();
    const int h = t >> 6, n = t & 63;
    float qa[32], ka[32], va[32];
#pragma unroll
    for (int cc = 0; cc < 32; ++cc) {
        qa[cc] = qb[h * 32 + cc];
        ka[cc] = qb[128 + h * 32 + cc];
        va[cc] = qb[256 + h * 32 + cc];
    }
    const float* wbase = qw + h * 32;
    for (int c = 0; c < 128; ++c) {
        const float xv = u2f(xw[c * 64 + n]);
        const float* wr = wbase + c * 384;
#pragma unroll
        for (int j = 0; j < 8; ++j) {
            const float4 aq = ((const float4*)wr)[j];
            const float4 ak = ((const float4*)(wr + 128))[j];
            const float4 av = ((const float4*)(wr + 256))[j];
            qa[4 * j + 0] += xv * aq.x; qa[4 * j + 1] += xv * aq.y;
            qa[4 * j + 2] += xv * aq.z; qa[4 * j + 3] += xv * aq.w;
            ka[4 * j + 0] += xv * ak.x; ka[4 * j + 1] += xv * ak.y;
            ka[4 * j + 2] += xv * ak.z; ka[4 * j + 3] += xv * ak.w;
            va[4 * j + 0] += xv * av.x; va[4 * j + 1] += xv * av.y;
            va[4 * j + 2] += xv * av.z; va[4 * j + 3] += xv * av.w;
        }
    }
#pragma unroll
    for (int cc = 0; cc < 32; ++cc) qa[cc] *= SCALE;
    uint_t* kv32 = (uint_t*)kvb;
#pragma unroll
    for (int j = 0; j < 16; ++j) {
        kv32[n * 66 + h * 16 + j] = pack2(ka[2 * j], ka[2 * j + 1]);
        kv32[4224 + n * 66 + h * 16 + j] = pack2(va[2 * j], va[2 * j + 1]);
    }
    __syncthreads();
    const int ry = n >> 3, rx = n & 7;
    float sar[64];
    float mx = -1e30f;
#pragma unroll
    for (int m = 0; m < 64; ++m) {
        const uint2* kr = (const uint2*)(kvb + m * 132 + h * 32);
        float s = 0.f;
#pragma unroll
        for (int j = 0; j < 8; ++j) {
            const uint2 u = kr[j];
            s += qa[4 * j + 0] * blo(u.x) + qa[4 * j + 1] * bhi(u.x)
               + qa[4 * j + 2] * blo(u.y) + qa[4 * j + 3] * bhi(u.y);
        }
        s += rpb[((ry - (m >> 3) + 7) * 15 + (rx - (m & 7) + 7)) * 4 + h];
        sar[m] = s;
        mx = fmaxf(mx, s);
    }
    float l = 0.f;
#pragma unroll
    for (int m = 0; m < 64; ++m) { const float e = __expf(sar[m] - mx); sar[m] = e; l += e; }
    const float inv = 1.f / l;
    float acc[32];
#pragma unroll
    for (int cc = 0; cc < 32; ++cc) acc[cc] = 0.f;
#pragma unroll
    for (int m = 0; m < 64; ++m) {
        const float pm = sar[m];
        const uint2* vr = (const uint2*)(kvb + 8448 + m * 132 + h * 32);
#pragma unroll
        for (int j = 0; j < 8; ++j) {
            const uint2 u = vr[j];
            acc[4 * j + 0] += pm * blo(u.x); acc[4 * j + 1] += pm * bhi(u.x);
            acc[4 * j + 2] += pm * blo(u.y); acc[4 * j + 3] += pm * bhi(u.y);
        }
    }
    __syncthreads();
#pragma unroll
    for (int cc = 0; cc < 32; ++cc) arena[n * 130 + h * 32 + cc] = acc[cc] * inv;
    __syncthreads();
    const int p = t & 63, jb = t >> 6;
    float aj[32];
#pragma unroll
    for (int jj = 0; jj < 32; ++jj) aj[jj] = pb[jb * 32 + jj];
    const float* xr = arena + p * 130;
    const float* pwb = pw + jb * 32;
    for (int c = 0; c < 128; ++c) {
        const float xv = xr[c];
        const float4* pr = (const float4*)(pwb + c * 128);
#pragma unroll
        for (int j = 0; j < 8; ++j) {
            const float4 w4 = pr[j];
            aj[4 * j + 0] += xv * w4.x; aj[4 * j + 1] += xv * w4.y;
            aj[4 * j + 2] += xv * w4.z; aj[4 * j + 3] += xv * w4.w;
        }
    }
    const float rate1 = r1[0];
    const int oy = wy * 8 + (p >> 3), ox = wx * 8 + (p & 7);
    float* ob = out + ((size_t)b << 21) + (size_t)(oy * 128 + ox);
#pragma unroll
    for (int jj = 0; jj < 32; ++jj)
        ob[(size_t)(jb * 32 + jj) << 14] = rate1 * aj[jj];
}

__global__ __launch_bounds__(256) void k_conv_f(
    const float* __restrict__ x, const float* __restrict__ ws,
    const float* __restrict__ depw, const float* __restrict__ depb,
    const float* __restrict__ r2, float* __restrict__ out)
{
    __shared__ float arena[12960];
    __shared__ float b2s[36];
    float* w2l = arena;
    ushort_t* xl = (ushort_t*)(arena + 4608);
    float* fcl = arena;
    float* dwl = arena + 11664;
    const int t = threadIdx.x;
    const int b = blockIdx.x >> 6, tile = blockIdx.x & 63;
    const int ty0 = (tile >> 3) << 4, tx0 = (tile & 7) << 4;
    const size_t xbase = ((size_t)b << 21);
    const float rate2 = r2[0];
    const int py = t >> 4, px = t & 15;
    float* ob = out + ((size_t)b << 21) + (size_t)((ty0 + py) * 128 + (tx0 + px));
    const int r0 = t / 18, c0 = t - r0 * 18;
    const bool ok0 = ((unsigned)(ty0 + r0 - 1) < 128u) && ((unsigned)(tx0 + c0 - 1) < 128u);
    const int t1 = 256 + t, r1i = t1 / 18, c1 = t1 - r1i * 18;
    const bool ok1 = (t < 68) && ((unsigned)(ty0 + r1i - 1) < 128u) && ((unsigned)(tx0 + c1 - 1) < 128u);
    for (int chunk = 0; chunk < 8; ++chunk) {
        __syncthreads();
        for (int i = t; i < 4608; i += 256) {
            const int c = i / 36, r = i - c * 36;
            w2l[i] = ws[WS_W2 + c * 288 + (r >> 2) * 32 + chunk * 4 + (r & 3)];
        }
        if (t < 36) b2s[t] = ws[WS_B2 + (t >> 2) * 32 + chunk * 4 + (t & 3)];
        __syncthreads();
        float fca[2][36];
#pragma unroll
        for (int r = 0; r < 36; ++r) { fca[0][r] = b2s[r]; fca[1][r] = b2s[r]; }
        for (int cs = 0; cs < 8; ++cs) {
            if (cs) __syncthreads();
            for (int i = t; i < 5184; i += 256) {
                const int cc = i / 324, pp = i - cc * 324;
                const int row = pp / 18, col = pp - row * 18;
                const int hy = ty0 + row - 1, hx = tx0 + col - 1;
                ushort_t v = 0;
                if ((unsigned)hy < 128u && (unsigned)hx < 128u)
                    v = f2u(x[xbase + (size_t)(cs * 16 + cc) * 16384 + hy * 128 + hx]);
                xl[i] = v;
            }
            __syncthreads();
#pragma unroll 4
            for (int cc = 0; cc < 16; ++cc) {
                const float xv0 = u2f(xl[cc * 324 + t]);
                const float xv1 = (t < 68) ? u2f(xl[cc * 324 + 256 + t]) : 0.f;
                const float* wr = w2l + (cs * 16 + cc) * 36;
#pragma unroll
                for (int r = 0; r < 36; r += 4) {
                    const float4 w4 = *(const float4*)(wr + r);
                    fca[0][r + 0] += xv0 * w4.x; fca[0][r + 1] += xv0 * w4.y;
                    fca[0][r + 2] += xv0 * w4.z; fca[0][r + 3] += xv0 * w4.w;
                    fca[1][r + 0] += xv1 * w4.x; fca[1][r + 1] += xv1 * w4.y;
                    fca[1][r + 2] += xv1 * w4.z; fca[1][r + 3] += xv1 * w4.w;
                }
            }
        }
        __syncthreads();
#pragma unroll
        for (int r = 0; r < 36; ++r) {
            fcl[r * 324 + t] = ok0 ? fca[0][r] : 0.f;
            if (t < 68) fcl[r * 324 + 256 + t] = ok1 ? fca[1][r] : 0.f;
        }
        for (int i = t; i < 1296; i += 256) {
            const int kk = i >> 4, ocl = i & 15;
            dwl[i] = depw[(chunk * 16 + ocl) * 81 + kk];
        }
        __syncthreads();
        float4 accv[4];
#pragma unroll
        for (int dd = 0; dd < 4; ++dd) accv[dd] = make_float4(0.f, 0.f, 0.f, 0.f);
#pragma unroll
        for (int ii = 0; ii < 9; ++ii) {
#pragma unroll
            for (int kk = 0; kk < 9; ++kk) {
                const int ky = kk / 3, kx = kk - (kk / 3) * 3;
                const int hpix = (py + ky) * 18 + px + kx;
                const float4* dwp = (const float4*)&dwl[(ii * 9 + kk) * 16];
#pragma unroll
                for (int dd = 0; dd < 4; ++dd) {
                    const float f = fcl[(ii * 4 + dd) * 324 + hpix];
                    const float4 d4 = dwp[dd];
                    accv[dd].x += f * d4.x; accv[dd].y += f * d4.y;
                    accv[dd].z += f * d4.z; accv[dd].w += f * d4.w;
                }
            }
        }
#pragma unroll
        for (int dd = 0; dd < 4; ++dd) {
            const float av[4] = {accv[dd].x, accv[dd].y, accv[dd].z, accv[dd].w};
#pragma unroll
            for (int j = 0; j < 4; ++j) {
                const int oc = chunk * 16 + dd * 4 + j;
                ob[(size_t)oc << 14] += rate2 * (av[j] + depb[oc]);
            }
        }
    }
}

// ------------------------------------------------------------------
extern "C" void kernel_launch(void* const* d_in, const int* in_sizes, int n_in,
                              void* d_out, int out_size, void* d_ws, size_t ws_size,
                              hipStream_t stream) {
    (void)in_sizes; (void)n_in; (void)out_size;
    const float* x      = (const float*)d_in[0];
    const float* qkv_w  = (const float*)d_in[1];
    const float* qkv_b  = (const float*)d_in[2];
    const float* proj_w = (const float*)d_in[3];
    const float* proj_b = (const float*)d_in[4];
    const float* rpb    = (const float*)d_in[5];
    const float* fc_w   = (const float*)d_in[6];
    const float* fc_b   = (const float*)d_in[7];
    const float* dep_w  = (const float*)d_in[8];
    const float* dep_b  = (const float*)d_in[9];
    const float* rate1  = (const float*)d_in[10];
    const float* rate2  = (const float*)d_in[11];
    float* out = (float*)d_out;

    if (ws_size >= (size_t)131072 * 384 * 2) {
        ushort_t* qkv = (ushort_t*)d_ws;   // 96 MB bf16
        k_qqkv<<<dim3(1024), dim3(256), 0, stream>>>(x, qkv_w, qkv_b, qkv);
        k_attn4<<<dim3(2048), dim3(256), 0, stream>>>(qkv, rpb, out);
        k_proj<<<dim3(1024), dim3(256), 0, stream>>>(proj_w, proj_b, rate1, out);
        k_conv2<<<dim3(512), dim3(256), 0, stream>>>(qkv, fc_w, fc_b, dep_w,
                                                     dep_b, rate2, out);
    } else {
        float* wsf = (float*)d_ws;         // 148.6 KB
        k_prep_f<<<dim3(146), dim3(256), 0, stream>>>(qkv_w, qkv_b, fc_w, fc_b, wsf);
        k_attn_f<<<dim3(2048), dim3(256), 0, stream>>>(x, qkv_w, qkv_b, proj_w,
                                                       proj_b, rpb, rate1, out);
        k_conv_f<<<dim3(512), dim3(256), 0, stream>>>(x, wsf, dep_w, dep_b,
                                                      rate2, out);
    }
}

// Round 11
// 432.498 us; speedup vs baseline: 1.4878x; 1.0016x over previous
//
#include <hip/hip_runtime.h>

typedef unsigned short ushort_t;
typedef unsigned int uint_t;
typedef __attribute__((ext_vector_type(8))) short short8;
typedef __attribute__((ext_vector_type(4))) float f32x4;

#define SCALE 0.17677669529663687f

__device__ __forceinline__ float blo(uint_t u) { return __uint_as_float(u << 16); }
__device__ __forceinline__ float bhi(uint_t u) { return __uint_as_float(u & 0xffff0000u); }
__device__ __forceinline__ float u2f(ushort_t u) { return __uint_as_float(((uint_t)u) << 16); }
// fp32 -> bf16 (RNE), finite inputs
__device__ __forceinline__ ushort_t f2u(float f) {
    const uint_t x = __float_as_uint(f);
    return (ushort_t)((x + 0x7fffu + ((x >> 16) & 1u)) >> 16);
}
__device__ __forceinline__ uint_t pack2(float a, float b) {
    return (uint_t)f2u(a) | ((uint_t)f2u(b) << 16);
}

__device__ __forceinline__ float dot8(const float* qa, uint4 u) {
    return qa[0] * blo(u.x) + qa[1] * bhi(u.x) + qa[2] * blo(u.y) + qa[3] * bhi(u.y)
         + qa[4] * blo(u.z) + qa[5] * bhi(u.z) + qa[6] * blo(u.w) + qa[7] * bhi(u.w);
}
__device__ __forceinline__ void pv8(float* a, float e, uint4 u) {
    a[0] += e * blo(u.x); a[1] += e * bhi(u.x); a[2] += e * blo(u.y); a[3] += e * bhi(u.y);
    a[4] += e * blo(u.z); a[5] += e * bhi(u.z); a[6] += e * blo(u.w); a[7] += e * bhi(u.w);
}

// ==================================================================
// MAIN PATH: qkv materialized in ws as bf16 [p][j], p=131072, j=384.
// Requires ws_size >= 96 MB.
// ==================================================================

// ------------------------------------------------------------------
// k_qqkv (MFMA): qkv[p, j] = bf16( sum_c x[b,c,p]*qkv_w[c,j] + qkv_b[j] )
// Block = 128 pixels x all 384 j (3 j-tiles of 128), K=128.
// ------------------------------------------------------------------
__global__ __launch_bounds__(256) void k_qqkv(
    const float* __restrict__ x, const float* __restrict__ w,
    const float* __restrict__ wb, ushort_t* __restrict__ qkv)
{
    __shared__ ushort_t XT[128 * 128];  // [p][c] swizzled
    __shared__ ushort_t WT[128 * 128];  // [j][c] swizzled; reused as D [p][j]
    const int t = threadIdx.x;
    const int p0 = blockIdx.x * 128;
    const int b = p0 >> 14;             // HW = 16384
    const int rem = p0 & 16383;
    const float* xb = x + ((size_t)b << 21) + rem;

    // ---- stage XT: x[c][p] -> bf16 XT[p][c] (coalesced reads along p)
#pragma unroll
    for (int it = 0; it < 8; ++it) {
        const int slot = it * 256 + t;
        const int p = slot & 127, cb = slot >> 7;   // cb = 16B block along c
        uint4 u;
        {
            const float a0 = xb[(size_t)(cb * 8 + 0) * 16384 + p];
            const float a1 = xb[(size_t)(cb * 8 + 1) * 16384 + p];
            const float a2 = xb[(size_t)(cb * 8 + 2) * 16384 + p];
            const float a3 = xb[(size_t)(cb * 8 + 3) * 16384 + p];
            const float a4 = xb[(size_t)(cb * 8 + 4) * 16384 + p];
            const float a5 = xb[(size_t)(cb * 8 + 5) * 16384 + p];
            const float a6 = xb[(size_t)(cb * 8 + 6) * 16384 + p];
            const float a7 = xb[(size_t)(cb * 8 + 7) * 16384 + p];
            u.x = pack2(a0, a1); u.y = pack2(a2, a3);
            u.z = pack2(a4, a5); u.w = pack2(a6, a7);
        }
        *(uint4*)&XT[p * 128 + ((cb ^ (p & 7)) << 3)] = u;
    }

    const int l = t & 63, wv = t >> 6;
    const int wj = (wv >> 1) * 64, wp = (wv & 1) * 64;
    const int lr = l & 15, lg = l >> 4;

    for (int jt = 0; jt < 3; ++jt) {
        const int j0 = jt * 128;
        __syncthreads();   // XT ready (jt=0) / prior D drained (jt>0)

        // ---- stage WT: w[c][j0+j] -> bf16 WT[j][c] (coalesced along j; L2-hot)
#pragma unroll
        for (int it = 0; it < 8; ++it) {
            const int slot = it * 256 + t;
            const int j = slot & 127, cb = slot >> 7;
            uint4 u;
            {
                const float a0 = w[(size_t)(cb * 8 + 0) * 384 + j0 + j];
                const float a1 = w[(size_t)(cb * 8 + 1) * 384 + j0 + j];
                const float a2 = w[(size_t)(cb * 8 + 2) * 384 + j0 + j];
                const float a3 = w[(size_t)(cb * 8 + 3) * 384 + j0 + j];
                const float a4 = w[(size_t)(cb * 8 + 4) * 384 + j0 + j];
                const float a5 = w[(size_t)(cb * 8 + 5) * 384 + j0 + j];
                const float a6 = w[(size_t)(cb * 8 + 6) * 384 + j0 + j];
                const float a7 = w[(size_t)(cb * 8 + 7) * 384 + j0 + j];
                u.x = pack2(a0, a1); u.y = pack2(a2, a3);
                u.z = pack2(a4, a5); u.w = pack2(a6, a7);
            }
            *(uint4*)&WT[j * 128 + ((cb ^ (j & 7)) << 3)] = u;
        }
        __syncthreads();

        f32x4 acc[4][4];
#pragma unroll
        for (int i = 0; i < 4; ++i)
#pragma unroll
            for (int j = 0; j < 4; ++j) acc[i][j] = (f32x4){0.f, 0.f, 0.f, 0.f};

#pragma unroll
        for (int ks = 0; ks < 4; ++ks) {
            const int kb = ks * 4 + lg;
            short8 af[4], bf[4];
#pragma unroll
            for (int i = 0; i < 4; ++i) {
                const int jr = wj + i * 16 + lr;
                af[i] = *(const short8*)&WT[jr * 128 + ((kb ^ (jr & 7)) << 3)];
                const int pr = wp + i * 16 + lr;
                bf[i] = *(const short8*)&XT[pr * 128 + ((kb ^ (pr & 7)) << 3)];
            }
#pragma unroll
            for (int ji = 0; ji < 4; ++ji)
#pragma unroll
                for (int pi = 0; pi < 4; ++pi)
                    acc[ji][pi] = __builtin_amdgcn_mfma_f32_16x16x32_bf16(
                        af[ji], bf[pi], acc[ji][pi], 0, 0, 0);
        }
        __syncthreads();   // all WT reads done before D overwrite

        // ---- D write: lane holds 4 consecutive j at fixed p per acc tile
#pragma unroll
        for (int ji = 0; ji < 4; ++ji) {
            const int jq = wj + ji * 16 + 4 * lg;            // local j quad base
            const float4 bias = *(const float4*)&wb[j0 + jq];
#pragma unroll
            for (int pi = 0; pi < 4; ++pi) {
                const int p = wp + pi * 16 + lr;
                uint2 o;
                o.x = pack2(acc[ji][pi][0] + bias.x, acc[ji][pi][1] + bias.y);
                o.y = pack2(acc[ji][pi][2] + bias.z, acc[ji][pi][3] + bias.w);
                *(uint2*)&WT[p * 128 + (((jq >> 3) ^ (p & 7)) << 3) + (jq & 7)] = o;
            }
        }
        __syncthreads();

        // ---- copy D -> qkv, coalesced 16B writes (lanes sweep j)
#pragma unroll
        for (int it = 0; it < 8; ++it) {
            const int slot = it * 256 + t;
            const int seg = slot & 15, p = slot >> 4;
            const uint4 v = *(const uint4*)&WT[p * 128 + ((seg ^ (p & 7)) << 3)];
            *(uint4*)&qkv[(size_t)(p0 + p) * 384 + j0 + seg * 8] = v;
        }
    }
}

// ------------------------------------------------------------------
// k_attn4 (MFMA attention): per 8x8 window, wave = head.
// ------------------------------------------------------------------
__global__ __launch_bounds__(256) void k_attn4(
    const ushort_t* __restrict__ qkv, const float* __restrict__ rpb,
    float* __restrict__ out)
{
    // uints: Q[0,4352) K[4352,8704) VT[8704,13056) rpb[13056,13956)
    // P aliases [0,8704): head h at h*2176, row stride 34 uints (68 sh).
    __shared__ uint_t lds[13956];
    ushort_t* lds_sh = (ushort_t*)lds;
    float* rpbl = (float*)(lds + 13056);
    const int t = threadIdx.x;
    const int b = blockIdx.x >> 8, wy = (blockIdx.x >> 4) & 15, wx = blockIdx.x & 15;
    const int prow0 = (b << 14) + (wy * 8) * 128 + wx * 8;
    const uint_t* qkvu = (const uint_t*)qkv;

    // ---- stage Q,K rows (68-uint stride) + V transposed (VT[d][m])
    for (int i = t; i < 4096; i += 256) {
        const int m = i >> 6, u = i & 63;
        const size_t pr = (size_t)(prow0 + (m >> 3) * 128 + (m & 7)) * 192;
        lds[m * 68 + u]        = qkvu[pr + u];
        lds[4352 + m * 68 + u] = qkvu[pr + 64 + u];
        const uint_t v = qkvu[pr + 128 + u];
        lds_sh[17408 + (2 * u) * 68 + m]     = (ushort_t)(v & 0xffffu);
        lds_sh[17408 + (2 * u + 1) * 68 + m] = (ushort_t)(v >> 16);
    }
    for (int i = t; i < 900; i += 256) rpbl[i] = rpb[i];
    __syncthreads();

    const int h = t >> 6, l = t & 63;
    const int lr = l & 15, lg = l >> 4;

    // ---- QK^T: 16 MFMAs
    short8 af_k[4], bf_q[4];
#pragma unroll
    for (int i = 0; i < 4; ++i) {
        af_k[i] = *(const short8*)&lds_sh[8704 + (i * 16 + lr) * 136 + h * 32 + lg * 8];
        bf_q[i] = *(const short8*)&lds_sh[(i * 16 + lr) * 136 + h * 32 + lg * 8];
    }
    f32x4 sA[4][4];   // [nt][mt]
#pragma unroll
    for (int nt = 0; nt < 4; ++nt)
#pragma unroll
        for (int mt = 0; mt < 4; ++mt)
            sA[nt][mt] = __builtin_amdgcn_mfma_f32_16x16x32_bf16(
                af_k[mt], bf_q[nt], (f32x4){0.f, 0.f, 0.f, 0.f}, 0, 0, 0);

    // ---- softmax per row n (lane owns n = nt*16+lr; m split over lg)
    float inv[4];
#pragma unroll
    for (int nt = 0; nt < 4; ++nt) {
        const int n = nt * 16 + lr;
        const int ry = n >> 3, rx = n & 7;
        float mxv = -1e30f;
#pragma unroll
        for (int mt = 0; mt < 4; ++mt)
#pragma unroll
            for (int r = 0; r < 4; ++r) {
                const int m = mt * 16 + lg * 4 + r;
                const float bias =
                    rpbl[((ry - (m >> 3) + 7) * 15 + (rx - (m & 7) + 7)) * 4 + h];
                const float s = sA[nt][mt][r] * SCALE + bias;
                sA[nt][mt][r] = s;
                mxv = fmaxf(mxv, s);
            }
        mxv = fmaxf(mxv, __shfl_xor(mxv, 16));
        mxv = fmaxf(mxv, __shfl_xor(mxv, 32));
        float ls = 0.f;
#pragma unroll
        for (int mt = 0; mt < 4; ++mt)
#pragma unroll
            for (int r = 0; r < 4; ++r) {
                const float e = __expf(sA[nt][mt][r] - mxv);
                sA[nt][mt][r] = e;
                ls += e;
            }
        ls += __shfl_xor(ls, 16);
        ls += __shfl_xor(ls, 32);
        inv[nt] = 1.f / ls;
    }

    __syncthreads();   // all waves done reading Q/K before P overwrites

    // ---- P (bf16) into LDS, row n stride 34 uints
    uint_t* Pb = lds + h * 2176;
#pragma unroll
    for (int nt = 0; nt < 4; ++nt) {
        const int n = nt * 16 + lr;
#pragma unroll
        for (int mt = 0; mt < 4; ++mt) {
            uint2 o;
            o.x = pack2(sA[nt][mt][0], sA[nt][mt][1]);
            o.y = pack2(sA[nt][mt][2], sA[nt][mt][3]);
            *(uint2*)&Pb[n * 34 + mt * 8 + lg * 2] = o;
        }
    }
    asm volatile("s_waitcnt lgkmcnt(0)" ::: "memory");

    // ---- PV: O = mfma(A=VT rows d, B=P rows n), K=64 (2 steps)
    union U8 { short8 s8; uint2 u2[2]; };
    f32x4 oA[2][4];
#pragma unroll
    for (int dt = 0; dt < 2; ++dt)
#pragma unroll
        for (int nt = 0; nt < 4; ++nt) oA[dt][nt] = (f32x4){0.f, 0.f, 0.f, 0.f};
#pragma unroll
    for (int ks = 0; ks < 2; ++ks) {
        const int kb = ks * 4 + lg;
        short8 av[2], bp[4];
#pragma unroll
        for (int dt = 0; dt < 2; ++dt) {
            U8 u;
            const int d = h * 32 + dt * 16 + lr;
            u.u2[0] = *(const uint2*)&lds[8704 + d * 34 + kb * 4];
            u.u2[1] = *(const uint2*)&lds[8704 + d * 34 + kb * 4 + 2];
            av[dt] = u.s8;
        }
#pragma unroll
        for (int nt = 0; nt < 4; ++nt) {
            U8 u;
            const int n = nt * 16 + lr;
            u.u2[0] = *(const uint2*)&Pb[n * 34 + kb * 4];
            u.u2[1] = *(const uint2*)&Pb[n * 34 + kb * 4 + 2];
            bp[nt] = u.s8;
        }
#pragma unroll
        for (int dt = 0; dt < 2; ++dt)
#pragma unroll
            for (int nt = 0; nt < 4; ++nt)
                oA[dt][nt] = __builtin_amdgcn_mfma_f32_16x16x32_bf16(
                    av[dt], bp[nt], oA[dt][nt], 0, 0, 0);
    }

    // ---- write raw xa channel-major: out[b][h*32+d][pix(n)]
    float* ob = out + ((size_t)b << 21);
    const int pixbase = (wy * 8) * 128 + wx * 8;
#pragma unroll
    for (int dt = 0; dt < 2; ++dt)
#pragma unroll
        for (int nt = 0; nt < 4; ++nt) {
            const int n = nt * 16 + lr;
            const size_t po = (size_t)(pixbase + (n >> 3) * 128 + (n & 7));
            const float iv = inv[nt];
#pragma unroll
            for (int r = 0; r < 4; ++r) {
                const int d = h * 32 + dt * 16 + lg * 4 + r;
                ob[((size_t)d << 14) + po] = oA[dt][nt][r] * iv;
            }
        }
}

// ------------------------------------------------------------------
// k_proj (MFMA, in-place on out): out[b][j][p] =
//    rate1 * ( sum_c xa[b][c][p] * pw[c][j] + pb[j] ), xa = current out.
// ------------------------------------------------------------------
__global__ __launch_bounds__(256) void k_proj(
    const float* __restrict__ pw, const float* __restrict__ pb,
    const float* __restrict__ r1, float* __restrict__ out)
{
    __shared__ ushort_t XT[128 * 128];  // xa^T [p][c] swizzled
    __shared__ ushort_t WT[128 * 128];  // pw^T [j][c] swizzled
    const int t = threadIdx.x;
    const int p0 = blockIdx.x * 128;
    const int b = p0 >> 14;
    const int rem = p0 & 16383;
    const float* xb = out + ((size_t)b << 21) + rem;

    // ---- stage XT from out (xa), coalesced along p
#pragma unroll
    for (int it = 0; it < 8; ++it) {
        const int slot = it * 256 + t;
        const int p = slot & 127, cb = slot >> 7;
        uint4 u;
        {
            const float a0 = xb[(size_t)(cb * 8 + 0) * 16384 + p];
            const float a1 = xb[(size_t)(cb * 8 + 1) * 16384 + p];
            const float a2 = xb[(size_t)(cb * 8 + 2) * 16384 + p];
            const float a3 = xb[(size_t)(cb * 8 + 3) * 16384 + p];
            const float a4 = xb[(size_t)(cb * 8 + 4) * 16384 + p];
            const float a5 = xb[(size_t)(cb * 8 + 5) * 16384 + p];
            const float a6 = xb[(size_t)(cb * 8 + 6) * 16384 + p];
            const float a7 = xb[(size_t)(cb * 8 + 7) * 16384 + p];
            u.x = pack2(a0, a1); u.y = pack2(a2, a3);
            u.z = pack2(a4, a5); u.w = pack2(a6, a7);
        }
        *(uint4*)&XT[p * 128 + ((cb ^ (p & 7)) << 3)] = u;
    }
    // ---- stage WT from pw (128x128), coalesced along j
#pragma unroll
    for (int it = 0; it < 8; ++it) {
        const int slot = it * 256 + t;
        const int j = slot & 127, cb = slot >> 7;
        uint4 u;
        {
            const float a0 = pw[(size_t)(cb * 8 + 0) * 128 + j];
            const float a1 = pw[(size_t)(cb * 8 + 1) * 128 + j];
            const float a2 = pw[(size_t)(cb * 8 + 2) * 128 + j];
            const float a3 = pw[(size_t)(cb * 8 + 3) * 128 + j];
            const float a4 = pw[(size_t)(cb * 8 + 4) * 128 + j];
            const float a5 = pw[(size_t)(cb * 8 + 5) * 128 + j];
            const float a6 = pw[(size_t)(cb * 8 + 6) * 128 + j];
            const float a7 = pw[(size_t)(cb * 8 + 7) * 128 + j];
            u.x = pack2(a0, a1); u.y = pack2(a2, a3);
            u.z = pack2(a4, a5); u.w = pack2(a6, a7);
        }
        *(uint4*)&WT[j * 128 + ((cb ^ (j & 7)) << 3)] = u;
    }
    __syncthreads();   // all global reads of this block's pixels complete here

    const int l = t & 63, wv = t >> 6;
    const int wj = (wv >> 1) * 64, wp = (wv & 1) * 64;
    const int lr = l & 15, lg = l >> 4;

    f32x4 acc[4][4];
#pragma unroll
    for (int i = 0; i < 4; ++i)
#pragma unroll
        for (int j = 0; j < 4; ++j) acc[i][j] = (f32x4){0.f, 0.f, 0.f, 0.f};

#pragma unroll
    for (int ks = 0; ks < 4; ++ks) {
        const int kb = ks * 4 + lg;
        short8 af[4], bf[4];
#pragma unroll
        for (int i = 0; i < 4; ++i) {
            const int jr = wj + i * 16 + lr;
            af[i] = *(const short8*)&WT[jr * 128 + ((kb ^ (jr & 7)) << 3)];
            const int pr = wp + i * 16 + lr;
            bf[i] = *(const short8*)&XT[pr * 128 + ((kb ^ (pr & 7)) << 3)];
        }
#pragma unroll
        for (int ji = 0; ji < 4; ++ji)
#pragma unroll
            for (int pi = 0; pi < 4; ++pi)
                acc[ji][pi] = __builtin_amdgcn_mfma_f32_16x16x32_bf16(
                    af[ji], bf[pi], acc[ji][pi], 0, 0, 0);
    }

    const float rate1 = r1[0];
    float* obase = out + ((size_t)b << 21) + rem;
    // lane holds j = jq..jq+3 at pixel p; stores are 16-lane p-contiguous
#pragma unroll
    for (int ji = 0; ji < 4; ++ji) {
        const int jq = wj + ji * 16 + 4 * lg;
        const float4 bias = *(const float4*)&pb[jq];
#pragma unroll
        for (int pi = 0; pi < 4; ++pi) {
            const int p = wp + pi * 16 + lr;
            float* op = obase + (size_t)jq * 16384 + p;
            op[0]     = rate1 * (acc[ji][pi][0] + bias.x);
            op[16384] = rate1 * (acc[ji][pi][1] + bias.y);
            op[32768] = rate1 * (acc[ji][pi][2] + bias.z);
            op[49152] = rate1 * (acc[ji][pi][3] + bias.w);
        }
    }
}

// ------------------------------------------------------------------
// k_conv6: conv2 structure verbatim EXCEPT fcl stored as bf16
// (ushort) -> LDS 52.7 KB -> ~29 KB -> 5 blocks/CU instead of 2.
// Same math; f_c rounded to bf16 before the 81-tap conv (error
// ~1.4e-4 on out, well under existing 9.8e-4 absmax).
// ------------------------------------------------------------------
__global__ __launch_bounds__(256) void k_conv6(
    const ushort_t* __restrict__ qkv, const float* __restrict__ fcw,
    const float* __restrict__ fcb, const float* __restrict__ depw,
    const float* __restrict__ depb, const float* __restrict__ r2,
    float* __restrict__ out)
{
    __shared__ ushort_t fcl[11664];             // [(ii*4+dd)*324 + pix] bf16
    __shared__ __align__(16) float dwl[1296];   // [kk81][16 oc-in-chunk]
    __shared__ float fcwl[108];
    __shared__ float fcbl[9];

    const int t = threadIdx.x;
    const int b = blockIdx.x >> 6, tile = blockIdx.x & 63;
    const int ty0 = (tile >> 3) << 4, tx0 = (tile & 7) << 4;
    if (t < 108) fcwl[t] = fcw[t];
    if (t < 9)   fcbl[t] = fcb[t];
    const float rate2 = r2[0];
    const int py = t >> 4, px = t & 15;
    float* ob = out + ((size_t)b << 21) + (size_t)((ty0 + py) * 128 + (tx0 + px));

    // this thread's halo pixels: pix0 = t, pix1 = 256+t (t<68)
    const int row0 = t / 18, col0 = t - row0 * 18;
    const int hy0 = ty0 + row0 - 1, hx0 = tx0 + col0 - 1;
    const int g0 = ((unsigned)hy0 < 128u && (unsigned)hx0 < 128u)
                       ? ((b << 14) + hy0 * 128 + hx0) : -1;
    const int t1 = t + 256, row1 = t1 / 18, col1 = t1 - row1 * 18;
    const int hy1 = ty0 + row1 - 1, hx1 = tx0 + col1 - 1;
    const int g1 = (t < 68 && (unsigned)hy1 < 128u && (unsigned)hx1 < 128u)
                       ? ((b << 14) + hy1 * 128 + hx1) : -1;

    for (int chunk = 0; chunk < 8; ++chunk) {
        __syncthreads();   // fcwl visible (chunk 0) / prior conv reads done
        for (int i = t; i < 1296; i += 256)
            dwl[i] = depw[(chunk * 16 + (i & 15)) * 81 + (i >> 4)];

#pragma unroll
        for (int half = 0; half < 2; ++half) {
            const int g = half ? g1 : g0;
            const int pix = half ? (256 + t) : t;
            if (half && t >= 68) break;
            float fo[9][4];
#pragma unroll
            for (int ii = 0; ii < 9; ++ii) {
                const float bv = (g >= 0) ? fcbl[ii] : 0.f;
                fo[ii][0] = bv; fo[ii][1] = bv; fo[ii][2] = bv; fo[ii][3] = bv;
            }
            if (g >= 0) {
                const uint2* qp = (const uint2*)(qkv + (size_t)g * 384 + chunk * 4);
#pragma unroll
                for (int e = 0; e < 12; ++e) {
                    const uint2 q = qp[e * 8];
                    const float f0 = blo(q.x), f1 = bhi(q.x);
                    const float f2 = blo(q.y), f3 = bhi(q.y);
#pragma unroll
                    for (int ii = 0; ii < 9; ++ii) {
                        const float wv = fcwl[ii * 12 + e];
                        fo[ii][0] += wv * f0; fo[ii][1] += wv * f1;
                        fo[ii][2] += wv * f2; fo[ii][3] += wv * f3;
                    }
                }
            }
#pragma unroll
            for (int ii = 0; ii < 9; ++ii)
#pragma unroll
                for (int dd = 0; dd < 4; ++dd)
                    fcl[(ii * 4 + dd) * 324 + pix] = f2u(fo[ii][dd]);
        }
        __syncthreads();

        float4 accv[4];
#pragma unroll
        for (int dd = 0; dd < 4; ++dd) accv[dd] = make_float4(0.f, 0.f, 0.f, 0.f);
#pragma unroll
        for (int ii = 0; ii < 9; ++ii) {
#pragma unroll
            for (int kk = 0; kk < 9; ++kk) {
                const int ky = kk / 3, kx = kk - (kk / 3) * 3;
                const int hpix = (py + ky) * 18 + px + kx;
                const float4* dwp = (const float4*)&dwl[(ii * 9 + kk) * 16];
#pragma unroll
                for (int dd = 0; dd < 4; ++dd) {
                    const float f = u2f(fcl[(ii * 4 + dd) * 324 + hpix]);
                    const float4 d4 = dwp[dd];
                    accv[dd].x += f * d4.x; accv[dd].y += f * d4.y;
                    accv[dd].z += f * d4.z; accv[dd].w += f * d4.w;
                }
            }
        }
#pragma unroll
        for (int dd = 0; dd < 4; ++dd) {
            const float av[4] = {accv[dd].x, accv[dd].y, accv[dd].z, accv[dd].w};
#pragma unroll
            for (int j = 0; j < 4; ++j) {
                const int oc = chunk * 16 + dd * 4 + j;
                ob[(size_t)oc << 14] += rate2 * (av[j] + depb[oc]);
            }
        }
    }
}

// ==================================================================
// FALLBACK PATH (ws too small): round-5 kernels, verbatim.
// ==================================================================
#define WS_W2  0
#define WS_B2  36864
#define WS_TOT 37152

__global__ __launch_bounds__(256) void k_prep_f(
    const float* __restrict__ qkv_w, const float* __restrict__ qkv_b,
    const float* __restrict__ fcw, const float* __restrict__ fcb,
    float* __restrict__ ws)
{
    const int idx = blockIdx.x * 256 + threadIdx.x;
    if (idx < WS_B2) {
        const int c = idx / 288, r = idx - c * 288, i = r >> 5, d = r & 31;
        float s = 0.f;
#pragma unroll
        for (int e = 0; e < 12; ++e)
            s += fcw[i * 12 + e] * qkv_w[c * 384 + e * 32 + d];
        ws[idx] = s;
    } else if (idx < WS_TOT) {
        const int r = idx - WS_B2, i = r >> 5, d = r & 31;
        float s = fcb[i];
#pragma unroll
        for (int e = 0; e < 12; ++e)
            s += fcw[i * 12 + e] * qkv_b[e * 32 + d];
        ws[idx] = s;
    }
}

__global__ __launch_bounds__(256) void k_attn_f(
    const float* __restrict__ x, const float* __restrict__ qw,
    const float* __restrict__ qb, const float* __restrict__ pw,
    const float* __restrict__ pb, const float* __restrict__ rpb,
    const float* __restrict__ r1, float* __restrict__ out)
{
    __shared__ ushort_t xw[8192];
    __shared__ float arena[8450];
    ushort_t* kvb = (ushort_t*)arena;
    const int t = threadIdx.x;
    const int b = blockIdx.x >> 8, wy = (blockIdx.x >> 4) & 15, wx = blockIdx.x & 15;
    const size_t xbase = ((size_t)b << 21) + (size_t)((wy * 8) * 128 + wx * 8);
    for (int i = t; i < 8192; i += 256) {
        const int c = i >> 6, p = i & 63;
        xw[i] = f2u(x[xbase + (size_t)c * 16384 + (p >> 3) * 128 + (p & 7)]);
    }
    __syncthreads();
    const int h = t >> 6, n = t & 63;
    float qa[32], ka[32], va[32];
#pragma unroll
    for (int cc = 0; cc < 32; ++cc) {
        qa[cc] = qb[h * 32 + cc];
        ka[cc] = qb[128 + h * 32 + cc];
        va[cc] = qb[256 + h * 32 + cc];
    }
    const float* wbase = qw + h * 32;
    for (int c = 0; c < 128; ++c) {
        const float xv = u2f(xw[c * 64 + n]);
        const float* wr = wbase + c * 384;
#pragma unroll
        for (int j = 0; j < 8; ++j) {
            const float4 aq = ((const float4*)wr)[j];
            const float4 ak = ((const float4*)(wr + 128))[j];
            const float4 av = ((const float4*)(wr + 256))[j];
            qa[4 * j + 0] += xv * aq.x; qa[4 * j + 1] += xv * aq.y;
            qa[4 * j + 2] += xv * aq.z; qa[4 * j + 3] += xv * aq.w;
            ka[4 * j + 0] += xv * ak.x; ka[4 * j + 1] += xv * ak.y;
            ka[4 * j + 2] += xv * ak.z; ka[4 * j + 3] += xv * ak.w;
            va[4 * j + 0] += xv * av.x; va[4 * j + 1] += xv * av.y;
            va[4 * j + 2] += xv * av.z; va[4 * j + 3] += xv * av.w;
        }
    }
#pragma unroll
    for (int cc = 0; cc < 32; ++cc) qa[cc] *= SCALE;
    uint_t* kv32 = (uint_t*)kvb;
#pragma unroll
    for (int j = 0; j < 16; ++j) {
        kv32[n * 66 + h * 16 + j] = pack2(ka[2 * j], ka[2 * j + 1]);
        kv32[4224 + n * 66 + h * 16 + j] = pack2(va[2 * j], va[2 * j + 1]);
    }
    __syncthreads();
    const int ry = n >> 3, rx = n & 7;
    float sar[64];
    float mx = -1e30f;
#pragma unroll
    for (int m = 0; m < 64; ++m) {
        const uint2* kr = (const uint2*)(kvb + m * 132 + h * 32);
        float s = 0.f;
#pragma unroll
        for (int j = 0; j < 8; ++j) {
            const uint2 u = kr[j];
            s += qa[4 * j + 0] * blo(u.x) + qa[4 * j + 1] * bhi(u.x)
               + qa[4 * j + 2] * blo(u.y) + qa[4 * j + 3] * bhi(u.y);
        }
        s += rpb[((ry - (m >> 3) + 7) * 15 + (rx - (m & 7) + 7)) * 4 + h];
        sar[m] = s;
        mx = fmaxf(mx, s);
    }
    float l = 0.f;
#pragma unroll
    for (int m = 0; m < 64; ++m) { const float e = __expf(sar[m] - mx); sar[m] = e; l += e; }
    const float inv = 1.f / l;
    float acc[32];
#pragma unroll
    for (int cc = 0; cc < 32; ++cc) acc[cc] = 0.f;
#pragma unroll
    for (int m = 0; m < 64; ++m) {
        const float pm = sar[m];
        const uint2* vr = (const uint2*)(kvb + 8448 + m * 132 + h * 32);
#pragma unroll
        for (int j = 0; j < 8; ++j) {
            const uint2 u = vr[j];
            acc[4 * j + 0] += pm * blo(u.x); acc[4 * j + 1] += pm * bhi(u.x);
            acc[4 * j + 2] += pm * blo(u.y); acc[4 * j + 3] += pm * bhi(u.y);
        }
    }
    __syncthreads();
#pragma unroll
    for (int cc = 0; cc < 32; ++cc) arena[n * 130 + h * 32 + cc] = acc[cc] * inv;
    __syncthreads();
    const int p = t & 63, jb = t >> 6;
    float aj[32];
#pragma unroll
    for (int jj = 0; jj < 32; ++jj) aj[jj] = pb[jb * 32 + jj];
    const float* xr = arena + p * 130;
    const float* pwb = pw + jb * 32;
    for (int c = 0; c < 128; ++c) {
        const float xv = xr[c];
        const float4* pr = (const float4*)(pwb + c * 128);
#pragma unroll
        for (int j = 0; j < 8; ++j) {
            const float4 w4 = pr[j];
            aj[4 * j + 0] += xv * w4.x; aj[4 * j + 1] += xv * w4.y;
            aj[4 * j + 2] += xv * w4.z; aj[4 * j + 3] += xv * w4.w;
        }
    }
    const float rate1 = r1[0];
    const int oy = wy * 8 + (p >> 3), ox = wx * 8 + (p & 7);
    float* ob = out + ((size_t)b << 21) + (size_t)(oy * 128 + ox);
#pragma unroll
    for (int jj = 0; jj < 32; ++jj)
        ob[(size_t)(jb * 32 + jj) << 14] = rate1 * aj[jj];
}

__global__ __launch_bounds__(256) void k_conv_f(
    const float* __restrict__ x, const float* __restrict__ ws,
    const float* __restrict__ depw, const float* __restrict__ depb,
    const float* __restrict__ r2, float* __restrict__ out)
{
    __shared__ float arena[12960];
    __shared__ float b2s[36];
    float* w2l = arena;
    ushort_t* xl = (ushort_t*)(arena + 4608);
    float* fcl = arena;
    float* dwl = arena + 11664;
    const int t = threadIdx.x;
    const int b = blockIdx.x >> 6, tile = blockIdx.x & 63;
    const int ty0 = (tile >> 3) << 4, tx0 = (tile & 7) << 4;
    const size_t xbase = ((size_t)b << 21);
    const float rate2 = r2[0];
    const int py = t >> 4, px = t & 15;
    float* ob = out + ((size_t)b << 21) + (size_t)((ty0 + py) * 128 + (tx0 + px));
    const int r0 = t / 18, c0 = t - r0 * 18;
    const bool ok0 = ((unsigned)(ty0 + r0 - 1) < 128u) && ((unsigned)(tx0 + c0 - 1) < 128u);
    const int t1 = 256 + t, r1i = t1 / 18, c1 = t1 - r1i * 18;
    const bool ok1 = (t < 68) && ((unsigned)(ty0 + r1i - 1) < 128u) && ((unsigned)(tx0 + c1 - 1) < 128u);
    for (int chunk = 0; chunk < 8; ++chunk) {
        __syncthreads();
        for (int i = t; i < 4608; i += 256) {
            const int c = i / 36, r = i - c * 36;
            w2l[i] = ws[WS_W2 + c * 288 + (r >> 2) * 32 + chunk * 4 + (r & 3)];
        }
        if (t < 36) b2s[t] = ws[WS_B2 + (t >> 2) * 32 + chunk * 4 + (t & 3)];
        __syncthreads();
        float fca[2][36];
#pragma unroll
        for (int r = 0; r < 36; ++r) { fca[0][r] = b2s[r]; fca[1][r] = b2s[r]; }
        for (int cs = 0; cs < 8; ++cs) {
            if (cs) __syncthreads();
            for (int i = t; i < 5184; i += 256) {
                const int cc = i / 324, pp = i - cc * 324;
                const int row = pp / 18, col = pp - row * 18;
                const int hy = ty0 + row - 1, hx = tx0 + col - 1;
                ushort_t v = 0;
                if ((unsigned)hy < 128u && (unsigned)hx < 128u)
                    v = f2u(x[xbase + (size_t)(cs * 16 + cc) * 16384 + hy * 128 + hx]);
                xl[i] = v;
            }
            __syncthreads();
#pragma unroll 4
            for (int cc = 0; cc < 16; ++cc) {
                const float xv0 = u2f(xl[cc * 324 + t]);
                const float xv1 = (t < 68) ? u2f(xl[cc * 324 + 256 + t]) : 0.f;
                const float* wr = w2l + (cs * 16 + cc) * 36;
#pragma unroll
                for (int r = 0; r < 36; r += 4) {
                    const float4 w4 = *(const float4*)(wr + r);
                    fca[0][r + 0] += xv0 * w4.x; fca[0][r + 1] += xv0 * w4.y;
                    fca[0][r + 2] += xv0 * w4.z; fca[0][r + 3] += xv0 * w4.w;
                    fca[1][r + 0] += xv1 * w4.x; fca[1][r + 1] += xv1 * w4.y;
                    fca[1][r + 2] += xv1 * w4.z; fca[1][r + 3] += xv1 * w4.w;
                }
            }
        }
        __syncthreads();
#pragma unroll
        for (int r = 0; r < 36; ++r) {
            fcl[r * 324 + t] = ok0 ? fca[0][r] : 0.f;
            if (t < 68) fcl[r * 324 + 256 + t] = ok1 ? fca[1][r] : 0.f;
        }
        for (int i = t; i < 1296; i += 256) {
            const int kk = i >> 4, ocl = i & 15;
            dwl[i] = depw[(chunk * 16 + ocl) * 81 + kk];
        }
        __syncthreads();
        float4 accv[4];
#pragma unroll
        for (int dd = 0; dd < 4; ++dd) accv[dd] = make_float4(0.f, 0.f, 0.f, 0.f);
#pragma unroll
        for (int ii = 0; ii < 9; ++ii) {
#pragma unroll
            for (int kk = 0; kk < 9; ++kk) {
                const int ky = kk / 3, kx = kk - (kk / 3) * 3;
                const int hpix = (py + ky) * 18 + px + kx;
                const float4* dwp = (const float4*)&dwl[(ii * 9 + kk) * 16];
#pragma unroll
                for (int dd = 0; dd < 4; ++dd) {
                    const float f = fcl[(ii * 4 + dd) * 324 + hpix];
                    const float4 d4 = dwp[dd];
                    accv[dd].x += f * d4.x; accv[dd].y += f * d4.y;
                    accv[dd].z += f * d4.z; accv[dd].w += f * d4.w;
                }
            }
        }
#pragma unroll
        for (int dd = 0; dd < 4; ++dd) {
            const float av[4] = {accv[dd].x, accv[dd].y, accv[dd].z, accv[dd].w};
#pragma unroll
            for (int j = 0; j < 4; ++j) {
                const int oc = chunk * 16 + dd * 4 + j;
                ob[(size_t)oc << 14] += rate2 * (av[j] + depb[oc]);
            }
        }
    }
}

// ------------------------------------------------------------------
extern "C" void kernel_launch(void* const* d_in, const int* in_sizes, int n_in,
                              void* d_out, int out_size, void* d_ws, size_t ws_size,
                              hipStream_t stream) {
    (void)in_sizes; (void)n_in; (void)out_size;
    const float* x      = (const float*)d_in[0];
    const float* qkv_w  = (const float*)d_in[1];
    const float* qkv_b  = (const float*)d_in[2];
    const float* proj_w = (const float*)d_in[3];
    const float* proj_b = (const float*)d_in[4];
    const float* rpb    = (const float*)d_in[5];
    const float* fc_w   = (const float*)d_in[6];
    const float* fc_b   = (const float*)d_in[7];
    const float* dep_w  = (const float*)d_in[8];
    const float* dep_b  = (const float*)d_in[9];
    const float* rate1  = (const float*)d_in[10];
    const float* rate2  = (const float*)d_in[11];
    float* out = (float*)d_out;

    if (ws_size >= (size_t)131072 * 384 * 2) {
        ushort_t* qkv = (ushort_t*)d_ws;   // 96 MB bf16
        k_qqkv<<<dim3(1024), dim3(256), 0, stream>>>(x, qkv_w, qkv_b, qkv);
        k_attn4<<<dim3(2048), dim3(256), 0, stream>>>(qkv, rpb, out);
        k_proj<<<dim3(1024), dim3(256), 0, stream>>>(proj_w, proj_b, rate1, out);
        k_conv6<<<dim3(512), dim3(256), 0, stream>>>(qkv, fc_w, fc_b, dep_w,
                                                     dep_b, rate2, out);
    } else {
        float* wsf = (float*)d_ws;         // 148.6 KB
        k_prep_f<<<dim3(146), dim3(256), 0, stream>>>(qkv_w, qkv_b, fc_w, fc_b, wsf);
        k_attn_f<<<dim3(2048), dim3(256), 0, stream>>>(x, qkv_w, qkv_b, proj_w,
                                                       proj_b, rpb, rate1, out);
        k_conv_f<<<dim3(512), dim3(256), 0, stream>>>(x, wsf, dep_w, dep_b,
                                                      rate2, out);
    }
}

// Round 12
// 431.744 us; speedup vs baseline: 1.4904x; 1.0017x over previous
//
#include <hip/hip_runtime.h>

typedef unsigned short ushort_t;
typedef unsigned int uint_t;
typedef __attribute__((ext_vector_type(8))) short short8;
typedef __attribute__((ext_vector_type(4))) float f32x4;

#define SCALE 0.17677669529663687f

__device__ __forceinline__ float blo(uint_t u) { return __uint_as_float(u << 16); }
__device__ __forceinline__ float bhi(uint_t u) { return __uint_as_float(u & 0xffff0000u); }
__device__ __forceinline__ float u2f(ushort_t u) { return __uint_as_float(((uint_t)u) << 16); }
// fp32 -> bf16 (RNE), finite inputs
__device__ __forceinline__ ushort_t f2u(float f) {
    const uint_t x = __float_as_uint(f);
    return (ushort_t)((x + 0x7fffu + ((x >> 16) & 1u)) >> 16);
}
__device__ __forceinline__ uint_t pack2(float a, float b) {
    return (uint_t)f2u(a) | ((uint_t)f2u(b) << 16);
}

__device__ __forceinline__ float dot8(const float* qa, uint4 u) {
    return qa[0] * blo(u.x) + qa[1] * bhi(u.x) + qa[2] * blo(u.y) + qa[3] * bhi(u.y)
         + qa[4] * blo(u.z) + qa[5] * bhi(u.z) + qa[6] * blo(u.w) + qa[7] * bhi(u.w);
}
__device__ __forceinline__ void pv8(float* a, float e, uint4 u) {
    a[0] += e * blo(u.x); a[1] += e * bhi(u.x); a[2] += e * blo(u.y); a[3] += e * bhi(u.y);
    a[4] += e * blo(u.z); a[5] += e * bhi(u.z); a[6] += e * blo(u.w); a[7] += e * bhi(u.w);
}

// ==================================================================
// MAIN PATH: qkv materialized in ws as bf16 [p][j], p=131072, j=384.
// Requires ws_size >= 96 MB.
// ==================================================================

// ------------------------------------------------------------------
// k_qqkv (MFMA): qkv[p, j] = bf16( sum_c x[b,c,p]*qkv_w[c,j] + qkv_b[j] )
// Block = 128 pixels x all 384 j (3 j-tiles of 128), K=128.
// ------------------------------------------------------------------
__global__ __launch_bounds__(256) void k_qqkv(
    const float* __restrict__ x, const float* __restrict__ w,
    const float* __restrict__ wb, ushort_t* __restrict__ qkv)
{
    __shared__ ushort_t XT[128 * 128];  // [p][c] swizzled
    __shared__ ushort_t WT[128 * 128];  // [j][c] swizzled; reused as D [p][j]
    const int t = threadIdx.x;
    const int p0 = blockIdx.x * 128;
    const int b = p0 >> 14;             // HW = 16384
    const int rem = p0 & 16383;
    const float* xb = x + ((size_t)b << 21) + rem;

    // ---- stage XT: x[c][p] -> bf16 XT[p][c] (coalesced reads along p)
#pragma unroll
    for (int it = 0; it < 8; ++it) {
        const int slot = it * 256 + t;
        const int p = slot & 127, cb = slot >> 7;   // cb = 16B block along c
        uint4 u;
        {
            const float a0 = xb[(size_t)(cb * 8 + 0) * 16384 + p];
            const float a1 = xb[(size_t)(cb * 8 + 1) * 16384 + p];
            const float a2 = xb[(size_t)(cb * 8 + 2) * 16384 + p];
            const float a3 = xb[(size_t)(cb * 8 + 3) * 16384 + p];
            const float a4 = xb[(size_t)(cb * 8 + 4) * 16384 + p];
            const float a5 = xb[(size_t)(cb * 8 + 5) * 16384 + p];
            const float a6 = xb[(size_t)(cb * 8 + 6) * 16384 + p];
            const float a7 = xb[(size_t)(cb * 8 + 7) * 16384 + p];
            u.x = pack2(a0, a1); u.y = pack2(a2, a3);
            u.z = pack2(a4, a5); u.w = pack2(a6, a7);
        }
        *(uint4*)&XT[p * 128 + ((cb ^ (p & 7)) << 3)] = u;
    }

    const int l = t & 63, wv = t >> 6;
    const int wj = (wv >> 1) * 64, wp = (wv & 1) * 64;
    const int lr = l & 15, lg = l >> 4;

    for (int jt = 0; jt < 3; ++jt) {
        const int j0 = jt * 128;
        __syncthreads();   // XT ready (jt=0) / prior D drained (jt>0)

        // ---- stage WT: w[c][j0+j] -> bf16 WT[j][c] (coalesced along j; L2-hot)
#pragma unroll
        for (int it = 0; it < 8; ++it) {
            const int slot = it * 256 + t;
            const int j = slot & 127, cb = slot >> 7;
            uint4 u;
            {
                const float a0 = w[(size_t)(cb * 8 + 0) * 384 + j0 + j];
                const float a1 = w[(size_t)(cb * 8 + 1) * 384 + j0 + j];
                const float a2 = w[(size_t)(cb * 8 + 2) * 384 + j0 + j];
                const float a3 = w[(size_t)(cb * 8 + 3) * 384 + j0 + j];
                const float a4 = w[(size_t)(cb * 8 + 4) * 384 + j0 + j];
                const float a5 = w[(size_t)(cb * 8 + 5) * 384 + j0 + j];
                const float a6 = w[(size_t)(cb * 8 + 6) * 384 + j0 + j];
                const float a7 = w[(size_t)(cb * 8 + 7) * 384 + j0 + j];
                u.x = pack2(a0, a1); u.y = pack2(a2, a3);
                u.z = pack2(a4, a5); u.w = pack2(a6, a7);
            }
            *(uint4*)&WT[j * 128 + ((cb ^ (j & 7)) << 3)] = u;
        }
        __syncthreads();

        f32x4 acc[4][4];
#pragma unroll
        for (int i = 0; i < 4; ++i)
#pragma unroll
            for (int j = 0; j < 4; ++j) acc[i][j] = (f32x4){0.f, 0.f, 0.f, 0.f};

#pragma unroll
        for (int ks = 0; ks < 4; ++ks) {
            const int kb = ks * 4 + lg;
            short8 af[4], bf[4];
#pragma unroll
            for (int i = 0; i < 4; ++i) {
                const int jr = wj + i * 16 + lr;
                af[i] = *(const short8*)&WT[jr * 128 + ((kb ^ (jr & 7)) << 3)];
                const int pr = wp + i * 16 + lr;
                bf[i] = *(const short8*)&XT[pr * 128 + ((kb ^ (pr & 7)) << 3)];
            }
#pragma unroll
            for (int ji = 0; ji < 4; ++ji)
#pragma unroll
                for (int pi = 0; pi < 4; ++pi)
                    acc[ji][pi] = __builtin_amdgcn_mfma_f32_16x16x32_bf16(
                        af[ji], bf[pi], acc[ji][pi], 0, 0, 0);
        }
        __syncthreads();   // all WT reads done before D overwrite

        // ---- D write: lane holds 4 consecutive j at fixed p per acc tile
#pragma unroll
        for (int ji = 0; ji < 4; ++ji) {
            const int jq = wj + ji * 16 + 4 * lg;            // local j quad base
            const float4 bias = *(const float4*)&wb[j0 + jq];
#pragma unroll
            for (int pi = 0; pi < 4; ++pi) {
                const int p = wp + pi * 16 + lr;
                uint2 o;
                o.x = pack2(acc[ji][pi][0] + bias.x, acc[ji][pi][1] + bias.y);
                o.y = pack2(acc[ji][pi][2] + bias.z, acc[ji][pi][3] + bias.w);
                *(uint2*)&WT[p * 128 + (((jq >> 3) ^ (p & 7)) << 3) + (jq & 7)] = o;
            }
        }
        __syncthreads();

        // ---- copy D -> qkv, coalesced 16B writes (lanes sweep j)
#pragma unroll
        for (int it = 0; it < 8; ++it) {
            const int slot = it * 256 + t;
            const int seg = slot & 15, p = slot >> 4;
            const uint4 v = *(const uint4*)&WT[p * 128 + ((seg ^ (p & 7)) << 3)];
            *(uint4*)&qkv[(size_t)(p0 + p) * 384 + j0 + seg * 8] = v;
        }
    }
}

// ------------------------------------------------------------------
// k_attn4 (MFMA attention): per 8x8 window, wave = head.
// ------------------------------------------------------------------
__global__ __launch_bounds__(256) void k_attn4(
    const ushort_t* __restrict__ qkv, const float* __restrict__ rpb,
    float* __restrict__ out)
{
    // uints: Q[0,4352) K[4352,8704) VT[8704,13056) rpb[13056,13956)
    // P aliases [0,8704): head h at h*2176, row stride 34 uints (68 sh).
    __shared__ uint_t lds[13956];
    ushort_t* lds_sh = (ushort_t*)lds;
    float* rpbl = (float*)(lds + 13056);
    const int t = threadIdx.x;
    const int b = blockIdx.x >> 8, wy = (blockIdx.x >> 4) & 15, wx = blockIdx.x & 15;
    const int prow0 = (b << 14) + (wy * 8) * 128 + wx * 8;
    const uint_t* qkvu = (const uint_t*)qkv;

    // ---- stage Q,K rows (68-uint stride) + V transposed (VT[d][m])
    for (int i = t; i < 4096; i += 256) {
        const int m = i >> 6, u = i & 63;
        const size_t pr = (size_t)(prow0 + (m >> 3) * 128 + (m & 7)) * 192;
        lds[m * 68 + u]        = qkvu[pr + u];
        lds[4352 + m * 68 + u] = qkvu[pr + 64 + u];
        const uint_t v = qkvu[pr + 128 + u];
        lds_sh[17408 + (2 * u) * 68 + m]     = (ushort_t)(v & 0xffffu);
        lds_sh[17408 + (2 * u + 1) * 68 + m] = (ushort_t)(v >> 16);
    }
    for (int i = t; i < 900; i += 256) rpbl[i] = rpb[i];
    __syncthreads();

    const int h = t >> 6, l = t & 63;
    const int lr = l & 15, lg = l >> 4;

    // ---- QK^T: 16 MFMAs
    short8 af_k[4], bf_q[4];
#pragma unroll
    for (int i = 0; i < 4; ++i) {
        af_k[i] = *(const short8*)&lds_sh[8704 + (i * 16 + lr) * 136 + h * 32 + lg * 8];
        bf_q[i] = *(const short8*)&lds_sh[(i * 16 + lr) * 136 + h * 32 + lg * 8];
    }
    f32x4 sA[4][4];   // [nt][mt]
#pragma unroll
    for (int nt = 0; nt < 4; ++nt)
#pragma unroll
        for (int mt = 0; mt < 4; ++mt)
            sA[nt][mt] = __builtin_amdgcn_mfma_f32_16x16x32_bf16(
                af_k[mt], bf_q[nt], (f32x4){0.f, 0.f, 0.f, 0.f}, 0, 0, 0);

    // ---- softmax per row n (lane owns n = nt*16+lr; m split over lg)
    float inv[4];
#pragma unroll
    for (int nt = 0; nt < 4; ++nt) {
        const int n = nt * 16 + lr;
        const int ry = n >> 3, rx = n & 7;
        float mxv = -1e30f;
#pragma unroll
        for (int mt = 0; mt < 4; ++mt)
#pragma unroll
            for (int r = 0; r < 4; ++r) {
                const int m = mt * 16 + lg * 4 + r;
                const float bias =
                    rpbl[((ry - (m >> 3) + 7) * 15 + (rx - (m & 7) + 7)) * 4 + h];
                const float s = sA[nt][mt][r] * SCALE + bias;
                sA[nt][mt][r] = s;
                mxv = fmaxf(mxv, s);
            }
        mxv = fmaxf(mxv, __shfl_xor(mxv, 16));
        mxv = fmaxf(mxv, __shfl_xor(mxv, 32));
        float ls = 0.f;
#pragma unroll
        for (int mt = 0; mt < 4; ++mt)
#pragma unroll
            for (int r = 0; r < 4; ++r) {
                const float e = __expf(sA[nt][mt][r] - mxv);
                sA[nt][mt][r] = e;
                ls += e;
            }
        ls += __shfl_xor(ls, 16);
        ls += __shfl_xor(ls, 32);
        inv[nt] = 1.f / ls;
    }

    __syncthreads();   // all waves done reading Q/K before P overwrites

    // ---- P (bf16) into LDS, row n stride 34 uints
    uint_t* Pb = lds + h * 2176;
#pragma unroll
    for (int nt = 0; nt < 4; ++nt) {
        const int n = nt * 16 + lr;
#pragma unroll
        for (int mt = 0; mt < 4; ++mt) {
            uint2 o;
            o.x = pack2(sA[nt][mt][0], sA[nt][mt][1]);
            o.y = pack2(sA[nt][mt][2], sA[nt][mt][3]);
            *(uint2*)&Pb[n * 34 + mt * 8 + lg * 2] = o;
        }
    }
    asm volatile("s_waitcnt lgkmcnt(0)" ::: "memory");

    // ---- PV: O = mfma(A=VT rows d, B=P rows n), K=64 (2 steps)
    union U8 { short8 s8; uint2 u2[2]; };
    f32x4 oA[2][4];
#pragma unroll
    for (int dt = 0; dt < 2; ++dt)
#pragma unroll
        for (int nt = 0; nt < 4; ++nt) oA[dt][nt] = (f32x4){0.f, 0.f, 0.f, 0.f};
#pragma unroll
    for (int ks = 0; ks < 2; ++ks) {
        const int kb = ks * 4 + lg;
        short8 av[2], bp[4];
#pragma unroll
        for (int dt = 0; dt < 2; ++dt) {
            U8 u;
            const int d = h * 32 + dt * 16 + lr;
            u.u2[0] = *(const uint2*)&lds[8704 + d * 34 + kb * 4];
            u.u2[1] = *(const uint2*)&lds[8704 + d * 34 + kb * 4 + 2];
            av[dt] = u.s8;
        }
#pragma unroll
        for (int nt = 0; nt < 4; ++nt) {
            U8 u;
            const int n = nt * 16 + lr;
            u.u2[0] = *(const uint2*)&Pb[n * 34 + kb * 4];
            u.u2[1] = *(const uint2*)&Pb[n * 34 + kb * 4 + 2];
            bp[nt] = u.s8;
        }
#pragma unroll
        for (int dt = 0; dt < 2; ++dt)
#pragma unroll
            for (int nt = 0; nt < 4; ++nt)
                oA[dt][nt] = __builtin_amdgcn_mfma_f32_16x16x32_bf16(
                    av[dt], bp[nt], oA[dt][nt], 0, 0, 0);
    }

    // ---- write raw xa channel-major: out[b][h*32+d][pix(n)]
    float* ob = out + ((size_t)b << 21);
    const int pixbase = (wy * 8) * 128 + wx * 8;
#pragma unroll
    for (int dt = 0; dt < 2; ++dt)
#pragma unroll
        for (int nt = 0; nt < 4; ++nt) {
            const int n = nt * 16 + lr;
            const size_t po = (size_t)(pixbase + (n >> 3) * 128 + (n & 7));
            const float iv = inv[nt];
#pragma unroll
            for (int r = 0; r < 4; ++r) {
                const int d = h * 32 + dt * 16 + lg * 4 + r;
                ob[((size_t)d << 14) + po] = oA[dt][nt][r] * iv;
            }
        }
}

// ------------------------------------------------------------------
// k_proj (MFMA, in-place on out): out[b][j][p] =
//    rate1 * ( sum_c xa[b][c][p] * pw[c][j] + pb[j] ), xa = current out.
// ------------------------------------------------------------------
__global__ __launch_bounds__(256) void k_proj(
    const float* __restrict__ pw, const float* __restrict__ pb,
    const float* __restrict__ r1, float* __restrict__ out)
{
    __shared__ ushort_t XT[128 * 128];  // xa^T [p][c] swizzled
    __shared__ ushort_t WT[128 * 128];  // pw^T [j][c] swizzled
    const int t = threadIdx.x;
    const int p0 = blockIdx.x * 128;
    const int b = p0 >> 14;
    const int rem = p0 & 16383;
    const float* xb = out + ((size_t)b << 21) + rem;

    // ---- stage XT from out (xa), coalesced along p
#pragma unroll
    for (int it = 0; it < 8; ++it) {
        const int slot = it * 256 + t;
        const int p = slot & 127, cb = slot >> 7;
        uint4 u;
        {
            const float a0 = xb[(size_t)(cb * 8 + 0) * 16384 + p];
            const float a1 = xb[(size_t)(cb * 8 + 1) * 16384 + p];
            const float a2 = xb[(size_t)(cb * 8 + 2) * 16384 + p];
            const float a3 = xb[(size_t)(cb * 8 + 3) * 16384 + p];
            const float a4 = xb[(size_t)(cb * 8 + 4) * 16384 + p];
            const float a5 = xb[(size_t)(cb * 8 + 5) * 16384 + p];
            const float a6 = xb[(size_t)(cb * 8 + 6) * 16384 + p];
            const float a7 = xb[(size_t)(cb * 8 + 7) * 16384 + p];
            u.x = pack2(a0, a1); u.y = pack2(a2, a3);
            u.z = pack2(a4, a5); u.w = pack2(a6, a7);
        }
        *(uint4*)&XT[p * 128 + ((cb ^ (p & 7)) << 3)] = u;
    }
    // ---- stage WT from pw (128x128), coalesced along j
#pragma unroll
    for (int it = 0; it < 8; ++it) {
        const int slot = it * 256 + t;
        const int j = slot & 127, cb = slot >> 7;
        uint4 u;
        {
            const float a0 = pw[(size_t)(cb * 8 + 0) * 128 + j];
            const float a1 = pw[(size_t)(cb * 8 + 1) * 128 + j];
            const float a2 = pw[(size_t)(cb * 8 + 2) * 128 + j];
            const float a3 = pw[(size_t)(cb * 8 + 3) * 128 + j];
            const float a4 = pw[(size_t)(cb * 8 + 4) * 128 + j];
            const float a5 = pw[(size_t)(cb * 8 + 5) * 128 + j];
            const float a6 = pw[(size_t)(cb * 8 + 6) * 128 + j];
            const float a7 = pw[(size_t)(cb * 8 + 7) * 128 + j];
            u.x = pack2(a0, a1); u.y = pack2(a2, a3);
            u.z = pack2(a4, a5); u.w = pack2(a6, a7);
        }
        *(uint4*)&WT[j * 128 + ((cb ^ (j & 7)) << 3)] = u;
    }
    __syncthreads();   // all global reads of this block's pixels complete here

    const int l = t & 63, wv = t >> 6;
    const int wj = (wv >> 1) * 64, wp = (wv & 1) * 64;
    const int lr = l & 15, lg = l >> 4;

    f32x4 acc[4][4];
#pragma unroll
    for (int i = 0; i < 4; ++i)
#pragma unroll
        for (int j = 0; j < 4; ++j) acc[i][j] = (f32x4){0.f, 0.f, 0.f, 0.f};

#pragma unroll
    for (int ks = 0; ks < 4; ++ks) {
        const int kb = ks * 4 + lg;
        short8 af[4], bf[4];
#pragma unroll
        for (int i = 0; i < 4; ++i) {
            const int jr = wj + i * 16 + lr;
            af[i] = *(const short8*)&WT[jr * 128 + ((kb ^ (jr & 7)) << 3)];
            const int pr = wp + i * 16 + lr;
            bf[i] = *(const short8*)&XT[pr * 128 + ((kb ^ (pr & 7)) << 3)];
        }
#pragma unroll
        for (int ji = 0; ji < 4; ++ji)
#pragma unroll
            for (int pi = 0; pi < 4; ++pi)
                acc[ji][pi] = __builtin_amdgcn_mfma_f32_16x16x32_bf16(
                    af[ji], bf[pi], acc[ji][pi], 0, 0, 0);
    }

    const float rate1 = r1[0];
    float* obase = out + ((size_t)b << 21) + rem;
    // lane holds j = jq..jq+3 at pixel p; stores are 16-lane p-contiguous
#pragma unroll
    for (int ji = 0; ji < 4; ++ji) {
        const int jq = wj + ji * 16 + 4 * lg;
        const float4 bias = *(const float4*)&pb[jq];
#pragma unroll
        for (int pi = 0; pi < 4; ++pi) {
            const int p = wp + pi * 16 + lr;
            float* op = obase + (size_t)jq * 16384 + p;
            op[0]     = rate1 * (acc[ji][pi][0] + bias.x);
            op[16384] = rate1 * (acc[ji][pi][1] + bias.y);
            op[32768] = rate1 * (acc[ji][pi][2] + bias.z);
            op[49152] = rate1 * (acc[ji][pi][3] + bias.w);
        }
    }
}

// ------------------------------------------------------------------
// k_conv7: conv6 (bf16 fcl, zero conflicts) with the 8 chunks SPLIT
// across 2 blocks (4 chunks each) -> grid 1024, 4+ blocks/CU
// co-resident (the 512-block grid was the occupancy cap).
// ------------------------------------------------------------------
__global__ __launch_bounds__(256) void k_conv7(
    const ushort_t* __restrict__ qkv, const float* __restrict__ fcw,
    const float* __restrict__ fcb, const float* __restrict__ depw,
    const float* __restrict__ depb, const float* __restrict__ r2,
    float* __restrict__ out)
{
    __shared__ ushort_t fcl[11664];             // [(ii*4+dd)*324 + pix] bf16
    __shared__ __align__(16) float dwl[1296];   // [kk81][16 oc-in-chunk]
    __shared__ float fcwl[108];
    __shared__ float fcbl[9];

    const int t = threadIdx.x;
    const int half = blockIdx.x & 1;
    const int tile = (blockIdx.x >> 1) & 63;
    const int b = blockIdx.x >> 7;
    const int ty0 = (tile >> 3) << 4, tx0 = (tile & 7) << 4;
    if (t < 108) fcwl[t] = fcw[t];
    if (t < 9)   fcbl[t] = fcb[t];
    const float rate2 = r2[0];
    const int py = t >> 4, px = t & 15;
    float* ob = out + ((size_t)b << 21) + (size_t)((ty0 + py) * 128 + (tx0 + px));

    // this thread's halo pixels: pix0 = t, pix1 = 256+t (t<68)
    const int row0 = t / 18, col0 = t - row0 * 18;
    const int hy0 = ty0 + row0 - 1, hx0 = tx0 + col0 - 1;
    const int g0 = ((unsigned)hy0 < 128u && (unsigned)hx0 < 128u)
                       ? ((b << 14) + hy0 * 128 + hx0) : -1;
    const int t1 = t + 256, row1 = t1 / 18, col1 = t1 - row1 * 18;
    const int hy1 = ty0 + row1 - 1, hx1 = tx0 + col1 - 1;
    const int g1 = (t < 68 && (unsigned)hy1 < 128u && (unsigned)hx1 < 128u)
                       ? ((b << 14) + hy1 * 128 + hx1) : -1;

    for (int ci = 0; ci < 4; ++ci) {
        const int chunk = half * 4 + ci;
        __syncthreads();   // fcwl visible (ci 0) / prior conv reads done
        for (int i = t; i < 1296; i += 256)
            dwl[i] = depw[(chunk * 16 + (i & 15)) * 81 + (i >> 4)];

#pragma unroll
        for (int hf = 0; hf < 2; ++hf) {
            const int g = hf ? g1 : g0;
            const int pix = hf ? (256 + t) : t;
            if (hf && t >= 68) break;
            float fo[9][4];
#pragma unroll
            for (int ii = 0; ii < 9; ++ii) {
                const float bv = (g >= 0) ? fcbl[ii] : 0.f;
                fo[ii][0] = bv; fo[ii][1] = bv; fo[ii][2] = bv; fo[ii][3] = bv;
            }
            if (g >= 0) {
                const uint2* qp = (const uint2*)(qkv + (size_t)g * 384 + chunk * 4);
#pragma unroll
                for (int e = 0; e < 12; ++e) {
                    const uint2 q = qp[e * 8];
                    const float f0 = blo(q.x), f1 = bhi(q.x);
                    const float f2 = blo(q.y), f3 = bhi(q.y);
#pragma unroll
                    for (int ii = 0; ii < 9; ++ii) {
                        const float wv = fcwl[ii * 12 + e];
                        fo[ii][0] += wv * f0; fo[ii][1] += wv * f1;
                        fo[ii][2] += wv * f2; fo[ii][3] += wv * f3;
                    }
                }
            }
#pragma unroll
            for (int ii = 0; ii < 9; ++ii)
#pragma unroll
                for (int dd = 0; dd < 4; ++dd)
                    fcl[(ii * 4 + dd) * 324 + pix] = f2u(fo[ii][dd]);
        }
        __syncthreads();

        float4 accv[4];
#pragma unroll
        for (int dd = 0; dd < 4; ++dd) accv[dd] = make_float4(0.f, 0.f, 0.f, 0.f);
#pragma unroll
        for (int ii = 0; ii < 9; ++ii) {
#pragma unroll
            for (int kk = 0; kk < 9; ++kk) {
                const int ky = kk / 3, kx = kk - (kk / 3) * 3;
                const int hpix = (py + ky) * 18 + px + kx;
                const float4* dwp = (const float4*)&dwl[(ii * 9 + kk) * 16];
#pragma unroll
                for (int dd = 0; dd < 4; ++dd) {
                    const float f = u2f(fcl[(ii * 4 + dd) * 324 + hpix]);
                    const float4 d4 = dwp[dd];
                    accv[dd].x += f * d4.x; accv[dd].y += f * d4.y;
                    accv[dd].z += f * d4.z; accv[dd].w += f * d4.w;
                }
            }
        }
#pragma unroll
        for (int dd = 0; dd < 4; ++dd) {
            const float av[4] = {accv[dd].x, accv[dd].y, accv[dd].z, accv[dd].w};
#pragma unroll
            for (int j = 0; j < 4; ++j) {
                const int oc = chunk * 16 + dd * 4 + j;
                ob[(size_t)oc << 14] += rate2 * (av[j] + depb[oc]);
            }
        }
    }
}

// ==================================================================
// FALLBACK PATH (ws too small): round-5 kernels, verbatim.
// ==================================================================
#define WS_W2  0
#define WS_B2  36864
#define WS_TOT 37152

__global__ __launch_bounds__(256) void k_prep_f(
    const float* __restrict__ qkv_w, const float* __restrict__ qkv_b,
    const float* __restrict__ fcw, const float* __restrict__ fcb,
    float* __restrict__ ws)
{
    const int idx = blockIdx.x * 256 + threadIdx.x;
    if (idx < WS_B2) {
        const int c = idx / 288, r = idx - c * 288, i = r >> 5, d = r & 31;
        float s = 0.f;
#pragma unroll
        for (int e = 0; e < 12; ++e)
            s += fcw[i * 12 + e] * qkv_w[c * 384 + e * 32 + d];
        ws[idx] = s;
    } else if (idx < WS_TOT) {
        const int r = idx - WS_B2, i = r >> 5, d = r & 31;
        float s = fcb[i];
#pragma unroll
        for (int e = 0; e < 12; ++e)
            s += fcw[i * 12 + e] * qkv_b[e * 32 + d];
        ws[idx] = s;
    }
}

__global__ __launch_bounds__(256) void k_attn_f(
    const float* __restrict__ x, const float* __restrict__ qw,
    const float* __restrict__ qb, const float* __restrict__ pw,
    const float* __restrict__ pb, const float* __restrict__ rpb,
    const float* __restrict__ r1, float* __restrict__ out)
{
    __shared__ ushort_t xw[8192];
    __shared__ float arena[8450];
    ushort_t* kvb = (ushort_t*)arena;
    const int t = threadIdx.x;
    const int b = blockIdx.x >> 8, wy = (blockIdx.x >> 4) & 15, wx = blockIdx.x & 15;
    const size_t xbase = ((size_t)b << 21) + (size_t)((wy * 8) * 128 + wx * 8);
    for (int i = t; i < 8192; i += 256) {
        const int c = i >> 6, p = i & 63;
        xw[i] = f2u(x[xbase + (size_t)c * 16384 + (p >> 3) * 128 + (p & 7)]);
    }
    __syncthreads();
    const int h = t >> 6, n = t & 63;
    float qa[32], ka[32], va[32];
#pragma unroll
    for (int cc = 0; cc < 32; ++cc) {
        qa[cc] = qb[h * 32 + cc];
        ka[cc] = qb[128 + h * 32 + cc];
        va[cc] = qb[256 + h * 32 + cc];
    }
    const float* wbase = qw + h * 32;
    for (int c = 0; c < 128; ++c) {
        const float xv = u2f(xw[c * 64 + n]);
        const float* wr = wbase + c * 384;
#pragma unroll
        for (int j = 0; j < 8; ++j) {
            const float4 aq = ((const float4*)wr)[j];
            const float4 ak = ((const float4*)(wr + 128))[j];
            const float4 av = ((const float4*)(wr + 256))[j];
            qa[4 * j + 0] += xv * aq.x; qa[4 * j + 1] += xv * aq.y;
            qa[4 * j + 2] += xv * aq.z; qa[4 * j + 3] += xv * aq.w;
            ka[4 * j + 0] += xv * ak.x; ka[4 * j + 1] += xv * ak.y;
            ka[4 * j + 2] += xv * ak.z; ka[4 * j + 3] += xv * ak.w;
            va[4 * j + 0] += xv * av.x; va[4 * j + 1] += xv * av.y;
            va[4 * j + 2] += xv * av.z; va[4 * j + 3] += xv * av.w;
        }
    }
#pragma unroll
    for (int cc = 0; cc < 32; ++cc) qa[cc] *= SCALE;
    uint_t* kv32 = (uint_t*)kvb;
#pragma unroll
    for (int j = 0; j < 16; ++j) {
        kv32[n * 66 + h * 16 + j] = pack2(ka[2 * j], ka[2 * j + 1]);
        kv32[4224 + n * 66 + h * 16 + j] = pack2(va[2 * j], va[2 * j + 1]);
    }
    __syncthreads();
    const int ry = n >> 3, rx = n & 7;
    float sar[64];
    float mx = -1e30f;
#pragma unroll
    for (int m = 0; m < 64; ++m) {
        const uint2* kr = (const uint2*)(kvb + m * 132 + h * 32);
        float s = 0.f;
#pragma unroll
        for (int j = 0; j < 8; ++j) {
            const uint2 u = kr[j];
            s += qa[4 * j + 0] * blo(u.x) + qa[4 * j + 1] * bhi(u.x)
               + qa[4 * j + 2] * blo(u.y) + qa[4 * j + 3] * bhi(u.y);
        }
        s += rpb[((ry - (m >> 3) + 7) * 15 + (rx - (m & 7) + 7)) * 4 + h];
        sar[m] = s;
        mx = fmaxf(mx, s);
    }
    float l = 0.f;
#pragma unroll
    for (int m = 0; m < 64; ++m) { const float e = __expf(sar[m] - mx); sar[m] = e; l += e; }
    const float inv = 1.f / l;
    float acc[32];
#pragma unroll
    for (int cc = 0; cc < 32; ++cc) acc[cc] = 0.f;
#pragma unroll
    for (int m = 0; m < 64; ++m) {
        const float pm = sar[m];
        const uint2* vr = (const uint2*)(kvb + 8448 + m * 132 + h * 32);
#pragma unroll
        for (int j = 0; j < 8; ++j) {
            const uint2 u = vr[j];
            acc[4 * j + 0] += pm * blo(u.x); acc[4 * j + 1] += pm * bhi(u.x);
            acc[4 * j + 2] += pm * blo(u.y); acc[4 * j + 3] += pm * bhi(u.y);
        }
    }
    __syncthreads();
#pragma unroll
    for (int cc = 0; cc < 32; ++cc) arena[n * 130 + h * 32 + cc] = acc[cc] * inv;
    __syncthreads();
    const int p = t & 63, jb = t >> 6;
    float aj[32];
#pragma unroll
    for (int jj = 0; jj < 32; ++jj) aj[jj] = pb[jb * 32 + jj];
    const float* xr = arena + p * 130;
    const float* pwb = pw + jb * 32;
    for (int c = 0; c < 128; ++c) {
        const float xv = xr[c];
        const float4* pr = (const float4*)(pwb + c * 128);
#pragma unroll
        for (int j = 0; j < 8; ++j) {
            const float4 w4 = pr[j];
            aj[4 * j + 0] += xv * w4.x; aj[4 * j + 1] += xv * w4.y;
            aj[4 * j + 2] += xv * w4.z; aj[4 * j + 3] += xv * w4.w;
        }
    }
    const float rate1 = r1[0];
    const int oy = wy * 8 + (p >> 3), ox = wx * 8 + (p & 7);
    float* ob = out + ((size_t)b << 21) + (size_t)(oy * 128 + ox);
#pragma unroll
    for (int jj = 0; jj < 32; ++jj)
        ob[(size_t)(jb * 32 + jj) << 14] = rate1 * aj[jj];
}

__global__ __launch_bounds__(256) void k_conv_f(
    const float* __restrict__ x, const float* __restrict__ ws,
    const float* __restrict__ depw, const float* __restrict__ depb,
    const float* __restrict__ r2, float* __restrict__ out)
{
    __shared__ float arena[12960];
    __shared__ float b2s[36];
    float* w2l = arena;
    ushort_t* xl = (ushort_t*)(arena + 4608);
    float* fcl = arena;
    float* dwl = arena + 11664;
    const int t = threadIdx.x;
    const int b = blockIdx.x >> 6, tile = blockIdx.x & 63;
    const int ty0 = (tile >> 3) << 4, tx0 = (tile & 7) << 4;
    const size_t xbase = ((size_t)b << 21);
    const float rate2 = r2[0];
    const int py = t >> 4, px = t & 15;
    float* ob = out + ((size_t)b << 21) + (size_t)((ty0 + py) * 128 + (tx0 + px));
    const int r0 = t / 18, c0 = t - r0 * 18;
    const bool ok0 = ((unsigned)(ty0 + r0 - 1) < 128u) && ((unsigned)(tx0 + c0 - 1) < 128u);
    const int t1 = 256 + t, r1i = t1 / 18, c1 = t1 - r1i * 18;
    const bool ok1 = (t < 68) && ((unsigned)(ty0 + r1i - 1) < 128u) && ((unsigned)(tx0 + c1 - 1) < 128u);
    for (int chunk = 0; chunk < 8; ++chunk) {
        __syncthreads();
        for (int i = t; i < 4608; i += 256) {
            const int c = i / 36, r = i - c * 36;
            w2l[i] = ws[WS_W2 + c * 288 + (r >> 2) * 32 + chunk * 4 + (r & 3)];
        }
        if (t < 36) b2s[t] = ws[WS_B2 + (t >> 2) * 32 + chunk * 4 + (t & 3)];
        __syncthreads();
        float fca[2][36];
#pragma unroll
        for (int r = 0; r < 36; ++r) { fca[0][r] = b2s[r]; fca[1][r] = b2s[r]; }
        for (int cs = 0; cs < 8; ++cs) {
            if (cs) __syncthreads();
            for (int i = t; i < 5184; i += 256) {
                const int cc = i / 324, pp = i - cc * 324;
                const int row = pp / 18, col = pp - row * 18;
                const int hy = ty0 + row - 1, hx = tx0 + col - 1;
                ushort_t v = 0;
                if ((unsigned)hy < 128u && (unsigned)hx < 128u)
                    v = f2u(x[xbase + (size_t)(cs * 16 + cc) * 16384 + hy * 128 + hx]);
                xl[i] = v;
            }
            __syncthreads();
#pragma unroll 4
            for (int cc = 0; cc < 16; ++cc) {
                const float xv0 = u2f(xl[cc * 324 + t]);
                const float xv1 = (t < 68) ? u2f(xl[cc * 324 + 256 + t]) : 0.f;
                const float* wr = w2l + (cs * 16 + cc) * 36;
#pragma unroll
                for (int r = 0; r < 36; r += 4) {
                    const float4 w4 = *(const float4*)(wr + r);
                    fca[0][r + 0] += xv0 * w4.x; fca[0][r + 1] += xv0 * w4.y;
                    fca[0][r + 2] += xv0 * w4.z; fca[0][r + 3] += xv0 * w4.w;
                    fca[1][r + 0] += xv1 * w4.x; fca[1][r + 1] += xv1 * w4.y;
                    fca[1][r + 2] += xv1 * w4.z; fca[1][r + 3] += xv1 * w4.w;
                }
            }
        }
        __syncthreads();
#pragma unroll
        for (int r = 0; r < 36; ++r) {
            fcl[r * 324 + t] = ok0 ? fca[0][r] : 0.f;
            if (t < 68) fcl[r * 324 + 256 + t] = ok1 ? fca[1][r] : 0.f;
        }
        for (int i = t; i < 1296; i += 256) {
            const int kk = i >> 4, ocl = i & 15;
            dwl[i] = depw[(chunk * 16 + ocl) * 81 + kk];
        }
        __syncthreads();
        float4 accv[4];
#pragma unroll
        for (int dd = 0; dd < 4; ++dd) accv[dd] = make_float4(0.f, 0.f, 0.f, 0.f);
#pragma unroll
        for (int ii = 0; ii < 9; ++ii) {
#pragma unroll
            for (int kk = 0; kk < 9; ++kk) {
                const int ky = kk / 3, kx = kk - (kk / 3) * 3;
                const int hpix = (py + ky) * 18 + px + kx;
                const float4* dwp = (const float4*)&dwl[(ii * 9 + kk) * 16];
#pragma unroll
                for (int dd = 0; dd < 4; ++dd) {
                    const float f = fcl[(ii * 4 + dd) * 324 + hpix];
                    const float4 d4 = dwp[dd];
                    accv[dd].x += f * d4.x; accv[dd].y += f * d4.y;
                    accv[dd].z += f * d4.z; accv[dd].w += f * d4.w;
                }
            }
        }
#pragma unroll
        for (int dd = 0; dd < 4; ++dd) {
            const float av[4] = {accv[dd].x, accv[dd].y, accv[dd].z, accv[dd].w};
#pragma unroll
            for (int j = 0; j < 4; ++j) {
                const int oc = chunk * 16 + dd * 4 + j;
                ob[(size_t)oc << 14] += rate2 * (av[j] + depb[oc]);
            }
        }
    }
}

// ------------------------------------------------------------------
extern "C" void kernel_launch(void* const* d_in, const int* in_sizes, int n_in,
                              void* d_out, int out_size, void* d_ws, size_t ws_size,
                              hipStream_t stream) {
    (void)in_sizes; (void)n_in; (void)out_size;
    const float* x      = (const float*)d_in[0];
    const float* qkv_w  = (const float*)d_in[1];
    const float* qkv_b  = (const float*)d_in[2];
    const float* proj_w = (const float*)d_in[3];
    const float* proj_b = (const float*)d_in[4];
    const float* rpb    = (const float*)d_in[5];
    const float* fc_w   = (const float*)d_in[6];
    const float* fc_b   = (const float*)d_in[7];
    const float* dep_w  = (const float*)d_in[8];
    const float* dep_b  = (const float*)d_in[9];
    const float* rate1  = (const float*)d_in[10];
    const float* rate2  = (const float*)d_in[11];
    float* out = (float*)d_out;

    if (ws_size >= (size_t)131072 * 384 * 2) {
        ushort_t* qkv = (ushort_t*)d_ws;   // 96 MB bf16
        k_qqkv<<<dim3(1024), dim3(256), 0, stream>>>(x, qkv_w, qkv_b, qkv);
        k_attn4<<<dim3(2048), dim3(256), 0, stream>>>(qkv, rpb, out);
        k_proj<<<dim3(1024), dim3(256), 0, stream>>>(proj_w, proj_b, rate1, out);
        k_conv7<<<dim3(1024), dim3(256), 0, stream>>>(qkv, fc_w, fc_b, dep_w,
                                                      dep_b, rate2, out);
    } else {
        float* wsf = (float*)d_ws;         // 148.6 KB
        k_prep_f<<<dim3(146), dim3(256), 0, stream>>>(qkv_w, qkv_b, fc_w, fc_b, wsf);
        k_attn_f<<<dim3(2048), dim3(256), 0, stream>>>(x, qkv_w, qkv_b, proj_w,
                                                       proj_b, rpb, rate1, out);
        k_conv_f<<<dim3(512), dim3(256), 0, stream>>>(x, wsf, dep_w, dep_b,
                                                      rate2, out);
    }
}

// Round 13
// 411.856 us; speedup vs baseline: 1.5624x; 1.0483x over previous
//
#include <hip/hip_runtime.h>

typedef unsigned short ushort_t;
typedef unsigned int uint_t;
typedef __attribute__((ext_vector_type(8))) short short8;
typedef __attribute__((ext_vector_type(4))) float f32x4;

#define SCALE 0.17677669529663687f
#define QC_PLANE ((size_t)131072 * 48)

__device__ __forceinline__ float blo(uint_t u) { return __uint_as_float(u << 16); }
__device__ __forceinline__ float bhi(uint_t u) { return __uint_as_float(u & 0xffff0000u); }
__device__ __forceinline__ float u2f(ushort_t u) { return __uint_as_float(((uint_t)u) << 16); }
// fp32 -> bf16 (RNE), finite inputs
__device__ __forceinline__ ushort_t f2u(float f) {
    const uint_t x = __float_as_uint(f);
    return (ushort_t)((x + 0x7fffu + ((x >> 16) & 1u)) >> 16);
}
__device__ __forceinline__ uint_t pack2(float a, float b) {
    return (uint_t)f2u(a) | ((uint_t)f2u(b) << 16);
}

__device__ __forceinline__ float dot8(const float* qa, uint4 u) {
    return qa[0] * blo(u.x) + qa[1] * bhi(u.x) + qa[2] * blo(u.y) + qa[3] * bhi(u.y)
         + qa[4] * blo(u.z) + qa[5] * bhi(u.z) + qa[6] * blo(u.w) + qa[7] * bhi(u.w);
}
__device__ __forceinline__ void pv8(float* a, float e, uint4 u) {
    a[0] += e * blo(u.x); a[1] += e * bhi(u.x); a[2] += e * blo(u.y); a[3] += e * bhi(u.y);
    a[4] += e * blo(u.z); a[5] += e * bhi(u.z); a[6] += e * blo(u.w); a[7] += e * bhi(u.w);
}

// ==================================================================
// MAIN PATH: qkv materialized in ws as bf16 [p][j], p=131072, j=384.
// If ws >= 192 MB, also a dense conv copy qc[chunk][p][48] (bf16).
// ==================================================================

// ------------------------------------------------------------------
// k_qqkv (MFMA): qkv[p, j] = bf16( sum_c x[b,c,p]*qkv_w[c,j] + qkv_b[j] )
// Block = 128 pixels x all 384 j (3 j-tiles of 128), K=128.
// If qc != nullptr, also stores the conv-dense permutation.
// ------------------------------------------------------------------
__global__ __launch_bounds__(256) void k_qqkv(
    const float* __restrict__ x, const float* __restrict__ w,
    const float* __restrict__ wb, ushort_t* __restrict__ qkv,
    ushort_t* __restrict__ qc)
{
    __shared__ ushort_t XT[128 * 128];  // [p][c] swizzled
    __shared__ ushort_t WT[128 * 128];  // [j][c] swizzled; reused as D [p][j]
    const int t = threadIdx.x;
    const int p0 = blockIdx.x * 128;
    const int b = p0 >> 14;             // HW = 16384
    const int rem = p0 & 16383;
    const float* xb = x + ((size_t)b << 21) + rem;

    // ---- stage XT: x[c][p] -> bf16 XT[p][c] (coalesced reads along p)
#pragma unroll
    for (int it = 0; it < 8; ++it) {
        const int slot = it * 256 + t;
        const int p = slot & 127, cb = slot >> 7;   // cb = 16B block along c
        uint4 u;
        {
            const float a0 = xb[(size_t)(cb * 8 + 0) * 16384 + p];
            const float a1 = xb[(size_t)(cb * 8 + 1) * 16384 + p];
            const float a2 = xb[(size_t)(cb * 8 + 2) * 16384 + p];
            const float a3 = xb[(size_t)(cb * 8 + 3) * 16384 + p];
            const float a4 = xb[(size_t)(cb * 8 + 4) * 16384 + p];
            const float a5 = xb[(size_t)(cb * 8 + 5) * 16384 + p];
            const float a6 = xb[(size_t)(cb * 8 + 6) * 16384 + p];
            const float a7 = xb[(size_t)(cb * 8 + 7) * 16384 + p];
            u.x = pack2(a0, a1); u.y = pack2(a2, a3);
            u.z = pack2(a4, a5); u.w = pack2(a6, a7);
        }
        *(uint4*)&XT[p * 128 + ((cb ^ (p & 7)) << 3)] = u;
    }

    const int l = t & 63, wv = t >> 6;
    const int wj = (wv >> 1) * 64, wp = (wv & 1) * 64;
    const int lr = l & 15, lg = l >> 4;

    for (int jt = 0; jt < 3; ++jt) {
        const int j0 = jt * 128;
        __syncthreads();   // XT ready (jt=0) / prior D drained (jt>0)

        // ---- stage WT: w[c][j0+j] -> bf16 WT[j][c] (coalesced along j; L2-hot)
#pragma unroll
        for (int it = 0; it < 8; ++it) {
            const int slot = it * 256 + t;
            const int j = slot & 127, cb = slot >> 7;
            uint4 u;
            {
                const float a0 = w[(size_t)(cb * 8 + 0) * 384 + j0 + j];
                const float a1 = w[(size_t)(cb * 8 + 1) * 384 + j0 + j];
                const float a2 = w[(size_t)(cb * 8 + 2) * 384 + j0 + j];
                const float a3 = w[(size_t)(cb * 8 + 3) * 384 + j0 + j];
                const float a4 = w[(size_t)(cb * 8 + 4) * 384 + j0 + j];
                const float a5 = w[(size_t)(cb * 8 + 5) * 384 + j0 + j];
                const float a6 = w[(size_t)(cb * 8 + 6) * 384 + j0 + j];
                const float a7 = w[(size_t)(cb * 8 + 7) * 384 + j0 + j];
                u.x = pack2(a0, a1); u.y = pack2(a2, a3);
                u.z = pack2(a4, a5); u.w = pack2(a6, a7);
            }
            *(uint4*)&WT[j * 128 + ((cb ^ (j & 7)) << 3)] = u;
        }
        __syncthreads();

        f32x4 acc[4][4];
#pragma unroll
        for (int i = 0; i < 4; ++i)
#pragma unroll
            for (int j = 0; j < 4; ++j) acc[i][j] = (f32x4){0.f, 0.f, 0.f, 0.f};

#pragma unroll
        for (int ks = 0; ks < 4; ++ks) {
            const int kb = ks * 4 + lg;
            short8 af[4], bf[4];
#pragma unroll
            for (int i = 0; i < 4; ++i) {
                const int jr = wj + i * 16 + lr;
                af[i] = *(const short8*)&WT[jr * 128 + ((kb ^ (jr & 7)) << 3)];
                const int pr = wp + i * 16 + lr;
                bf[i] = *(const short8*)&XT[pr * 128 + ((kb ^ (pr & 7)) << 3)];
            }
#pragma unroll
            for (int ji = 0; ji < 4; ++ji)
#pragma unroll
                for (int pi = 0; pi < 4; ++pi)
                    acc[ji][pi] = __builtin_amdgcn_mfma_f32_16x16x32_bf16(
                        af[ji], bf[pi], acc[ji][pi], 0, 0, 0);
        }
        __syncthreads();   // all WT reads done before D overwrite

        // ---- D write: lane holds 4 consecutive j at fixed p per acc tile
#pragma unroll
        for (int ji = 0; ji < 4; ++ji) {
            const int jq = wj + ji * 16 + 4 * lg;            // local j quad base
            const float4 bias = *(const float4*)&wb[j0 + jq];
#pragma unroll
            for (int pi = 0; pi < 4; ++pi) {
                const int p = wp + pi * 16 + lr;
                uint2 o;
                o.x = pack2(acc[ji][pi][0] + bias.x, acc[ji][pi][1] + bias.y);
                o.y = pack2(acc[ji][pi][2] + bias.z, acc[ji][pi][3] + bias.w);
                *(uint2*)&WT[p * 128 + (((jq >> 3) ^ (p & 7)) << 3) + (jq & 7)] = o;
            }
        }
        __syncthreads();

        // ---- copy D -> qkv, coalesced 16B writes (lanes sweep j)
#pragma unroll
        for (int it = 0; it < 8; ++it) {
            const int slot = it * 256 + t;
            const int seg = slot & 15, p = slot >> 4;
            const uint4 v = *(const uint4*)&WT[p * 128 + ((seg ^ (p & 7)) << 3)];
            *(uint4*)&qkv[(size_t)(p0 + p) * 384 + j0 + seg * 8] = v;
        }

        // ---- qc stores: dense conv layout [c][p][48]; this jt covers
        // e in [jt*4, jt*4+4) -> 16 contiguous ushorts at offset jt*16.
        if (qc) {
#pragma unroll
            for (int it = 0; it < 4; ++it) {
                const int unit = it * 256 + t;
                const int p = unit & 127, c = unit >> 7;   // c = 0..7
                uint2 r[4];
#pragma unroll
                for (int ee = 0; ee < 4; ++ee) {
                    const int jl = ee * 32 + c * 4;
                    r[ee] = *(const uint2*)&WT[p * 128 +
                        (((jl >> 3) ^ (p & 7)) << 3) + (jl & 7)];
                }
                ushort_t* dst = qc + (size_t)c * QC_PLANE +
                                (size_t)(p0 + p) * 48 + jt * 16;
                *(uint4*)dst       = make_uint4(r[0].x, r[0].y, r[1].x, r[1].y);
                *(uint4*)(dst + 8) = make_uint4(r[2].x, r[2].y, r[3].x, r[3].y);
            }
        }
    }
}

// ------------------------------------------------------------------
// k_attn4 (MFMA attention): per 8x8 window, wave = head.
// ------------------------------------------------------------------
__global__ __launch_bounds__(256) void k_attn4(
    const ushort_t* __restrict__ qkv, const float* __restrict__ rpb,
    float* __restrict__ out)
{
    // uints: Q[0,4352) K[4352,8704) VT[8704,13056) rpb[13056,13956)
    // P aliases [0,8704): head h at h*2176, row stride 34 uints (68 sh).
    __shared__ uint_t lds[13956];
    ushort_t* lds_sh = (ushort_t*)lds;
    float* rpbl = (float*)(lds + 13056);
    const int t = threadIdx.x;
    const int b = blockIdx.x >> 8, wy = (blockIdx.x >> 4) & 15, wx = blockIdx.x & 15;
    const int prow0 = (b << 14) + (wy * 8) * 128 + wx * 8;
    const uint_t* qkvu = (const uint_t*)qkv;

    // ---- stage Q,K rows (68-uint stride) + V transposed (VT[d][m])
    for (int i = t; i < 4096; i += 256) {
        const int m = i >> 6, u = i & 63;
        const size_t pr = (size_t)(prow0 + (m >> 3) * 128 + (m & 7)) * 192;
        lds[m * 68 + u]        = qkvu[pr + u];
        lds[4352 + m * 68 + u] = qkvu[pr + 64 + u];
        const uint_t v = qkvu[pr + 128 + u];
        lds_sh[17408 + (2 * u) * 68 + m]     = (ushort_t)(v & 0xffffu);
        lds_sh[17408 + (2 * u + 1) * 68 + m] = (ushort_t)(v >> 16);
    }
    for (int i = t; i < 900; i += 256) rpbl[i] = rpb[i];
    __syncthreads();

    const int h = t >> 6, l = t & 63;
    const int lr = l & 15, lg = l >> 4;

    // ---- QK^T: 16 MFMAs
    short8 af_k[4], bf_q[4];
#pragma unroll
    for (int i = 0; i < 4; ++i) {
        af_k[i] = *(const short8*)&lds_sh[8704 + (i * 16 + lr) * 136 + h * 32 + lg * 8];
        bf_q[i] = *(const short8*)&lds_sh[(i * 16 + lr) * 136 + h * 32 + lg * 8];
    }
    f32x4 sA[4][4];   // [nt][mt]
#pragma unroll
    for (int nt = 0; nt < 4; ++nt)
#pragma unroll
        for (int mt = 0; mt < 4; ++mt)
            sA[nt][mt] = __builtin_amdgcn_mfma_f32_16x16x32_bf16(
                af_k[mt], bf_q[nt], (f32x4){0.f, 0.f, 0.f, 0.f}, 0, 0, 0);

    // ---- softmax per row n (lane owns n = nt*16+lr; m split over lg)
    float inv[4];
#pragma unroll
    for (int nt = 0; nt < 4; ++nt) {
        const int n = nt * 16 + lr;
        const int ry = n >> 3, rx = n & 7;
        float mxv = -1e30f;
#pragma unroll
        for (int mt = 0; mt < 4; ++mt)
#pragma unroll
            for (int r = 0; r < 4; ++r) {
                const int m = mt * 16 + lg * 4 + r;
                const float bias =
                    rpbl[((ry - (m >> 3) + 7) * 15 + (rx - (m & 7) + 7)) * 4 + h];
                const float s = sA[nt][mt][r] * SCALE + bias;
                sA[nt][mt][r] = s;
                mxv = fmaxf(mxv, s);
            }
        mxv = fmaxf(mxv, __shfl_xor(mxv, 16));
        mxv = fmaxf(mxv, __shfl_xor(mxv, 32));
        float ls = 0.f;
#pragma unroll
        for (int mt = 0; mt < 4; ++mt)
#pragma unroll
            for (int r = 0; r < 4; ++r) {
                const float e = __expf(sA[nt][mt][r] - mxv);
                sA[nt][mt][r] = e;
                ls += e;
            }
        ls += __shfl_xor(ls, 16);
        ls += __shfl_xor(ls, 32);
        inv[nt] = 1.f / ls;
    }

    __syncthreads();   // all waves done reading Q/K before P overwrites

    // ---- P (bf16) into LDS, row n stride 34 uints
    uint_t* Pb = lds + h * 2176;
#pragma unroll
    for (int nt = 0; nt < 4; ++nt) {
        const int n = nt * 16 + lr;
#pragma unroll
        for (int mt = 0; mt < 4; ++mt) {
            uint2 o;
            o.x = pack2(sA[nt][mt][0], sA[nt][mt][1]);
            o.y = pack2(sA[nt][mt][2], sA[nt][mt][3]);
            *(uint2*)&Pb[n * 34 + mt * 8 + lg * 2] = o;
        }
    }
    asm volatile("s_waitcnt lgkmcnt(0)" ::: "memory");

    // ---- PV: O = mfma(A=VT rows d, B=P rows n), K=64 (2 steps)
    union U8 { short8 s8; uint2 u2[2]; };
    f32x4 oA[2][4];
#pragma unroll
    for (int dt = 0; dt < 2; ++dt)
#pragma unroll
        for (int nt = 0; nt < 4; ++nt) oA[dt][nt] = (f32x4){0.f, 0.f, 0.f, 0.f};
#pragma unroll
    for (int ks = 0; ks < 2; ++ks) {
        const int kb = ks * 4 + lg;
        short8 av[2], bp[4];
#pragma unroll
        for (int dt = 0; dt < 2; ++dt) {
            U8 u;
            const int d = h * 32 + dt * 16 + lr;
            u.u2[0] = *(const uint2*)&lds[8704 + d * 34 + kb * 4];
            u.u2[1] = *(const uint2*)&lds[8704 + d * 34 + kb * 4 + 2];
            av[dt] = u.s8;
        }
#pragma unroll
        for (int nt = 0; nt < 4; ++nt) {
            U8 u;
            const int n = nt * 16 + lr;
            u.u2[0] = *(const uint2*)&Pb[n * 34 + kb * 4];
            u.u2[1] = *(const uint2*)&Pb[n * 34 + kb * 4 + 2];
            bp[nt] = u.s8;
        }
#pragma unroll
        for (int dt = 0; dt < 2; ++dt)
#pragma unroll
            for (int nt = 0; nt < 4; ++nt)
                oA[dt][nt] = __builtin_amdgcn_mfma_f32_16x16x32_bf16(
                    av[dt], bp[nt], oA[dt][nt], 0, 0, 0);
    }

    // ---- write raw xa channel-major: out[b][h*32+d][pix(n)]
    float* ob = out + ((size_t)b << 21);
    const int pixbase = (wy * 8) * 128 + wx * 8;
#pragma unroll
    for (int dt = 0; dt < 2; ++dt)
#pragma unroll
        for (int nt = 0; nt < 4; ++nt) {
            const int n = nt * 16 + lr;
            const size_t po = (size_t)(pixbase + (n >> 3) * 128 + (n & 7));
            const float iv = inv[nt];
#pragma unroll
            for (int r = 0; r < 4; ++r) {
                const int d = h * 32 + dt * 16 + lg * 4 + r;
                ob[((size_t)d << 14) + po] = oA[dt][nt][r] * iv;
            }
        }
}

// ------------------------------------------------------------------
// k_proj (MFMA, in-place on out): out[b][j][p] =
//    rate1 * ( sum_c xa[b][c][p] * pw[c][j] + pb[j] ), xa = current out.
// ------------------------------------------------------------------
__global__ __launch_bounds__(256) void k_proj(
    const float* __restrict__ pw, const float* __restrict__ pb,
    const float* __restrict__ r1, float* __restrict__ out)
{
    __shared__ ushort_t XT[128 * 128];  // xa^T [p][c] swizzled
    __shared__ ushort_t WT[128 * 128];  // pw^T [j][c] swizzled
    const int t = threadIdx.x;
    const int p0 = blockIdx.x * 128;
    const int b = p0 >> 14;
    const int rem = p0 & 16383;
    const float* xb = out + ((size_t)b << 21) + rem;

    // ---- stage XT from out (xa), coalesced along p
#pragma unroll
    for (int it = 0; it < 8; ++it) {
        const int slot = it * 256 + t;
        const int p = slot & 127, cb = slot >> 7;
        uint4 u;
        {
            const float a0 = xb[(size_t)(cb * 8 + 0) * 16384 + p];
            const float a1 = xb[(size_t)(cb * 8 + 1) * 16384 + p];
            const float a2 = xb[(size_t)(cb * 8 + 2) * 16384 + p];
            const float a3 = xb[(size_t)(cb * 8 + 3) * 16384 + p];
            const float a4 = xb[(size_t)(cb * 8 + 4) * 16384 + p];
            const float a5 = xb[(size_t)(cb * 8 + 5) * 16384 + p];
            const float a6 = xb[(size_t)(cb * 8 + 6) * 16384 + p];
            const float a7 = xb[(size_t)(cb * 8 + 7) * 16384 + p];
            u.x = pack2(a0, a1); u.y = pack2(a2, a3);
            u.z = pack2(a4, a5); u.w = pack2(a6, a7);
        }
        *(uint4*)&XT[p * 128 + ((cb ^ (p & 7)) << 3)] = u;
    }
    // ---- stage WT from pw (128x128), coalesced along j
#pragma unroll
    for (int it = 0; it < 8; ++it) {
        const int slot = it * 256 + t;
        const int j = slot & 127, cb = slot >> 7;
        uint4 u;
        {
            const float a0 = pw[(size_t)(cb * 8 + 0) * 128 + j];
            const float a1 = pw[(size_t)(cb * 8 + 1) * 128 + j];
            const float a2 = pw[(size_t)(cb * 8 + 2) * 128 + j];
            const float a3 = pw[(size_t)(cb * 8 + 3) * 128 + j];
            const float a4 = pw[(size_t)(cb * 8 + 4) * 128 + j];
            const float a5 = pw[(size_t)(cb * 8 + 5) * 128 + j];
            const float a6 = pw[(size_t)(cb * 8 + 6) * 128 + j];
            const float a7 = pw[(size_t)(cb * 8 + 7) * 128 + j];
            u.x = pack2(a0, a1); u.y = pack2(a2, a3);
            u.z = pack2(a4, a5); u.w = pack2(a6, a7);
        }
        *(uint4*)&WT[j * 128 + ((cb ^ (j & 7)) << 3)] = u;
    }
    __syncthreads();   // all global reads of this block's pixels complete here

    const int l = t & 63, wv = t >> 6;
    const int wj = (wv >> 1) * 64, wp = (wv & 1) * 64;
    const int lr = l & 15, lg = l >> 4;

    f32x4 acc[4][4];
#pragma unroll
    for (int i = 0; i < 4; ++i)
#pragma unroll
        for (int j = 0; j < 4; ++j) acc[i][j] = (f32x4){0.f, 0.f, 0.f, 0.f};

#pragma unroll
    for (int ks = 0; ks < 4; ++ks) {
        const int kb = ks * 4 + lg;
        short8 af[4], bf[4];
#pragma unroll
        for (int i = 0; i < 4; ++i) {
            const int jr = wj + i * 16 + lr;
            af[i] = *(const short8*)&WT[jr * 128 + ((kb ^ (jr & 7)) << 3)];
            const int pr = wp + i * 16 + lr;
            bf[i] = *(const short8*)&XT[pr * 128 + ((kb ^ (pr & 7)) << 3)];
        }
#pragma unroll
        for (int ji = 0; ji < 4; ++ji)
#pragma unroll
            for (int pi = 0; pi < 4; ++pi)
                acc[ji][pi] = __builtin_amdgcn_mfma_f32_16x16x32_bf16(
                    af[ji], bf[pi], acc[ji][pi], 0, 0, 0);
    }

    const float rate1 = r1[0];
    float* obase = out + ((size_t)b << 21) + rem;
    // lane holds j = jq..jq+3 at pixel p; stores are 16-lane p-contiguous
#pragma unroll
    for (int ji = 0; ji < 4; ++ji) {
        const int jq = wj + ji * 16 + 4 * lg;
        const float4 bias = *(const float4*)&pb[jq];
#pragma unroll
        for (int pi = 0; pi < 4; ++pi) {
            const int p = wp + pi * 16 + lr;
            float* op = obase + (size_t)jq * 16384 + p;
            op[0]     = rate1 * (acc[ji][pi][0] + bias.x);
            op[16384] = rate1 * (acc[ji][pi][1] + bias.y);
            op[32768] = rate1 * (acc[ji][pi][2] + bias.z);
            op[49152] = rate1 * (acc[ji][pi][3] + bias.w);
        }
    }
}

// ------------------------------------------------------------------
// k_conv8: conv7 structure, but reads the DENSE qc[chunk][p][48]
// layout: 6 contiguous uint4 (96 B) per halo pixel per chunk,
// killing the 4.2x line over-fetch of the strided qkv reads.
// ------------------------------------------------------------------
__global__ __launch_bounds__(256) void k_conv8(
    const ushort_t* __restrict__ qc, const float* __restrict__ fcw,
    const float* __restrict__ fcb, const float* __restrict__ depw,
    const float* __restrict__ depb, const float* __restrict__ r2,
    float* __restrict__ out)
{
    __shared__ ushort_t fcl[11664];             // [(ii*4+dd)*324 + pix] bf16
    __shared__ __align__(16) float dwl[1296];   // [kk81][16 oc-in-chunk]
    __shared__ float fcwl[108];
    __shared__ float fcbl[9];

    const int t = threadIdx.x;
    const int half = blockIdx.x & 1;
    const int tile = (blockIdx.x >> 1) & 63;
    const int b = blockIdx.x >> 7;
    const int ty0 = (tile >> 3) << 4, tx0 = (tile & 7) << 4;
    if (t < 108) fcwl[t] = fcw[t];
    if (t < 9)   fcbl[t] = fcb[t];
    const float rate2 = r2[0];
    const int py = t >> 4, px = t & 15;
    float* ob = out + ((size_t)b << 21) + (size_t)((ty0 + py) * 128 + (tx0 + px));

    // this thread's halo pixels: pix0 = t, pix1 = 256+t (t<68)
    const int row0 = t / 18, col0 = t - row0 * 18;
    const int hy0 = ty0 + row0 - 1, hx0 = tx0 + col0 - 1;
    const int g0 = ((unsigned)hy0 < 128u && (unsigned)hx0 < 128u)
                       ? ((b << 14) + hy0 * 128 + hx0) : -1;
    const int t1 = t + 256, row1 = t1 / 18, col1 = t1 - row1 * 18;
    const int hy1 = ty0 + row1 - 1, hx1 = tx0 + col1 - 1;
    const int g1 = (t < 68 && (unsigned)hy1 < 128u && (unsigned)hx1 < 128u)
                       ? ((b << 14) + hy1 * 128 + hx1) : -1;

    for (int ci = 0; ci < 4; ++ci) {
        const int chunk = half * 4 + ci;
        __syncthreads();   // fcwl visible (ci 0) / prior conv reads done
        for (int i = t; i < 1296; i += 256)
            dwl[i] = depw[(chunk * 16 + (i & 15)) * 81 + (i >> 4)];

        const ushort_t* qp_base = qc + (size_t)chunk * QC_PLANE;
#pragma unroll
        for (int hf = 0; hf < 2; ++hf) {
            const int g = hf ? g1 : g0;
            const int pix = hf ? (256 + t) : t;
            if (hf && t >= 68) break;
            float fo[9][4];
#pragma unroll
            for (int ii = 0; ii < 9; ++ii) {
                const float bv = (g >= 0) ? fcbl[ii] : 0.f;
                fo[ii][0] = bv; fo[ii][1] = bv; fo[ii][2] = bv; fo[ii][3] = bv;
            }
            if (g >= 0) {
                const uint4* qp = (const uint4*)(qp_base + (size_t)g * 48);
                const uint4 v0 = qp[0], v1 = qp[1], v2 = qp[2];
                const uint4 v3 = qp[3], v4 = qp[4], v5 = qp[5];
                const uint_t uu[24] = {v0.x, v0.y, v0.z, v0.w, v1.x, v1.y, v1.z, v1.w,
                                       v2.x, v2.y, v2.z, v2.w, v3.x, v3.y, v3.z, v3.w,
                                       v4.x, v4.y, v4.z, v4.w, v5.x, v5.y, v5.z, v5.w};
#pragma unroll
                for (int e = 0; e < 12; ++e) {
                    const uint_t lo = uu[e * 2], hi = uu[e * 2 + 1];
                    const float f0 = blo(lo), f1 = bhi(lo);
                    const float f2 = blo(hi), f3 = bhi(hi);
#pragma unroll
                    for (int ii = 0; ii < 9; ++ii) {
                        const float wv = fcwl[ii * 12 + e];
                        fo[ii][0] += wv * f0; fo[ii][1] += wv * f1;
                        fo[ii][2] += wv * f2; fo[ii][3] += wv * f3;
                    }
                }
            }
#pragma unroll
            for (int ii = 0; ii < 9; ++ii)
#pragma unroll
                for (int dd = 0; dd < 4; ++dd)
                    fcl[(ii * 4 + dd) * 324 + pix] = f2u(fo[ii][dd]);
        }
        __syncthreads();

        float4 accv[4];
#pragma unroll
        for (int dd = 0; dd < 4; ++dd) accv[dd] = make_float4(0.f, 0.f, 0.f, 0.f);
#pragma unroll
        for (int ii = 0; ii < 9; ++ii) {
#pragma unroll
            for (int kk = 0; kk < 9; ++kk) {
                const int ky = kk / 3, kx = kk - (kk / 3) * 3;
                const int hpix = (py + ky) * 18 + px + kx;
                const float4* dwp = (const float4*)&dwl[(ii * 9 + kk) * 16];
#pragma unroll
                for (int dd = 0; dd < 4; ++dd) {
                    const float f = u2f(fcl[(ii * 4 + dd) * 324 + hpix]);
                    const float4 d4 = dwp[dd];
                    accv[dd].x += f * d4.x; accv[dd].y += f * d4.y;
                    accv[dd].z += f * d4.z; accv[dd].w += f * d4.w;
                }
            }
        }
#pragma unroll
        for (int dd = 0; dd < 4; ++dd) {
            const float av[4] = {accv[dd].x, accv[dd].y, accv[dd].z, accv[dd].w};
#pragma unroll
            for (int j = 0; j < 4; ++j) {
                const int oc = chunk * 16 + dd * 4 + j;
                ob[(size_t)oc << 14] += rate2 * (av[j] + depb[oc]);
            }
        }
    }
}

// ------------------------------------------------------------------
// k_conv7 (fallback when ws < 192 MB): strided qkv reads, measured.
// ------------------------------------------------------------------
__global__ __launch_bounds__(256) void k_conv7(
    const ushort_t* __restrict__ qkv, const float* __restrict__ fcw,
    const float* __restrict__ fcb, const float* __restrict__ depw,
    const float* __restrict__ depb, const float* __restrict__ r2,
    float* __restrict__ out)
{
    __shared__ ushort_t fcl[11664];             // [(ii*4+dd)*324 + pix] bf16
    __shared__ __align__(16) float dwl[1296];   // [kk81][16 oc-in-chunk]
    __shared__ float fcwl[108];
    __shared__ float fcbl[9];

    const int t = threadIdx.x;
    const int half = blockIdx.x & 1;
    const int tile = (blockIdx.x >> 1) & 63;
    const int b = blockIdx.x >> 7;
    const int ty0 = (tile >> 3) << 4, tx0 = (tile & 7) << 4;
    if (t < 108) fcwl[t] = fcw[t];
    if (t < 9)   fcbl[t] = fcb[t];
    const float rate2 = r2[0];
    const int py = t >> 4, px = t & 15;
    float* ob = out + ((size_t)b << 21) + (size_t)((ty0 + py) * 128 + (tx0 + px));

    const int row0 = t / 18, col0 = t - row0 * 18;
    const int hy0 = ty0 + row0 - 1, hx0 = tx0 + col0 - 1;
    const int g0 = ((unsigned)hy0 < 128u && (unsigned)hx0 < 128u)
                       ? ((b << 14) + hy0 * 128 + hx0) : -1;
    const int t1 = t + 256, row1 = t1 / 18, col1 = t1 - row1 * 18;
    const int hy1 = ty0 + row1 - 1, hx1 = tx0 + col1 - 1;
    const int g1 = (t < 68 && (unsigned)hy1 < 128u && (unsigned)hx1 < 128u)
                       ? ((b << 14) + hy1 * 128 + hx1) : -1;

    for (int ci = 0; ci < 4; ++ci) {
        const int chunk = half * 4 + ci;
        __syncthreads();
        for (int i = t; i < 1296; i += 256)
            dwl[i] = depw[(chunk * 16 + (i & 15)) * 81 + (i >> 4)];

#pragma unroll
        for (int hf = 0; hf < 2; ++hf) {
            const int g = hf ? g1 : g0;
            const int pix = hf ? (256 + t) : t;
            if (hf && t >= 68) break;
            float fo[9][4];
#pragma unroll
            for (int ii = 0; ii < 9; ++ii) {
                const float bv = (g >= 0) ? fcbl[ii] : 0.f;
                fo[ii][0] = bv; fo[ii][1] = bv; fo[ii][2] = bv; fo[ii][3] = bv;
            }
            if (g >= 0) {
                const uint2* qp = (const uint2*)(qkv + (size_t)g * 384 + chunk * 4);
#pragma unroll
                for (int e = 0; e < 12; ++e) {
                    const uint2 q = qp[e * 8];
                    const float f0 = blo(q.x), f1 = bhi(q.x);
                    const float f2 = blo(q.y), f3 = bhi(q.y);
#pragma unroll
                    for (int ii = 0; ii < 9; ++ii) {
                        const float wv = fcwl[ii * 12 + e];
                        fo[ii][0] += wv * f0; fo[ii][1] += wv * f1;
                        fo[ii][2] += wv * f2; fo[ii][3] += wv * f3;
                    }
                }
            }
#pragma unroll
            for (int ii = 0; ii < 9; ++ii)
#pragma unroll
                for (int dd = 0; dd < 4; ++dd)
                    fcl[(ii * 4 + dd) * 324 + pix] = f2u(fo[ii][dd]);
        }
        __syncthreads();

        float4 accv[4];
#pragma unroll
        for (int dd = 0; dd < 4; ++dd) accv[dd] = make_float4(0.f, 0.f, 0.f, 0.f);
#pragma unroll
        for (int ii = 0; ii < 9; ++ii) {
#pragma unroll
            for (int kk = 0; kk < 9; ++kk) {
                const int ky = kk / 3, kx = kk - (kk / 3) * 3;
                const int hpix = (py + ky) * 18 + px + kx;
                const float4* dwp = (const float4*)&dwl[(ii * 9 + kk) * 16];
#pragma unroll
                for (int dd = 0; dd < 4; ++dd) {
                    const float f = u2f(fcl[(ii * 4 + dd) * 324 + hpix]);
                    const float4 d4 = dwp[dd];
                    accv[dd].x += f * d4.x; accv[dd].y += f * d4.y;
                    accv[dd].z += f * d4.z; accv[dd].w += f * d4.w;
                }
            }
        }
#pragma unroll
        for (int dd = 0; dd < 4; ++dd) {
            const float av[4] = {accv[dd].x, accv[dd].y, accv[dd].z, accv[dd].w};
#pragma unroll
            for (int j = 0; j < 4; ++j) {
                const int oc = chunk * 16 + dd * 4 + j;
                ob[(size_t)oc << 14] += rate2 * (av[j] + depb[oc]);
            }
        }
    }
}

// ==================================================================
// FALLBACK PATH (ws too small): round-5 kernels, verbatim.
// ==================================================================
#define WS_W2  0
#define WS_B2  36864
#define WS_TOT 37152

__global__ __launch_bounds__(256) void k_prep_f(
    const float* __restrict__ qkv_w, const float* __restrict__ qkv_b,
    const float* __restrict__ fcw, const float* __restrict__ fcb,
    float* __restrict__ ws)
{
    const int idx = blockIdx.x * 256 + threadIdx.x;
    if (idx < WS_B2) {
        const int c = idx / 288, r = idx - c * 288, i = r >> 5, d = r & 31;
        float s = 0.f;
#pragma unroll
        for (int e = 0; e < 12; ++e)
            s += fcw[i * 12 + e] * qkv_w[c * 384 + e * 32 + d];
        ws[idx] = s;
    } else if (idx < WS_TOT) {
        const int r = idx - WS_B2, i = r >> 5, d = r & 31;
        float s = fcb[i];
#pragma unroll
        for (int e = 0; e < 12; ++e)
            s += fcw[i * 12 + e] * qkv_b[e * 32 + d];
        ws[idx] = s;
    }
}

__global__ __launch_bounds__(256) void k_attn_f(
    const float* __restrict__ x, const float* __restrict__ qw,
    const float* __restrict__ qb, const float* __restrict__ pw,
    const float* __restrict__ pb, const float* __restrict__ rpb,
    const float* __restrict__ r1, float* __restrict__ out)
{
    __shared__ ushort_t xw[8192];
    __shared__ float arena[8450];
    ushort_t* kvb = (ushort_t*)arena;
    const int t = threadIdx.x;
    const int b = blockIdx.x >> 8, wy = (blockIdx.x >> 4) & 15, wx = blockIdx.x & 15;
    const size_t xbase = ((size_t)b << 21) + (size_t)((wy * 8) * 128 + wx * 8);
    for (int i = t; i < 8192; i += 256) {
        const int c = i >> 6, p = i & 63;
        xw[i] = f2u(x[xbase + (size_t)c * 16384 + (p >> 3) * 128 + (p & 7)]);
    }
    __syncthreads();
    const int h = t >> 6, n = t & 63;
    float qa[32], ka[32], va[32];
#pragma unroll
    for (int cc = 0; cc < 32; ++cc) {
        qa[cc] = qb[h * 32 + cc];
        ka[cc] = qb[128 + h * 32 + cc];
        va[cc] = qb[256 + h * 32 + cc];
    }
    const float* wbase = qw + h * 32;
    for (int c = 0; c < 128; ++c) {
        const float xv = u2f(xw[c * 64 + n]);
        const float* wr = wbase + c * 384;
#pragma unroll
        for (int j = 0; j < 8; ++j) {
            const float4 aq = ((const float4*)wr)[j];
            const float4 ak = ((const float4*)(wr + 128))[j];
            const float4 av = ((const float4*)(wr + 256))[j];
            qa[4 * j + 0] += xv * aq.x; qa[4 * j + 1] += xv * aq.y;
            qa[4 * j + 2] += xv * aq.z; qa[4 * j + 3] += xv * aq.w;
            ka[4 * j + 0] += xv * ak.x; ka[4 * j + 1] += xv * ak.y;
            ka[4 * j + 2] += xv * ak.z; ka[4 * j + 3] += xv * ak.w;
            va[4 * j + 0] += xv * av.x; va[4 * j + 1] += xv * av.y;
            va[4 * j + 2] += xv * av.z; va[4 * j + 3] += xv * av.w;
        }
    }
#pragma unroll
    for (int cc = 0; cc < 32; ++cc) qa[cc] *= SCALE;
    uint_t* kv32 = (uint_t*)kvb;
#pragma unroll
    for (int j = 0; j < 16; ++j) {
        kv32[n * 66 + h * 16 + j] = pack2(ka[2 * j], ka[2 * j + 1]);
        kv32[4224 + n * 66 + h * 16 + j] = pack2(va[2 * j], va[2 * j + 1]);
    }
    __syncthreads();
    const int ry = n >> 3, rx = n & 7;
    float sar[64];
    float mx = -1e30f;
#pragma unroll
    for (int m = 0; m < 64; ++m) {
        const uint2* kr = (const uint2*)(kvb + m * 132 + h * 32);
        float s = 0.f;
#pragma unroll
        for (int j = 0; j < 8; ++j) {
            const uint2 u = kr[j];
            s += qa[4 * j + 0] * blo(u.x) + qa[4 * j + 1] * bhi(u.x)
               + qa[4 * j + 2] * blo(u.y) + qa[4 * j + 3] * bhi(u.y);
        }
        s += rpb[((ry - (m >> 3) + 7) * 15 + (rx - (m & 7) + 7)) * 4 + h];
        sar[m] = s;
        mx = fmaxf(mx, s);
    }
    float l = 0.f;
#pragma unroll
    for (int m = 0; m < 64; ++m) { const float e = __expf(sar[m] - mx); sar[m] = e; l += e; }
    const float inv = 1.f / l;
    float acc[32];
#pragma unroll
    for (int cc = 0; cc < 32; ++cc) acc[cc] = 0.f;
#pragma unroll
    for (int m = 0; m < 64; ++m) {
        const float pm = sar[m];
        const uint2* vr = (const uint2*)(kvb + 8448 + m * 132 + h * 32);
#pragma unroll
        for (int j = 0; j < 8; ++j) {
            const uint2 u = vr[j];
            acc[4 * j + 0] += pm * blo(u.x); acc[4 * j + 1] += pm * bhi(u.x);
            acc[4 * j + 2] += pm * blo(u.y); acc[4 * j + 3] += pm * bhi(u.y);
        }
    }
    __syncthreads();
#pragma unroll
    for (int cc = 0; cc < 32; ++cc) arena[n * 130 + h * 32 + cc] = acc[cc] * inv;
    __syncthreads();
    const int p = t & 63, jb = t >> 6;
    float aj[32];
#pragma unroll
    for (int jj = 0; jj < 32; ++jj) aj[jj] = pb[jb * 32 + jj];
    const float* xr = arena + p * 130;
    const float* pwb = pw + jb * 32;
    for (int c = 0; c < 128; ++c) {
        const float xv = xr[c];
        const float4* pr = (const float4*)(pwb + c * 128);
#pragma unroll
        for (int j = 0; j < 8; ++j) {
            const float4 w4 = pr[j];
            aj[4 * j + 0] += xv * w4.x; aj[4 * j + 1] += xv * w4.y;
            aj[4 * j + 2] += xv * w4.z; aj[4 * j + 3] += xv * w4.w;
        }
    }
    const float rate1 = r1[0];
    const int oy = wy * 8 + (p >> 3), ox = wx * 8 + (p & 7);
    float* ob = out + ((size_t)b << 21) + (size_t)(oy * 128 + ox);
#pragma unroll
    for (int jj = 0; jj < 32; ++jj)
        ob[(size_t)(jb * 32 + jj) << 14] = rate1 * aj[jj];
}

__global__ __launch_bounds__(256) void k_conv_f(
    const float* __restrict__ x, const float* __restrict__ ws,
    const float* __restrict__ depw, const float* __restrict__ depb,
    const float* __restrict__ r2, float* __restrict__ out)
{
    __shared__ float arena[12960];
    __shared__ float b2s[36];
    float* w2l = arena;
    ushort_t* xl = (ushort_t*)(arena + 4608);
    float* fcl = arena;
    float* dwl = arena + 11664;
    const int t = threadIdx.x;
    const int b = blockIdx.x >> 6, tile = blockIdx.x & 63;
    const int ty0 = (tile >> 3) << 4, tx0 = (tile & 7) << 4;
    const size_t xbase = ((size_t)b << 21);
    const float rate2 = r2[0];
    const int py = t >> 4, px = t & 15;
    float* ob = out + ((size_t)b << 21) + (size_t)((ty0 + py) * 128 + (tx0 + px));
    const int r0 = t / 18, c0 = t - r0 * 18;
    const bool ok0 = ((unsigned)(ty0 + r0 - 1) < 128u) && ((unsigned)(tx0 + c0 - 1) < 128u);
    const int t1 = 256 + t, r1i = t1 / 18, c1 = t1 - r1i * 18;
    const bool ok1 = (t < 68) && ((unsigned)(ty0 + r1i - 1) < 128u) && ((unsigned)(tx0 + c1 - 1) < 128u);
    for (int chunk = 0; chunk < 8; ++chunk) {
        __syncthreads();
        for (int i = t; i < 4608; i += 256) {
            const int c = i / 36, r = i - c * 36;
            w2l[i] = ws[WS_W2 + c * 288 + (r >> 2) * 32 + chunk * 4 + (r & 3)];
        }
        if (t < 36) b2s[t] = ws[WS_B2 + (t >> 2) * 32 + chunk * 4 + (t & 3)];
        __syncthreads();
        float fca[2][36];
#pragma unroll
        for (int r = 0; r < 36; ++r) { fca[0][r] = b2s[r]; fca[1][r] = b2s[r]; }
        for (int cs = 0; cs < 8; ++cs) {
            if (cs) __syncthreads();
            for (int i = t; i < 5184; i += 256) {
                const int cc = i / 324, pp = i - cc * 324;
                const int row = pp / 18, col = pp - row * 18;
                const int hy = ty0 + row - 1, hx = tx0 + col - 1;
                ushort_t v = 0;
                if ((unsigned)hy < 128u && (unsigned)hx < 128u)
                    v = f2u(x[xbase + (size_t)(cs * 16 + cc) * 16384 + hy * 128 + hx]);
                xl[i] = v;
            }
            __syncthreads();
#pragma unroll 4
            for (int cc = 0; cc < 16; ++cc) {
                const float xv0 = u2f(xl[cc * 324 + t]);
                const float xv1 = (t < 68) ? u2f(xl[cc * 324 + 256 + t]) : 0.f;
                const float* wr = w2l + (cs * 16 + cc) * 36;
#pragma unroll
                for (int r = 0; r < 36; r += 4) {
                    const float4 w4 = *(const float4*)(wr + r);
                    fca[0][r + 0] += xv0 * w4.x; fca[0][r + 1] += xv0 * w4.y;
                    fca[0][r + 2] += xv0 * w4.z; fca[0][r + 3] += xv0 * w4.w;
                    fca[1][r + 0] += xv1 * w4.x; fca[1][r + 1] += xv1 * w4.y;
                    fca[1][r + 2] += xv1 * w4.z; fca[1][r + 3] += xv1 * w4.w;
                }
            }
        }
        __syncthreads();
#pragma unroll
        for (int r = 0; r < 36; ++r) {
            fcl[r * 324 + t] = ok0 ? fca[0][r] : 0.f;
            if (t < 68) fcl[r * 324 + 256 + t] = ok1 ? fca[1][r] : 0.f;
        }
        for (int i = t; i < 1296; i += 256) {
            const int kk = i >> 4, ocl = i & 15;
            dwl[i] = depw[(chunk * 16 + ocl) * 81 + kk];
        }
        __syncthreads();
        float4 accv[4];
#pragma unroll
        for (int dd = 0; dd < 4; ++dd) accv[dd] = make_float4(0.f, 0.f, 0.f, 0.f);
#pragma unroll
        for (int ii = 0; ii < 9; ++ii) {
#pragma unroll
            for (int kk = 0; kk < 9; ++kk) {
                const int ky = kk / 3, kx = kk - (kk / 3) * 3;
                const int hpix = (py + ky) * 18 + px + kx;
                const float4* dwp = (const float4*)&dwl[(ii * 9 + kk) * 16];
#pragma unroll
                for (int dd = 0; dd < 4; ++dd) {
                    const float f = fcl[(ii * 4 + dd) * 324 + hpix];
                    const float4 d4 = dwp[dd];
                    accv[dd].x += f * d4.x; accv[dd].y += f * d4.y;
                    accv[dd].z += f * d4.z; accv[dd].w += f * d4.w;
                }
            }
        }
#pragma unroll
        for (int dd = 0; dd < 4; ++dd) {
            const float av[4] = {accv[dd].x, accv[dd].y, accv[dd].z, accv[dd].w};
#pragma unroll
            for (int j = 0; j < 4; ++j) {
                const int oc = chunk * 16 + dd * 4 + j;
                ob[(size_t)oc << 14] += rate2 * (av[j] + depb[oc]);
            }
        }
    }
}

// ------------------------------------------------------------------
extern "C" void kernel_launch(void* const* d_in, const int* in_sizes, int n_in,
                              void* d_out, int out_size, void* d_ws, size_t ws_size,
                              hipStream_t stream) {
    (void)in_sizes; (void)n_in; (void)out_size;
    const float* x      = (const float*)d_in[0];
    const float* qkv_w  = (const float*)d_in[1];
    const float* qkv_b  = (const float*)d_in[2];
    const float* proj_w = (const float*)d_in[3];
    const float* proj_b = (const float*)d_in[4];
    const float* rpb    = (const float*)d_in[5];
    const float* fc_w   = (const float*)d_in[6];
    const float* fc_b   = (const float*)d_in[7];
    const float* dep_w  = (const float*)d_in[8];
    const float* dep_b  = (const float*)d_in[9];
    const float* rate1  = (const float*)d_in[10];
    const float* rate2  = (const float*)d_in[11];
    float* out = (float*)d_out;

    const size_t QKV_SZ = (size_t)131072 * 384;  // elements (ushort)
    if (ws_size >= QKV_SZ * 2 * 2) {
        // qkv + dense conv copy qc (96 MB each)
        ushort_t* qkv = (ushort_t*)d_ws;
        ushort_t* qc  = qkv + QKV_SZ;
        k_qqkv<<<dim3(1024), dim3(256), 0, stream>>>(x, qkv_w, qkv_b, qkv, qc);
        k_attn4<<<dim3(2048), dim3(256), 0, stream>>>(qkv, rpb, out);
        k_proj<<<dim3(1024), dim3(256), 0, stream>>>(proj_w, proj_b, rate1, out);
        k_conv8<<<dim3(1024), dim3(256), 0, stream>>>(qc, fc_w, fc_b, dep_w,
                                                      dep_b, rate2, out);
    } else if (ws_size >= QKV_SZ * 2) {
        ushort_t* qkv = (ushort_t*)d_ws;   // 96 MB bf16
        k_qqkv<<<dim3(1024), dim3(256), 0, stream>>>(x, qkv_w, qkv_b, qkv,
                                                     (ushort_t*)nullptr);
        k_attn4<<<dim3(2048), dim3(256), 0, stream>>>(qkv, rpb, out);
        k_proj<<<dim3(1024), dim3(256), 0, stream>>>(proj_w, proj_b, rate1, out);
        k_conv7<<<dim3(1024), dim3(256), 0, stream>>>(qkv, fc_w, fc_b, dep_w,
                                                      dep_b, rate2, out);
    } else {
        float* wsf = (float*)d_ws;         // 148.6 KB
        k_prep_f<<<dim3(146), dim3(256), 0, stream>>>(qkv_w, qkv_b, fc_w, fc_b, wsf);
        k_attn_f<<<dim3(2048), dim3(256), 0, stream>>>(x, qkv_w, qkv_b, proj_w,
                                                       proj_b, rpb, rate1, out);
        k_conv_f<<<dim3(512), dim3(256), 0, stream>>>(x, wsf, dep_w, dep_b,
                                                      rate2, out);
    }
}